// Round 1
// 2187.707 us; speedup vs baseline: 1.1537x; 1.1537x over previous
//
#include <hip/hip_runtime.h>
#include <math.h>

typedef unsigned short u16;
typedef unsigned int u32;
typedef __attribute__((ext_vector_type(8))) short bf16x8;
typedef __attribute__((ext_vector_type(4))) float f32x4;

#define CNU 40000
#define CNN 80000
#define CD  128
#define CEMP 640000
#define CEUI 1600000
#define CB  8192

#define BK_CAP 8064     // per-bucket capacity (mean 5120 UI / 4096 MP; >40 sigma margin)
#define P1_CHUNK 4096   // edges per block in bucket pass 1 (16/thread)

__device__ __forceinline__ float bf2f(u16 b){
  union { u32 u; float f; } v; v.u = ((u32)b) << 16; return v.f;
}
__device__ __forceinline__ u16 f2bf(float f){
  union { float f; u32 u; } v; v.f = f;
  u32 u = v.u + 0x7FFFu + ((v.u >> 16) & 1u);
  return (u16)(u >> 16);
}
__device__ __forceinline__ float lo16f(u32 q){ union { u32 u; float f; } v; v.u = q << 16; return v.f; }
__device__ __forceinline__ float hi16f(u32 q){ union { u32 u; float f; } v; v.u = q & 0xFFFF0000u; return v.f; }

__global__ void k_zero(float* __restrict__ p, long long n){
  long long i = (long long)blockIdx.x*256 + threadIdx.x;
  if (i < n) p[i] = 0.f;
}

__global__ void k_izero(int* __restrict__ p, int n){
  int i = blockIdx.x*256 + threadIdx.x;
  if (i < n) p[i] = 0;
}

__global__ void k_initb(const float* __restrict__ fu, const float* __restrict__ fi,
                        u16* __restrict__ fb){
  int idx = blockIdx.x*256 + threadIdx.x;
  if (idx >= CNN*CD) return;
  float v = (idx < CNU*CD) ? fu[idx] : fi[idx - CNU*CD];
  fb[idx] = f2bf(v);
}

// transpose W1 (f32 [k][j]) -> bf16 [j][k] for MFMA B-operand loads
__global__ void k_w1t(const float* __restrict__ Wu, const float* __restrict__ Wi,
                      u16* __restrict__ Wut, u16* __restrict__ Wit){
  int idx = blockIdx.x*256 + threadIdx.x;
  if (idx >= 16384) return;
  int k = idx >> 7, j = idx & 127;
  Wut[j*128 + k] = f2bf(Wu[idx]);
  Wit[j*128 + k] = f2bf(Wi[idx]);
}

__global__ void k_deg(const int* __restrict__ src, const int* __restrict__ dst,
                      float* __restrict__ dego, float* __restrict__ degi, int E){
  int e = blockIdx.x*256 + threadIdx.x;
  if (e >= E) return;
  atomicAdd(&dego[src[e]], 1.0f);
  atomicAdd(&degi[dst[e]], 1.0f);
}

__global__ void k_rs(float* __restrict__ d, int n){
  int i = blockIdx.x*256 + threadIdx.x;
  if (i >= n) return;
  float v = d[i];
  v = (v > 1.0f) ? v : 1.0f;
  d[i] = rsqrtf(v);
}

__global__ void k_degui(const int* __restrict__ row, float* __restrict__ deg, int E){
  int e = blockIdx.x*256 + threadIdx.x;
  if (e >= E) return;
  atomicAdd(&deg[row[e]], 1.0f);
}

__global__ void k_dinv(float* __restrict__ d, int n){
  int i = blockIdx.x*256 + threadIdx.x;
  if (i >= n) return;
  float v = d[i];
  d[i] = (v > 0.f) ? rsqrtf(v) : 0.f;
}

// ---- CSR build via LDS-aggregated counting sort (replaces hist+scan+fill) ----
// Pass 1: chunk edges per block; LDS hist over dst>>8 buckets gives in-block ranks;
// one global atomicAdd per (block,bucket) reserves a contiguous region; edges stored
// packed (src | d_local<<18) into per-bucket arrays. Streaming-ish writes, ~100x fewer
// fabric transactions than the per-edge atomic fill.
__global__ void k_bucket1(const int* __restrict__ src, const int* __restrict__ dst,
                          int* __restrict__ gcur, u32* __restrict__ gpairs,
                          int E, int NB){
  __shared__ int cnt[320];
  __shared__ int sbase[320];
  int t = threadIdx.x;
  for (int i = t; i < NB; i += 256) cnt[i] = 0;
  __syncthreads();
  int base = blockIdx.x * P1_CHUNK;
  int r[16], dv[16], sv[16];
  #pragma unroll
  for (int u = 0; u < 16; ++u){
    int e = base + u*256 + t;
    bool ok = (e < E);
    dv[u] = ok ? dst[e] : -1;
    sv[u] = ok ? src[e] : 0;
    if (ok) r[u] = atomicAdd(&cnt[dv[u] >> 8], 1);
  }
  __syncthreads();
  for (int i = t; i < NB; i += 256){
    int c = cnt[i];
    sbase[i] = c ? atomicAdd(&gcur[i], c) : 0;
  }
  __syncthreads();
  #pragma unroll
  for (int u = 0; u < 16; ++u){
    if (dv[u] >= 0){
      int b = dv[u] >> 8;
      int p = sbase[b] + r[u];
      if (p < BK_CAP)
        gpairs[(long long)b*BK_CAP + p] = (u32)sv[u] | ((u32)(dv[u] & 255) << 18);
    }
  }
}

// exclusive scan of <=512 bucket counts (single block)
__global__ void k_scanb(const int* __restrict__ gcur, int* __restrict__ bbase, int NB){
  __shared__ int s[512];
  int t = threadIdx.x;
  int v = (t < NB) ? gcur[t] : 0;
  s[t] = v;
  __syncthreads();
  for (int off = 1; off < 512; off <<= 1){
    int u = (t >= off) ? s[t-off] : 0;
    __syncthreads();
    s[t] += u;
    __syncthreads();
  }
  if (t < NB) bbase[t] = s[t] - v;
}

// Pass 2: one block per bucket. Local hist over the bucket's 256 dst values,
// LDS scan, LDS scatter, then coalesced streaming write of the CSR segment + ptr slice.
__global__ void k_bucket2(const u32* __restrict__ gpairs, const int* __restrict__ gcur,
                          const int* __restrict__ bbase, int* __restrict__ csr,
                          int* __restrict__ ptr, int n){
  __shared__ int hist[256];
  __shared__ int excl[256];
  __shared__ int lptr[256];
  __shared__ int lsrc[BK_CAP];
  int b = blockIdx.x, t = threadIdx.x;
  int cnt = gcur[b]; if (cnt > BK_CAP) cnt = BK_CAP;
  int base = bbase[b];
  hist[t] = 0;
  __syncthreads();
  const u32* pp = gpairs + (long long)b*BK_CAP;
  for (int i = t; i < cnt; i += 256) atomicAdd(&hist[(pp[i] >> 18) & 255], 1);
  __syncthreads();
  int h = hist[t];
  lptr[t] = h;
  __syncthreads();
  for (int off = 1; off < 256; off <<= 1){
    int u2 = (t >= off) ? lptr[t-off] : 0;
    __syncthreads();
    lptr[t] += u2;
    __syncthreads();
  }
  excl[t] = lptr[t] - h;
  __syncthreads();
  hist[t] = excl[t];           // reuse hist as running cursor
  __syncthreads();
  for (int i = t; i < cnt; i += 256){
    u32 v = pp[i];
    int d = (v >> 18) & 255;
    int p = atomicAdd(&hist[d], 1);
    lsrc[p] = (int)(v & 0x3FFFFu);
  }
  __syncthreads();
  for (int i = t; i < cnt; i += 256) csr[base + i] = lsrc[i];
  int dg = (b << 8) + t;
  if (dg <= n) ptr[dg] = base + excl[t];
}

// ---- gather: 1 wave/row, lane=(g=edge-slot 0..3, c=16B-chunk 0..15) ----
__global__ void k_gather_mp(const u16* __restrict__ h, const int* __restrict__ ptr,
                            const int* __restrict__ csr_src, const float* __restrict__ rso,
                            u16* __restrict__ z, int n){
  int row = (blockIdx.x*256 + threadIdx.x) >> 6;
  if (row >= n) return;
  int lane = threadIdx.x & 63;
  int g = lane >> 4, c = lane & 15;
  int p = ptr[row], pe = ptr[row+1];
  float a0=0,a1=0,a2=0,a3=0,a4=0,a5=0,a6=0,a7=0;
  const u16* hb = h + (long long)c*8;
  while (p < pe){
    uint4 q[4]; float w[4];
    #pragma unroll
    for (int u = 0; u < 4; ++u){
      int ei = p + u*4 + g;
      int s  = (ei < pe) ? csr_src[ei] : 0;
      w[u]   = (ei < pe) ? rso[s] : 0.f;
      q[u]   = *(const uint4*)(hb + (long long)s*CD);
    }
    #pragma unroll
    for (int u = 0; u < 4; ++u){
      a0 += lo16f(q[u].x)*w[u]; a1 += hi16f(q[u].x)*w[u];
      a2 += lo16f(q[u].y)*w[u]; a3 += hi16f(q[u].y)*w[u];
      a4 += lo16f(q[u].z)*w[u]; a5 += hi16f(q[u].z)*w[u];
      a6 += lo16f(q[u].w)*w[u]; a7 += hi16f(q[u].w)*w[u];
    }
    p += 16;
  }
  #pragma unroll
  for (int m = 16; m <= 32; m <<= 1){
    a0 += __shfl_xor(a0, m); a1 += __shfl_xor(a1, m);
    a2 += __shfl_xor(a2, m); a3 += __shfl_xor(a3, m);
    a4 += __shfl_xor(a4, m); a5 += __shfl_xor(a5, m);
    a6 += __shfl_xor(a6, m); a7 += __shfl_xor(a7, m);
  }
  if (g == 0){
    uint4 o;
    o.x = (u32)f2bf(a0) | ((u32)f2bf(a1) << 16);
    o.y = (u32)f2bf(a2) | ((u32)f2bf(a3) << 16);
    o.z = (u32)f2bf(a4) | ((u32)f2bf(a5) << 16);
    o.w = (u32)f2bf(a6) | ((u32)f2bf(a7) << 16);
    *(uint4*)(z + (long long)row*CD + c*8) = o;
  }
}

__global__ void k_gather_ui(const u16* __restrict__ xin, const int* __restrict__ ptr,
                            const int* __restrict__ csr_src, const float* __restrict__ dinv,
                            u16* __restrict__ xout, int n){
  int row = (blockIdx.x*256 + threadIdx.x) >> 6;
  if (row >= n) return;
  int lane = threadIdx.x & 63;
  int g = lane >> 4, c = lane & 15;
  int p = ptr[row], pe = ptr[row+1];
  float a0=0,a1=0,a2=0,a3=0,a4=0,a5=0,a6=0,a7=0;
  const u16* hb = xin + (long long)c*8;
  while (p < pe){
    uint4 q[4]; float w[4];
    #pragma unroll
    for (int u = 0; u < 4; ++u){
      int ei = p + u*4 + g;
      int s  = (ei < pe) ? csr_src[ei] : 0;
      w[u]   = (ei < pe) ? dinv[s] : 0.f;
      q[u]   = *(const uint4*)(hb + (long long)s*CD);
    }
    #pragma unroll
    for (int u = 0; u < 4; ++u){
      a0 += lo16f(q[u].x)*w[u]; a1 += hi16f(q[u].x)*w[u];
      a2 += lo16f(q[u].y)*w[u]; a3 += hi16f(q[u].y)*w[u];
      a4 += lo16f(q[u].z)*w[u]; a5 += hi16f(q[u].z)*w[u];
      a6 += lo16f(q[u].w)*w[u]; a7 += hi16f(q[u].w)*w[u];
    }
    p += 16;
  }
  #pragma unroll
  for (int m = 16; m <= 32; m <<= 1){
    a0 += __shfl_xor(a0, m); a1 += __shfl_xor(a1, m);
    a2 += __shfl_xor(a2, m); a3 += __shfl_xor(a3, m);
    a4 += __shfl_xor(a4, m); a5 += __shfl_xor(a5, m);
    a6 += __shfl_xor(a6, m); a7 += __shfl_xor(a7, m);
  }
  if (g == 0){
    float wd = dinv[row];
    uint4 o;
    o.x = (u32)f2bf(a0*wd) | ((u32)f2bf(a1*wd) << 16);
    o.y = (u32)f2bf(a2*wd) | ((u32)f2bf(a3*wd) << 16);
    o.z = (u32)f2bf(a4*wd) | ((u32)f2bf(a5*wd) << 16);
    o.w = (u32)f2bf(a6*wd) | ((u32)f2bf(a7*wd) << 16);
    *(uint4*)(xout + (long long)row*CD + c*8) = o;
  }
}

// semantic attention scores via MFMA: s_out[ch] += sum_rows sum_j tanh(rsi*(z@W1)+b1)_j * W2_j
__global__ void k_att(const u16* __restrict__ z0, const u16* __restrict__ z1,
                      const float* __restrict__ rsi0, const float* __restrict__ rsi1,
                      const u16* __restrict__ W1T, const float* __restrict__ b1,
                      const float* __restrict__ W2, float* __restrict__ s_out, int n){
  int nb = n >> 6;
  int blk = blockIdx.x;
  int ch = (blk >= nb) ? 1 : 0;
  int rb = (ch ? (blk - nb) : blk) * 64;
  const u16* z = ch ? z1 : z0;
  const float* rsi = ch ? rsi1 : rsi0;
  int wv = threadIdx.x >> 6, lane = threadIdx.x & 63;
  int i0 = rb + wv*16;
  int m = lane & 15, kq = lane >> 4;
  bf16x8 a[4];
  #pragma unroll
  for (int t = 0; t < 4; ++t){
    uint4 q = *(const uint4*)(z + (long long)(i0+m)*CD + t*32 + kq*8);
    a[t] = *(bf16x8*)&q;
  }
  float rsv[4];
  #pragma unroll
  for (int ri = 0; ri < 4; ++ri) rsv[ri] = rsi[i0 + kq*4 + ri];
  float psum = 0.f;
  #pragma unroll
  for (int jt = 0; jt < 8; ++jt){
    f32x4 acc = {0.f,0.f,0.f,0.f};
    #pragma unroll
    for (int t = 0; t < 4; ++t){
      uint4 qb = *(const uint4*)(W1T + (jt*16 + m)*CD + t*32 + kq*8);
      bf16x8 b = *(bf16x8*)&qb;
      acc = __builtin_amdgcn_mfma_f32_16x16x32_bf16(a[t], b, acc, 0, 0, 0);
    }
    int j = jt*16 + m;
    float bb = b1[j], w2 = W2[j];
    #pragma unroll
    for (int ri = 0; ri < 4; ++ri){
      float x = acc[ri]*rsv[ri] + bb;
      x = fminf(fmaxf(x, -15.f), 15.f);
      float t2 = __expf(2.f*x);
      psum += ((t2 - 1.f)/(t2 + 1.f))*w2;
    }
  }
  #pragma unroll
  for (int msk = 1; msk <= 32; msk <<= 1) psum += __shfl_xor(psum, msk);
  if (lane == 0) atomicAdd(&s_out[ch], psum);
}

__global__ void k_combine(const u16* __restrict__ z0, const u16* __restrict__ z1,
                          const float* __restrict__ rsi0, const float* __restrict__ rsi1,
                          const float* __restrict__ s, u16* __restrict__ h, int n){
  int idx = blockIdx.x*256 + threadIdx.x;
  if (idx >= n*CD) return;
  int v = idx >> 7;
  float s0 = s[0]*(1.0f/n), s1 = s[1]*(1.0f/n);
  float m = fmaxf(s0, s1);
  float e0 = __expf(s0 - m), e1 = __expf(s1 - m);
  float r = 1.0f/(e0 + e1);
  h[idx] = f2bf((e0*r)*bf2f(z0[idx])*rsi0[v] + (e1*r)*bf2f(z1[idx])*rsi1[v]);
}

__global__ void k_emb(const u16* __restrict__ x2, u16* __restrict__ h_u,
                      u16* __restrict__ h_i){
  int idx = blockIdx.x*256 + threadIdx.x;
  if (idx >= CNN*CD) return;
  if (idx < CNU*CD) h_u[idx] = f2bf(0.5f*bf2f(h_u[idx]) + 0.5f*bf2f(x2[idx]));
  else { int k = idx - CNU*CD; h_i[k] = f2bf(0.5f*bf2f(h_i[k]) + 0.5f*bf2f(x2[idx])); }
}

__global__ void k_sslnorm(const u16* __restrict__ xui, const u16* __restrict__ hemb,
                          const int* __restrict__ idx, int rowoff,
                          u16* __restrict__ n1b, u16* __restrict__ n2b,
                          float* __restrict__ pos_acc){
  int r = blockIdx.x*4 + (threadIdx.x >> 6);
  int lane = threadIdx.x & 63;
  if (r >= CB) return;
  int g = idx[r];
  const u16* e1 = xui + (long long)(g + rowoff)*CD;
  const u16* e2 = hemb + (long long)g*CD;
  float a0 = bf2f(e1[lane]), a1 = bf2f(e1[lane+64]);
  float b0 = bf2f(e2[lane]), b1 = bf2f(e2[lane+64]);
  float s1 = a0*a0 + a1*a1, s2 = b0*b0 + b1*b1, s12 = a0*b0 + a1*b1;
  for (int off = 32; off > 0; off >>= 1){
    s1  += __shfl_down(s1, off);
    s2  += __shfl_down(s2, off);
    s12 += __shfl_down(s12, off);
  }
  s1 = __shfl(s1, 0); s2 = __shfl(s2, 0); s12 = __shfl(s12, 0);
  float i1 = 1.0f / fmaxf(sqrtf(s1), 1e-12f);
  float i2 = 1.0f / fmaxf(sqrtf(s2), 1e-12f);
  u16* o1 = n1b + (long long)r*CD;
  u16* o2 = n2b + (long long)r*CD;
  o1[lane] = f2bf(a0*i1); o1[lane+64] = f2bf(a1*i1);
  o2[lane] = f2bf(b0*i2); o2[lane+64] = f2bf(b1*i2);
  if (lane == 0) atomicAdd(pos_acc, s12*i1*i2*2.0f);
}

// alls[i] += sum_j exp(2 * n1_i . n2_j) via MFMA; 4 j-tiles in flight.
__global__ void k_alls(const u16* __restrict__ n1b, const u16* __restrict__ n2b,
                       float* __restrict__ alls){
  int wv = threadIdx.x >> 6;
  int lane = threadIdx.x & 63;
  int i0 = (blockIdx.x*4 + wv)*16;
  int m = lane & 15, kq = lane >> 4;
  bf16x8 a[4];
  #pragma unroll
  for (int t = 0; t < 4; ++t){
    uint4 q = *(const uint4*)(n1b + (long long)(i0+m)*CD + t*32 + kq*8);
    a[t] = *(bf16x8*)&q;
  }
  float es0=0.f, es1=0.f, es2=0.f, es3=0.f;
  int j0s = blockIdx.y*1024;
  for (int jt = 0; jt < 64; jt += 4){
    f32x4 ac0 = {0.f,0.f,0.f,0.f}, ac1 = ac0, ac2 = ac0, ac3 = ac0;
    const u16* base0 = n2b + (long long)(j0s + (jt+0)*16 + m)*CD + kq*8;
    const u16* base1 = n2b + (long long)(j0s + (jt+1)*16 + m)*CD + kq*8;
    const u16* base2 = n2b + (long long)(j0s + (jt+2)*16 + m)*CD + kq*8;
    const u16* base3 = n2b + (long long)(j0s + (jt+3)*16 + m)*CD + kq*8;
    #pragma unroll
    for (int t = 0; t < 4; ++t){
      uint4 q0 = *(const uint4*)(base0 + t*32);
      uint4 q1 = *(const uint4*)(base1 + t*32);
      uint4 q2 = *(const uint4*)(base2 + t*32);
      uint4 q3 = *(const uint4*)(base3 + t*32);
      ac0 = __builtin_amdgcn_mfma_f32_16x16x32_bf16(a[t], *(bf16x8*)&q0, ac0, 0, 0, 0);
      ac1 = __builtin_amdgcn_mfma_f32_16x16x32_bf16(a[t], *(bf16x8*)&q1, ac1, 0, 0, 0);
      ac2 = __builtin_amdgcn_mfma_f32_16x16x32_bf16(a[t], *(bf16x8*)&q2, ac2, 0, 0, 0);
      ac3 = __builtin_amdgcn_mfma_f32_16x16x32_bf16(a[t], *(bf16x8*)&q3, ac3, 0, 0, 0);
    }
    es0 += __expf(ac0[0]*2.f) + __expf(ac1[0]*2.f) + __expf(ac2[0]*2.f) + __expf(ac3[0]*2.f);
    es1 += __expf(ac0[1]*2.f) + __expf(ac1[1]*2.f) + __expf(ac2[1]*2.f) + __expf(ac3[1]*2.f);
    es2 += __expf(ac0[2]*2.f) + __expf(ac1[2]*2.f) + __expf(ac2[2]*2.f) + __expf(ac3[2]*2.f);
    es3 += __expf(ac0[3]*2.f) + __expf(ac1[3]*2.f) + __expf(ac2[3]*2.f) + __expf(ac3[3]*2.f);
  }
  #pragma unroll
  for (int msk = 1; msk <= 8; msk <<= 1){
    es0 += __shfl_xor(es0, msk);
    es1 += __shfl_xor(es1, msk);
    es2 += __shfl_xor(es2, msk);
    es3 += __shfl_xor(es3, msk);
  }
  if (m == 0){
    int rb = i0 + kq*4;
    atomicAdd(&alls[rb+0], es0);
    atomicAdd(&alls[rb+1], es1);
    atomicAdd(&alls[rb+2], es2);
    atomicAdd(&alls[rb+3], es3);
  }
}

__global__ void k_logsum(const float* __restrict__ alls, float* __restrict__ misc){
  int i = blockIdx.x*256 + threadIdx.x;
  float v = logf(alls[i]);
  for (int off = 32; off > 0; off >>= 1) v += __shfl_down(v, off);
  if ((threadIdx.x & 63) == 0) atomicAdd(&misc[(i < CB) ? 13 : 15], v);
}

__global__ void k_final(const u16* __restrict__ emb, const int* __restrict__ idx,
                        const float* __restrict__ W, const float* __restrict__ bias,
                        const float* __restrict__ lg, const float* __restrict__ lb,
                        float* __restrict__ outp){
  __shared__ float A[8][128];
  __shared__ float red[8][4];
  int j = threadIdx.x;
  int r0 = blockIdx.x*8;
  for (int r = 0; r < 8; ++r){
    int g = idx[r0 + r];
    A[r][j] = bf2f(emb[(long long)g*CD + j]);
  }
  __syncthreads();
  float acc[8];
  #pragma unroll
  for (int r = 0; r < 8; ++r) acc[r] = 0.f;
  for (int k = 0; k < 128; k += 4){
    float w0 = W[(k+0)*128 + j];
    float w1 = W[(k+1)*128 + j];
    float w2 = W[(k+2)*128 + j];
    float w3 = W[(k+3)*128 + j];
    #pragma unroll
    for (int r = 0; r < 8; ++r){
      float4 a = *(const float4*)&A[r][k];
      acc[r] += a.x*w0 + a.y*w1 + a.z*w2 + a.w*w3;
    }
  }
  float bb = bias[j];
  #pragma unroll
  for (int r = 0; r < 8; ++r){
    float v = acc[r] + bb;
    acc[r] = (v < 0.f) ? 0.f : v;
  }
  int wid = j >> 6, lane = j & 63;
  #pragma unroll
  for (int r = 0; r < 8; ++r){
    float s = acc[r], q = acc[r]*acc[r];
    for (int off = 32; off > 0; off >>= 1){
      s += __shfl_down(s, off); q += __shfl_down(q, off);
    }
    if (lane == 0){ red[r][wid*2] = s; red[r][wid*2+1] = q; }
  }
  __syncthreads();
  float gg = lg[j], be = lb[j];
  #pragma unroll
  for (int r = 0; r < 8; ++r){
    float mu = (red[r][0] + red[r][2]) * (1.0f/128.0f);
    float ms = (red[r][1] + red[r][3]) * (1.0f/128.0f);
    float var = ms - mu*mu;
    float y = (acc[r] - mu) * rsqrtf(var + 1e-5f) * gg + be;
    outp[(long long)(r0 + r)*CD + j] = y;
  }
}

__global__ void k_loss(const float* __restrict__ misc, float* __restrict__ o){
  float lu = (misc[13] - misc[12]) * (1.0f/CB);
  float li = (misc[15] - misc[14]) * (1.0f/CB);
  o[0] = 0.4f*(lu + li);
}

extern "C" void kernel_launch(void* const* d_in, const int* in_sizes, int n_in,
                              void* d_out, int out_size, void* d_ws, size_t ws_size,
                              hipStream_t stream){
  (void)in_sizes; (void)n_in; (void)out_size; (void)ws_size;
  const float* feat_user = (const float*)d_in[0];
  const float* feat_item = (const float*)d_in[1];
  const float* u_W1 = (const float*)d_in[2];
  const float* u_b1 = (const float*)d_in[3];
  const float* u_W2 = (const float*)d_in[4];
  const float* i_W1 = (const float*)d_in[5];
  const float* i_b1 = (const float*)d_in[6];
  const float* i_W2 = (const float*)d_in[7];
  const float* user_W = (const float*)d_in[8];
  const float* user_b = (const float*)d_in[9];
  const float* item_W = (const float*)d_in[10];
  const float* item_b = (const float*)d_in[11];
  const float* ln_g = (const float*)d_in[12];
  const float* ln_b = (const float*)d_in[13];
  const int* ump0s = (const int*)d_in[14]; const int* ump0d = (const int*)d_in[15];
  const int* ump1s = (const int*)d_in[16]; const int* ump1d = (const int*)d_in[17];
  const int* imp0s = (const int*)d_in[18]; const int* imp0d = (const int*)d_in[19];
  const int* imp1s = (const int*)d_in[20]; const int* imp1d = (const int*)d_in[21];
  const int* ui_row = (const int*)d_in[22]; const int* ui_col = (const int*)d_in[23];
  const int* user_idx = (const int*)d_in[24]; const int* item_idx = (const int*)d_in[25];
  const int* neg_idx = (const int*)d_in[26];

  u16* W  = (u16*)d_ws;
  u16* fb = W;                      // 10,240,000 bf16
  u16* hu = W + 10240000LL;
  u16* hi = W + 15360000LL;
  u16* xb = W + 20480000LL;
  u16* x2 = W + 30720000LL;
  u16* z0 = W + 40960000LL;
  u16* z1 = W + 46080000LL;
  float* F   = (float*)(W + 51200000LL);
  float* rs  = F;                   // 320,000
  float* dinv= F + 320000;          // 80,000
  float* alls= F + 400000;          // 16,384
  float* misc= F + 416384;          // 64
  int* I     = (int*)(F + 416448);
  int* mp_p0 = I;                   // 40,001
  int* mp_p1 = I + 40001;           // 40,001
  int* gcur  = I + 80002;           // 320  (bucket cursors/counts)
  int* bbase = I + 80322;           // 320  (bucket exclusive-scan bases)
  int* mp_c0 = I + 120002;          // 640,000
  int* mp_c1 = I + 760002;          // 640,000
  u16* w1tu  = (u16*)(I + 1400128); // 16,384 bf16 (W1^T user)
  u16* w1ti  = w1tu + 16384;        // 16,384 bf16 (W1^T item)
  int* ui_ptr    = (int*)hu;        // overlay (hu/hi dead until first combine)
  int* ui_csr    = ui_ptr + 160001; // 1,600,000 ints
  u32* gpairs    = (u32*)z0;        // overlay: bucket pairs, 313*8064*4B = 10.1MB (z0 dead during builds)
  u16* n1ub = xb;                   // overlay (xb dead after UI hop 3)
  u16* n2ub = xb + (long long)CB*CD;
  u16* n1ib = xb + 2LL*CB*CD;
  u16* n2ib = xb + 3LL*CB*CD;
  float* out = (float*)d_out;

  k_zero<<<(400000 + 255)/256, 256, 0, stream>>>(rs, 400000);
  k_zero<<<(16448 + 255)/256, 256, 0, stream>>>(alls, 16448);

  k_initb<<<40000, 256, 0, stream>>>(feat_user, feat_item, fb);
  k_w1t<<<64, 256, 0, stream>>>(u_W1, i_W1, w1tu, w1ti);

  k_deg<<<2500, 256, 0, stream>>>(ump0s, ump0d, rs + 0,      rs + 40000,  CEMP);
  k_deg<<<2500, 256, 0, stream>>>(ump1s, ump1d, rs + 80000,  rs + 120000, CEMP);
  k_deg<<<2500, 256, 0, stream>>>(imp0s, imp0d, rs + 160000, rs + 200000, CEMP);
  k_deg<<<2500, 256, 0, stream>>>(imp1s, imp1d, rs + 240000, rs + 280000, CEMP);
  k_rs<<<1250, 256, 0, stream>>>(rs, 320000);
  k_degui<<<6250, 256, 0, stream>>>(ui_row, dinv, CEUI);
  k_dinv<<<(CNN + 255)/256, 256, 0, stream>>>(dinv, CNN);

  // UI CSR build (counting sort; NB=313 buckets of 256 dst)
  k_izero<<<2, 256, 0, stream>>>(gcur, 320);
  k_bucket1<<<(CEUI + P1_CHUNK - 1)/P1_CHUNK, 256, 0, stream>>>(ui_col, ui_row, gcur, gpairs, CEUI, 313);
  k_scanb<<<1, 512, 0, stream>>>(gcur, bbase, 313);
  k_bucket2<<<313, 256, 0, stream>>>(gpairs, gcur, bbase, ui_csr, ui_ptr, CNN);

  // UI propagation: fb -> x2 -> xb -> x2
  k_gather_ui<<<20000, 256, 0, stream>>>(fb, ui_ptr, ui_csr, dinv, x2, CNN);
  k_gather_ui<<<20000, 256, 0, stream>>>(x2, ui_ptr, ui_csr, dinv, xb, CNN);
  k_gather_ui<<<20000, 256, 0, stream>>>(xb, ui_ptr, ui_csr, dinv, x2, CNN);

  // HAN user CSRs (NB=157)
  k_izero<<<2, 256, 0, stream>>>(gcur, 320);
  k_bucket1<<<(CEMP + P1_CHUNK - 1)/P1_CHUNK, 256, 0, stream>>>(ump0s, ump0d, gcur, gpairs, CEMP, 157);
  k_scanb<<<1, 512, 0, stream>>>(gcur, bbase, 157);
  k_bucket2<<<157, 256, 0, stream>>>(gpairs, gcur, bbase, mp_c0, mp_p0, CNU);
  k_izero<<<2, 256, 0, stream>>>(gcur, 320);
  k_bucket1<<<(CEMP + P1_CHUNK - 1)/P1_CHUNK, 256, 0, stream>>>(ump1s, ump1d, gcur, gpairs, CEMP, 157);
  k_scanb<<<1, 512, 0, stream>>>(gcur, bbase, 157);
  k_bucket2<<<157, 256, 0, stream>>>(gpairs, gcur, bbase, mp_c1, mp_p1, CNU);
  for (int L = 0; L < 3; ++L){
    const u16* hin = (L == 0) ? fb : hu;
    k_gather_mp<<<10000, 256, 0, stream>>>(hin, mp_p0, mp_c0, rs + 0,     z0, CNU);
    k_gather_mp<<<10000, 256, 0, stream>>>(hin, mp_p1, mp_c1, rs + 80000, z1, CNU);
    k_att<<<1250, 256, 0, stream>>>(z0, z1, rs + 40000, rs + 120000,
                                    w1tu, u_b1, u_W2, misc + 2*L, CNU);
    k_combine<<<20000, 256, 0, stream>>>(z0, z1, rs + 40000, rs + 120000,
                                         misc + 2*L, hu, CNU);
  }
  // HAN item CSRs (z0/z1 dead between loops -> gpairs overlay safe)
  k_izero<<<2, 256, 0, stream>>>(gcur, 320);
  k_bucket1<<<(CEMP + P1_CHUNK - 1)/P1_CHUNK, 256, 0, stream>>>(imp0s, imp0d, gcur, gpairs, CEMP, 157);
  k_scanb<<<1, 512, 0, stream>>>(gcur, bbase, 157);
  k_bucket2<<<157, 256, 0, stream>>>(gpairs, gcur, bbase, mp_c0, mp_p0, CNU);
  k_izero<<<2, 256, 0, stream>>>(gcur, 320);
  k_bucket1<<<(CEMP + P1_CHUNK - 1)/P1_CHUNK, 256, 0, stream>>>(imp1s, imp1d, gcur, gpairs, CEMP, 157);
  k_scanb<<<1, 512, 0, stream>>>(gcur, bbase, 157);
  k_bucket2<<<157, 256, 0, stream>>>(gpairs, gcur, bbase, mp_c1, mp_p1, CNU);
  for (int L = 0; L < 3; ++L){
    const u16* hin = (L == 0) ? (fb + (long long)CNU*CD) : hi;
    k_gather_mp<<<10000, 256, 0, stream>>>(hin, mp_p0, mp_c0, rs + 160000, z0, CNU);
    k_gather_mp<<<10000, 256, 0, stream>>>(hin, mp_p1, mp_c1, rs + 240000, z1, CNU);
    k_att<<<1250, 256, 0, stream>>>(z0, z1, rs + 200000, rs + 280000,
                                    w1ti, i_b1, i_W2, misc + 6 + 2*L, CNU);
    k_combine<<<20000, 256, 0, stream>>>(z0, z1, rs + 200000, rs + 280000,
                                         misc + 6 + 2*L, hi, CNU);
  }

  k_emb<<<40000, 256, 0, stream>>>(x2, hu, hi);

  // SSL
  k_sslnorm<<<CB/4, 256, 0, stream>>>(x2, hu, user_idx, 0,   n1ub, n2ub, misc + 12);
  k_sslnorm<<<CB/4, 256, 0, stream>>>(x2, hi, item_idx, CNU, n1ib, n2ib, misc + 14);
  k_alls<<<dim3(128, 8), 256, 0, stream>>>(n1ub, n2ub, alls);
  k_alls<<<dim3(128, 8), 256, 0, stream>>>(n1ib, n2ib, alls + CB);
  k_logsum<<<64, 256, 0, stream>>>(alls, misc);

  k_final<<<1024, 128, 0, stream>>>(hu, user_idx, user_W, user_b, ln_g, ln_b, out);
  k_final<<<1024, 128, 0, stream>>>(hi, item_idx, item_W, item_b, ln_g, ln_b, out + (long long)CB*CD);
  k_final<<<1024, 128, 0, stream>>>(hi, neg_idx,  item_W, item_b, ln_g, ln_b, out + 2LL*CB*CD);
  k_loss<<<1, 1, 0, stream>>>(misc, out + 3LL*CB*CD);
}

// Round 2
// 2032.996 us; speedup vs baseline: 1.2415x; 1.0761x over previous
//
#include <hip/hip_runtime.h>
#include <math.h>

typedef unsigned short u16;
typedef unsigned int u32;
typedef __attribute__((ext_vector_type(8))) short bf16x8;
typedef __attribute__((ext_vector_type(4))) float f32x4;

#define CNU 40000
#define CNN 80000
#define CD  128
#define CEMP 640000
#define CEUI 1600000
#define CB  8192

#define BK_CAP 8064     // per-bucket capacity (mean 5120 UI / 4096 MP; >40 sigma margin)
#define P1_CHUNK 4096   // edges per block in bucket pass 1 (16/thread)

__device__ __forceinline__ float bf2f(u16 b){
  union { u32 u; float f; } v; v.u = ((u32)b) << 16; return v.f;
}
__device__ __forceinline__ u16 f2bf(float f){
  union { float f; u32 u; } v; v.f = f;
  u32 u = v.u + 0x7FFFu + ((v.u >> 16) & 1u);
  return (u16)(u >> 16);
}
__device__ __forceinline__ float lo16f(u32 q){ union { u32 u; float f; } v; v.u = q << 16; return v.f; }
__device__ __forceinline__ float hi16f(u32 q){ union { u32 u; float f; } v; v.u = q & 0xFFFF0000u; return v.f; }

__global__ void k_zero(float* __restrict__ p, long long n){
  long long i = (long long)blockIdx.x*256 + threadIdx.x;
  if (i < n) p[i] = 0.f;
}

__global__ void k_izero(int* __restrict__ p, int n){
  int i = blockIdx.x*256 + threadIdx.x;
  if (i < n) p[i] = 0;
}

__global__ void k_initb(const float* __restrict__ fu, const float* __restrict__ fi,
                        u16* __restrict__ fb){
  int idx = blockIdx.x*256 + threadIdx.x;
  if (idx >= CNN*CD) return;
  float v = (idx < CNU*CD) ? fu[idx] : fi[idx - CNU*CD];
  fb[idx] = f2bf(v);
}

// transpose W1 (f32 [k][j]) -> bf16 [j][k] for MFMA B-operand loads
__global__ void k_w1t(const float* __restrict__ Wu, const float* __restrict__ Wi,
                      u16* __restrict__ Wut, u16* __restrict__ Wit){
  int idx = blockIdx.x*256 + threadIdx.x;
  if (idx >= 16384) return;
  int k = idx >> 7, j = idx & 127;
  Wut[j*128 + k] = f2bf(Wu[idx]);
  Wit[j*128 + k] = f2bf(Wi[idx]);
}

__global__ void k_deg(const int* __restrict__ src, const int* __restrict__ dst,
                      float* __restrict__ dego, float* __restrict__ degi, int E){
  int e = blockIdx.x*256 + threadIdx.x;
  if (e >= E) return;
  atomicAdd(&dego[src[e]], 1.0f);
  atomicAdd(&degi[dst[e]], 1.0f);
}

__global__ void k_rs(float* __restrict__ d, int n){
  int i = blockIdx.x*256 + threadIdx.x;
  if (i >= n) return;
  float v = d[i];
  v = (v > 1.0f) ? v : 1.0f;
  d[i] = rsqrtf(v);
}

__global__ void k_degui(const int* __restrict__ row, float* __restrict__ deg, int E){
  int e = blockIdx.x*256 + threadIdx.x;
  if (e >= E) return;
  atomicAdd(&deg[row[e]], 1.0f);
}

__global__ void k_dinv(float* __restrict__ d, int n){
  int i = blockIdx.x*256 + threadIdx.x;
  if (i >= n) return;
  float v = d[i];
  d[i] = (v > 0.f) ? rsqrtf(v) : 0.f;
}

// ---- CSR build via LDS-aggregated counting sort ----
__global__ void k_bucket1(const int* __restrict__ src, const int* __restrict__ dst,
                          int* __restrict__ gcur, u32* __restrict__ gpairs,
                          int E, int NB){
  __shared__ int cnt[320];
  __shared__ int sbase[320];
  int t = threadIdx.x;
  for (int i = t; i < NB; i += 256) cnt[i] = 0;
  __syncthreads();
  int base = blockIdx.x * P1_CHUNK;
  int r[16], dv[16], sv[16];
  #pragma unroll
  for (int u = 0; u < 16; ++u){
    int e = base + u*256 + t;
    bool ok = (e < E);
    dv[u] = ok ? dst[e] : -1;
    sv[u] = ok ? src[e] : 0;
    if (ok) r[u] = atomicAdd(&cnt[dv[u] >> 8], 1);
  }
  __syncthreads();
  for (int i = t; i < NB; i += 256){
    int c = cnt[i];
    sbase[i] = c ? atomicAdd(&gcur[i], c) : 0;
  }
  __syncthreads();
  #pragma unroll
  for (int u = 0; u < 16; ++u){
    if (dv[u] >= 0){
      int b = dv[u] >> 8;
      int p = sbase[b] + r[u];
      if (p < BK_CAP)
        gpairs[(long long)b*BK_CAP + p] = (u32)sv[u] | ((u32)(dv[u] & 255) << 18);
    }
  }
}

// exclusive scan of <=512 bucket counts (single block)
__global__ void k_scanb(const int* __restrict__ gcur, int* __restrict__ bbase, int NB){
  __shared__ int s[512];
  int t = threadIdx.x;
  int v = (t < NB) ? gcur[t] : 0;
  s[t] = v;
  __syncthreads();
  for (int off = 1; off < 512; off <<= 1){
    int u = (t >= off) ? s[t-off] : 0;
    __syncthreads();
    s[t] += u;
    __syncthreads();
  }
  if (t < NB) bbase[t] = s[t] - v;
}

// Pass 2: one block per bucket; LDS scatter then streaming CSR write + ptr slice.
__global__ void k_bucket2(const u32* __restrict__ gpairs, const int* __restrict__ gcur,
                          const int* __restrict__ bbase, int* __restrict__ csr,
                          int* __restrict__ ptr, int n){
  __shared__ int hist[256];
  __shared__ int excl[256];
  __shared__ int lptr[256];
  __shared__ int lsrc[BK_CAP];
  int b = blockIdx.x, t = threadIdx.x;
  int cnt = gcur[b]; if (cnt > BK_CAP) cnt = BK_CAP;
  int base = bbase[b];
  hist[t] = 0;
  __syncthreads();
  const u32* pp = gpairs + (long long)b*BK_CAP;
  for (int i = t; i < cnt; i += 256) atomicAdd(&hist[(pp[i] >> 18) & 255], 1);
  __syncthreads();
  int h = hist[t];
  lptr[t] = h;
  __syncthreads();
  for (int off = 1; off < 256; off <<= 1){
    int u2 = (t >= off) ? lptr[t-off] : 0;
    __syncthreads();
    lptr[t] += u2;
    __syncthreads();
  }
  excl[t] = lptr[t] - h;
  __syncthreads();
  hist[t] = excl[t];           // reuse hist as running cursor
  __syncthreads();
  for (int i = t; i < cnt; i += 256){
    u32 v = pp[i];
    int d = (v >> 18) & 255;
    int p = atomicAdd(&hist[d], 1);
    lsrc[p] = (int)(v & 0x3FFFFu);
  }
  __syncthreads();
  for (int i = t; i < cnt; i += 256) csr[base + i] = lsrc[i];
  int dg = (b << 8) + t;
  if (dg <= n) ptr[dg] = base + excl[t];
}

// ---- gather: 1 wave/row, lane=(g=edge-slot 0..3, c=16B-chunk 0..15) ----
__global__ void k_gather_mp(const u16* __restrict__ h, const int* __restrict__ ptr,
                            const int* __restrict__ csr_src, const float* __restrict__ rso,
                            u16* __restrict__ z, int n){
  int row = (blockIdx.x*256 + threadIdx.x) >> 6;
  if (row >= n) return;
  int lane = threadIdx.x & 63;
  int g = lane >> 4, c = lane & 15;
  int p = ptr[row], pe = ptr[row+1];
  float a0=0,a1=0,a2=0,a3=0,a4=0,a5=0,a6=0,a7=0;
  const u16* hb = h + (long long)c*8;
  while (p < pe){
    uint4 q[4]; float w[4];
    #pragma unroll
    for (int u = 0; u < 4; ++u){
      int ei = p + u*4 + g;
      int s  = (ei < pe) ? csr_src[ei] : 0;
      w[u]   = (ei < pe) ? rso[s] : 0.f;
      q[u]   = *(const uint4*)(hb + (long long)s*CD);
    }
    #pragma unroll
    for (int u = 0; u < 4; ++u){
      a0 += lo16f(q[u].x)*w[u]; a1 += hi16f(q[u].x)*w[u];
      a2 += lo16f(q[u].y)*w[u]; a3 += hi16f(q[u].y)*w[u];
      a4 += lo16f(q[u].z)*w[u]; a5 += hi16f(q[u].z)*w[u];
      a6 += lo16f(q[u].w)*w[u]; a7 += hi16f(q[u].w)*w[u];
    }
    p += 16;
  }
  #pragma unroll
  for (int m = 16; m <= 32; m <<= 1){
    a0 += __shfl_xor(a0, m); a1 += __shfl_xor(a1, m);
    a2 += __shfl_xor(a2, m); a3 += __shfl_xor(a3, m);
    a4 += __shfl_xor(a4, m); a5 += __shfl_xor(a5, m);
    a6 += __shfl_xor(a6, m); a7 += __shfl_xor(a7, m);
  }
  if (g == 0){
    uint4 o;
    o.x = (u32)f2bf(a0) | ((u32)f2bf(a1) << 16);
    o.y = (u32)f2bf(a2) | ((u32)f2bf(a3) << 16);
    o.z = (u32)f2bf(a4) | ((u32)f2bf(a5) << 16);
    o.w = (u32)f2bf(a6) | ((u32)f2bf(a7) << 16);
    *(uint4*)(z + (long long)row*CD + c*8) = o;
  }
}

__global__ void k_gather_ui(const u16* __restrict__ xin, const int* __restrict__ ptr,
                            const int* __restrict__ csr_src, const float* __restrict__ dinv,
                            u16* __restrict__ xout, int n){
  int row = (blockIdx.x*256 + threadIdx.x) >> 6;
  if (row >= n) return;
  int lane = threadIdx.x & 63;
  int g = lane >> 4, c = lane & 15;
  int p = ptr[row], pe = ptr[row+1];
  float a0=0,a1=0,a2=0,a3=0,a4=0,a5=0,a6=0,a7=0;
  const u16* hb = xin + (long long)c*8;
  while (p < pe){
    uint4 q[4]; float w[4];
    #pragma unroll
    for (int u = 0; u < 4; ++u){
      int ei = p + u*4 + g;
      int s  = (ei < pe) ? csr_src[ei] : 0;
      w[u]   = (ei < pe) ? dinv[s] : 0.f;
      q[u]   = *(const uint4*)(hb + (long long)s*CD);
    }
    #pragma unroll
    for (int u = 0; u < 4; ++u){
      a0 += lo16f(q[u].x)*w[u]; a1 += hi16f(q[u].x)*w[u];
      a2 += lo16f(q[u].y)*w[u]; a3 += hi16f(q[u].y)*w[u];
      a4 += lo16f(q[u].z)*w[u]; a5 += hi16f(q[u].z)*w[u];
      a6 += lo16f(q[u].w)*w[u]; a7 += hi16f(q[u].w)*w[u];
    }
    p += 16;
  }
  #pragma unroll
  for (int m = 16; m <= 32; m <<= 1){
    a0 += __shfl_xor(a0, m); a1 += __shfl_xor(a1, m);
    a2 += __shfl_xor(a2, m); a3 += __shfl_xor(a3, m);
    a4 += __shfl_xor(a4, m); a5 += __shfl_xor(a5, m);
    a6 += __shfl_xor(a6, m); a7 += __shfl_xor(a7, m);
  }
  if (g == 0){
    float wd = dinv[row];
    uint4 o;
    o.x = (u32)f2bf(a0*wd) | ((u32)f2bf(a1*wd) << 16);
    o.y = (u32)f2bf(a2*wd) | ((u32)f2bf(a3*wd) << 16);
    o.z = (u32)f2bf(a4*wd) | ((u32)f2bf(a5*wd) << 16);
    o.w = (u32)f2bf(a6*wd) | ((u32)f2bf(a7*wd) << 16);
    *(uint4*)(xout + (long long)row*CD + c*8) = o;
  }
}

// semantic attention scores via MFMA
__global__ void k_att(const u16* __restrict__ z0, const u16* __restrict__ z1,
                      const float* __restrict__ rsi0, const float* __restrict__ rsi1,
                      const u16* __restrict__ W1T, const float* __restrict__ b1,
                      const float* __restrict__ W2, float* __restrict__ s_out, int n){
  int nb = n >> 6;
  int blk = blockIdx.x;
  int ch = (blk >= nb) ? 1 : 0;
  int rb = (ch ? (blk - nb) : blk) * 64;
  const u16* z = ch ? z1 : z0;
  const float* rsi = ch ? rsi1 : rsi0;
  int wv = threadIdx.x >> 6, lane = threadIdx.x & 63;
  int i0 = rb + wv*16;
  int m = lane & 15, kq = lane >> 4;
  bf16x8 a[4];
  #pragma unroll
  for (int t = 0; t < 4; ++t){
    uint4 q = *(const uint4*)(z + (long long)(i0+m)*CD + t*32 + kq*8);
    a[t] = *(bf16x8*)&q;
  }
  float rsv[4];
  #pragma unroll
  for (int ri = 0; ri < 4; ++ri) rsv[ri] = rsi[i0 + kq*4 + ri];
  float psum = 0.f;
  #pragma unroll
  for (int jt = 0; jt < 8; ++jt){
    f32x4 acc = {0.f,0.f,0.f,0.f};
    #pragma unroll
    for (int t = 0; t < 4; ++t){
      uint4 qb = *(const uint4*)(W1T + (jt*16 + m)*CD + t*32 + kq*8);
      bf16x8 b = *(bf16x8*)&qb;
      acc = __builtin_amdgcn_mfma_f32_16x16x32_bf16(a[t], b, acc, 0, 0, 0);
    }
    int j = jt*16 + m;
    float bb = b1[j], w2 = W2[j];
    #pragma unroll
    for (int ri = 0; ri < 4; ++ri){
      float x = acc[ri]*rsv[ri] + bb;
      x = fminf(fmaxf(x, -15.f), 15.f);
      float t2 = __expf(2.f*x);
      psum += ((t2 - 1.f)/(t2 + 1.f))*w2;
    }
  }
  #pragma unroll
  for (int msk = 1; msk <= 32; msk <<= 1) psum += __shfl_xor(psum, msk);
  if (lane == 0) atomicAdd(&s_out[ch], psum);
}

__global__ void k_combine(const u16* __restrict__ z0, const u16* __restrict__ z1,
                          const float* __restrict__ rsi0, const float* __restrict__ rsi1,
                          const float* __restrict__ s, u16* __restrict__ h, int n){
  int idx = blockIdx.x*256 + threadIdx.x;
  if (idx >= n*CD) return;
  int v = idx >> 7;
  float s0 = s[0]*(1.0f/n), s1 = s[1]*(1.0f/n);
  float m = fmaxf(s0, s1);
  float e0 = __expf(s0 - m), e1 = __expf(s1 - m);
  float r = 1.0f/(e0 + e1);
  h[idx] = f2bf((e0*r)*bf2f(z0[idx])*rsi0[v] + (e1*r)*bf2f(z1[idx])*rsi1[v]);
}

__global__ void k_emb(const u16* __restrict__ x2, u16* __restrict__ h_u,
                      u16* __restrict__ h_i){
  int idx = blockIdx.x*256 + threadIdx.x;
  if (idx >= CNN*CD) return;
  if (idx < CNU*CD) h_u[idx] = f2bf(0.5f*bf2f(h_u[idx]) + 0.5f*bf2f(x2[idx]));
  else { int k = idx - CNU*CD; h_i[k] = f2bf(0.5f*bf2f(h_i[k]) + 0.5f*bf2f(x2[idx])); }
}

__global__ void k_sslnorm(const u16* __restrict__ xui, const u16* __restrict__ hemb,
                          const int* __restrict__ idx, int rowoff,
                          u16* __restrict__ n1b, u16* __restrict__ n2b,
                          float* __restrict__ pos_acc){
  int r = blockIdx.x*4 + (threadIdx.x >> 6);
  int lane = threadIdx.x & 63;
  if (r >= CB) return;
  int g = idx[r];
  const u16* e1 = xui + (long long)(g + rowoff)*CD;
  const u16* e2 = hemb + (long long)g*CD;
  float a0 = bf2f(e1[lane]), a1 = bf2f(e1[lane+64]);
  float b0 = bf2f(e2[lane]), b1 = bf2f(e2[lane+64]);
  float s1 = a0*a0 + a1*a1, s2 = b0*b0 + b1*b1, s12 = a0*b0 + a1*b1;
  for (int off = 32; off > 0; off >>= 1){
    s1  += __shfl_down(s1, off);
    s2  += __shfl_down(s2, off);
    s12 += __shfl_down(s12, off);
  }
  s1 = __shfl(s1, 0); s2 = __shfl(s2, 0); s12 = __shfl(s12, 0);
  float i1 = 1.0f / fmaxf(sqrtf(s1), 1e-12f);
  float i2 = 1.0f / fmaxf(sqrtf(s2), 1e-12f);
  u16* o1 = n1b + (long long)r*CD;
  u16* o2 = n2b + (long long)r*CD;
  o1[lane] = f2bf(a0*i1); o1[lane+64] = f2bf(a1*i1);
  o2[lane] = f2bf(b0*i2); o2[lane+64] = f2bf(b1*i2);
  if (lane == 0) atomicAdd(pos_acc, s12*i1*i2*2.0f);
}

// alls[i] += sum_j exp(2 * n1_i . n2_j) via MFMA.
// Register-blocked: each wave owns 4 i-tiles (64 rows, a[4][4] = 64 VGPRs); per j-tile the
// B-fragment is loaded ONCE and reused across all 4 i-tiles (4x fewer loads/MFMA), with the
// next j-tile's loads double-buffered so L2 latency hides under MFMA+exp compute.
__global__ void k_alls(const u16* __restrict__ n1b, const u16* __restrict__ n2b,
                       float* __restrict__ alls){
  int wv = threadIdx.x >> 6;
  int lane = threadIdx.x & 63;
  int m = lane & 15, kq = lane >> 4;
  int i0 = (blockIdx.x*4 + wv)*64;
  bf16x8 a[4][4];
  #pragma unroll
  for (int c = 0; c < 4; ++c){
    #pragma unroll
    for (int t = 0; t < 4; ++t){
      uint4 q = *(const uint4*)(n1b + (long long)(i0 + c*16 + m)*CD + t*32 + kq*8);
      a[c][t] = *(bf16x8*)&q;
    }
  }
  float es[4][4];
  #pragma unroll
  for (int c = 0; c < 4; ++c)
    #pragma unroll
    for (int ri = 0; ri < 4; ++ri) es[c][ri] = 0.f;

  const u16* jb = n2b + (long long)(blockIdx.y*512 + m)*CD + kq*8;
  uint4 q[4];
  #pragma unroll
  for (int t = 0; t < 4; ++t) q[t] = *(const uint4*)(jb + t*32);
  for (int jt = 0; jt < 32; ++jt){
    uint4 qn[4];
    if (jt < 31){
      const u16* jb2 = jb + (long long)(jt+1)*16*CD;
      #pragma unroll
      for (int t = 0; t < 4; ++t) qn[t] = *(const uint4*)(jb2 + t*32);
    }
    f32x4 ac[4];
    #pragma unroll
    for (int c = 0; c < 4; ++c) ac[c] = (f32x4){0.f,0.f,0.f,0.f};
    #pragma unroll
    for (int t = 0; t < 4; ++t){
      bf16x8 b = *(bf16x8*)&q[t];
      #pragma unroll
      for (int c = 0; c < 4; ++c)
        ac[c] = __builtin_amdgcn_mfma_f32_16x16x32_bf16(a[c][t], b, ac[c], 0, 0, 0);
    }
    #pragma unroll
    for (int c = 0; c < 4; ++c)
      #pragma unroll
      for (int ri = 0; ri < 4; ++ri)
        es[c][ri] += __expf(ac[c][ri]*2.f);
    if (jt < 31){
      #pragma unroll
      for (int t = 0; t < 4; ++t) q[t] = qn[t];
    }
  }
  #pragma unroll
  for (int c = 0; c < 4; ++c){
    #pragma unroll
    for (int ri = 0; ri < 4; ++ri){
      float v = es[c][ri];
      #pragma unroll
      for (int msk = 1; msk <= 8; msk <<= 1) v += __shfl_xor(v, msk);
      if (m == 0) atomicAdd(&alls[i0 + c*16 + kq*4 + ri], v);
    }
  }
}

__global__ void k_logsum(const float* __restrict__ alls, float* __restrict__ misc){
  int i = blockIdx.x*256 + threadIdx.x;
  float v = logf(alls[i]);
  for (int off = 32; off > 0; off >>= 1) v += __shfl_down(v, off);
  if ((threadIdx.x & 63) == 0) atomicAdd(&misc[(i < CB) ? 13 : 15], v);
}

__global__ void k_final(const u16* __restrict__ emb, const int* __restrict__ idx,
                        const float* __restrict__ W, const float* __restrict__ bias,
                        const float* __restrict__ lg, const float* __restrict__ lb,
                        float* __restrict__ outp){
  __shared__ float A[8][128];
  __shared__ float red[8][4];
  int j = threadIdx.x;
  int r0 = blockIdx.x*8;
  for (int r = 0; r < 8; ++r){
    int g = idx[r0 + r];
    A[r][j] = bf2f(emb[(long long)g*CD + j]);
  }
  __syncthreads();
  float acc[8];
  #pragma unroll
  for (int r = 0; r < 8; ++r) acc[r] = 0.f;
  for (int k = 0; k < 128; k += 4){
    float w0 = W[(k+0)*128 + j];
    float w1 = W[(k+1)*128 + j];
    float w2 = W[(k+2)*128 + j];
    float w3 = W[(k+3)*128 + j];
    #pragma unroll
    for (int r = 0; r < 8; ++r){
      float4 a = *(const float4*)&A[r][k];
      acc[r] += a.x*w0 + a.y*w1 + a.z*w2 + a.w*w3;
    }
  }
  float bb = bias[j];
  #pragma unroll
  for (int r = 0; r < 8; ++r){
    float v = acc[r] + bb;
    acc[r] = (v < 0.f) ? 0.f : v;
  }
  int wid = j >> 6, lane = j & 63;
  #pragma unroll
  for (int r = 0; r < 8; ++r){
    float s = acc[r], q = acc[r]*acc[r];
    for (int off = 32; off > 0; off >>= 1){
      s += __shfl_down(s, off); q += __shfl_down(q, off);
    }
    if (lane == 0){ red[r][wid*2] = s; red[r][wid*2+1] = q; }
  }
  __syncthreads();
  float gg = lg[j], be = lb[j];
  #pragma unroll
  for (int r = 0; r < 8; ++r){
    float mu = (red[r][0] + red[r][2]) * (1.0f/128.0f);
    float ms = (red[r][1] + red[r][3]) * (1.0f/128.0f);
    float var = ms - mu*mu;
    float y = (acc[r] - mu) * rsqrtf(var + 1e-5f) * gg + be;
    outp[(long long)(r0 + r)*CD + j] = y;
  }
}

__global__ void k_loss(const float* __restrict__ misc, float* __restrict__ o){
  float lu = (misc[13] - misc[12]) * (1.0f/CB);
  float li = (misc[15] - misc[14]) * (1.0f/CB);
  o[0] = 0.4f*(lu + li);
}

extern "C" void kernel_launch(void* const* d_in, const int* in_sizes, int n_in,
                              void* d_out, int out_size, void* d_ws, size_t ws_size,
                              hipStream_t stream){
  (void)in_sizes; (void)n_in; (void)out_size; (void)ws_size;
  const float* feat_user = (const float*)d_in[0];
  const float* feat_item = (const float*)d_in[1];
  const float* u_W1 = (const float*)d_in[2];
  const float* u_b1 = (const float*)d_in[3];
  const float* u_W2 = (const float*)d_in[4];
  const float* i_W1 = (const float*)d_in[5];
  const float* i_b1 = (const float*)d_in[6];
  const float* i_W2 = (const float*)d_in[7];
  const float* user_W = (const float*)d_in[8];
  const float* user_b = (const float*)d_in[9];
  const float* item_W = (const float*)d_in[10];
  const float* item_b = (const float*)d_in[11];
  const float* ln_g = (const float*)d_in[12];
  const float* ln_b = (const float*)d_in[13];
  const int* ump0s = (const int*)d_in[14]; const int* ump0d = (const int*)d_in[15];
  const int* ump1s = (const int*)d_in[16]; const int* ump1d = (const int*)d_in[17];
  const int* imp0s = (const int*)d_in[18]; const int* imp0d = (const int*)d_in[19];
  const int* imp1s = (const int*)d_in[20]; const int* imp1d = (const int*)d_in[21];
  const int* ui_row = (const int*)d_in[22]; const int* ui_col = (const int*)d_in[23];
  const int* user_idx = (const int*)d_in[24]; const int* item_idx = (const int*)d_in[25];
  const int* neg_idx = (const int*)d_in[26];

  u16* W  = (u16*)d_ws;
  u16* fb = W;                      // 10,240,000 bf16
  u16* hu = W + 10240000LL;
  u16* hi = W + 15360000LL;
  u16* xb = W + 20480000LL;
  u16* x2 = W + 30720000LL;
  u16* z0 = W + 40960000LL;
  u16* z1 = W + 46080000LL;
  float* F   = (float*)(W + 51200000LL);
  float* rs  = F;                   // 320,000
  float* dinv= F + 320000;          // 80,000
  float* alls= F + 400000;          // 16,384
  float* misc= F + 416384;          // 64
  int* I     = (int*)(F + 416448);
  int* mp_p0 = I;                   // 40,001
  int* mp_p1 = I + 40001;           // 40,001
  int* gcur  = I + 80002;           // 320  (bucket cursors/counts)
  int* bbase = I + 80322;           // 320  (bucket exclusive-scan bases)
  int* mp_c0 = I + 120002;          // 640,000
  int* mp_c1 = I + 760002;          // 640,000
  u16* w1tu  = (u16*)(I + 1400128); // 16,384 bf16 (W1^T user)
  u16* w1ti  = w1tu + 16384;        // 16,384 bf16 (W1^T item)
  int* ui_ptr    = (int*)hu;        // overlay (hu/hi dead until first combine)
  int* ui_csr    = ui_ptr + 160001; // 1,600,000 ints
  u32* gpairs    = (u32*)z0;        // overlay: bucket pairs, 313*8064*4B = 10.1MB (z0 dead during builds)
  u16* n1ub = xb;                   // overlay (xb dead after UI hop 3)
  u16* n2ub = xb + (long long)CB*CD;
  u16* n1ib = xb + 2LL*CB*CD;
  u16* n2ib = xb + 3LL*CB*CD;
  float* out = (float*)d_out;

  k_zero<<<(400000 + 255)/256, 256, 0, stream>>>(rs, 400000);
  k_zero<<<(16448 + 255)/256, 256, 0, stream>>>(alls, 16448);

  k_initb<<<40000, 256, 0, stream>>>(feat_user, feat_item, fb);
  k_w1t<<<64, 256, 0, stream>>>(u_W1, i_W1, w1tu, w1ti);

  k_deg<<<2500, 256, 0, stream>>>(ump0s, ump0d, rs + 0,      rs + 40000,  CEMP);
  k_deg<<<2500, 256, 0, stream>>>(ump1s, ump1d, rs + 80000,  rs + 120000, CEMP);
  k_deg<<<2500, 256, 0, stream>>>(imp0s, imp0d, rs + 160000, rs + 200000, CEMP);
  k_deg<<<2500, 256, 0, stream>>>(imp1s, imp1d, rs + 240000, rs + 280000, CEMP);
  k_rs<<<1250, 256, 0, stream>>>(rs, 320000);
  k_degui<<<6250, 256, 0, stream>>>(ui_row, dinv, CEUI);
  k_dinv<<<(CNN + 255)/256, 256, 0, stream>>>(dinv, CNN);

  // UI CSR build (counting sort; NB=313 buckets of 256 dst)
  k_izero<<<2, 256, 0, stream>>>(gcur, 320);
  k_bucket1<<<(CEUI + P1_CHUNK - 1)/P1_CHUNK, 256, 0, stream>>>(ui_col, ui_row, gcur, gpairs, CEUI, 313);
  k_scanb<<<1, 512, 0, stream>>>(gcur, bbase, 313);
  k_bucket2<<<313, 256, 0, stream>>>(gpairs, gcur, bbase, ui_csr, ui_ptr, CNN);

  // UI propagation: fb -> x2 -> xb -> x2
  k_gather_ui<<<20000, 256, 0, stream>>>(fb, ui_ptr, ui_csr, dinv, x2, CNN);
  k_gather_ui<<<20000, 256, 0, stream>>>(x2, ui_ptr, ui_csr, dinv, xb, CNN);
  k_gather_ui<<<20000, 256, 0, stream>>>(xb, ui_ptr, ui_csr, dinv, x2, CNN);

  // HAN user CSRs (NB=157)
  k_izero<<<2, 256, 0, stream>>>(gcur, 320);
  k_bucket1<<<(CEMP + P1_CHUNK - 1)/P1_CHUNK, 256, 0, stream>>>(ump0s, ump0d, gcur, gpairs, CEMP, 157);
  k_scanb<<<1, 512, 0, stream>>>(gcur, bbase, 157);
  k_bucket2<<<157, 256, 0, stream>>>(gpairs, gcur, bbase, mp_c0, mp_p0, CNU);
  k_izero<<<2, 256, 0, stream>>>(gcur, 320);
  k_bucket1<<<(CEMP + P1_CHUNK - 1)/P1_CHUNK, 256, 0, stream>>>(ump1s, ump1d, gcur, gpairs, CEMP, 157);
  k_scanb<<<1, 512, 0, stream>>>(gcur, bbase, 157);
  k_bucket2<<<157, 256, 0, stream>>>(gpairs, gcur, bbase, mp_c1, mp_p1, CNU);
  for (int L = 0; L < 3; ++L){
    const u16* hin = (L == 0) ? fb : hu;
    k_gather_mp<<<10000, 256, 0, stream>>>(hin, mp_p0, mp_c0, rs + 0,     z0, CNU);
    k_gather_mp<<<10000, 256, 0, stream>>>(hin, mp_p1, mp_c1, rs + 80000, z1, CNU);
    k_att<<<1250, 256, 0, stream>>>(z0, z1, rs + 40000, rs + 120000,
                                    w1tu, u_b1, u_W2, misc + 2*L, CNU);
    k_combine<<<20000, 256, 0, stream>>>(z0, z1, rs + 40000, rs + 120000,
                                         misc + 2*L, hu, CNU);
  }
  // HAN item CSRs (z0/z1 dead between loops -> gpairs overlay safe)
  k_izero<<<2, 256, 0, stream>>>(gcur, 320);
  k_bucket1<<<(CEMP + P1_CHUNK - 1)/P1_CHUNK, 256, 0, stream>>>(imp0s, imp0d, gcur, gpairs, CEMP, 157);
  k_scanb<<<1, 512, 0, stream>>>(gcur, bbase, 157);
  k_bucket2<<<157, 256, 0, stream>>>(gpairs, gcur, bbase, mp_c0, mp_p0, CNU);
  k_izero<<<2, 256, 0, stream>>>(gcur, 320);
  k_bucket1<<<(CEMP + P1_CHUNK - 1)/P1_CHUNK, 256, 0, stream>>>(imp1s, imp1d, gcur, gpairs, CEMP, 157);
  k_scanb<<<1, 512, 0, stream>>>(gcur, bbase, 157);
  k_bucket2<<<157, 256, 0, stream>>>(gpairs, gcur, bbase, mp_c1, mp_p1, CNU);
  for (int L = 0; L < 3; ++L){
    const u16* hin = (L == 0) ? (fb + (long long)CNU*CD) : hi;
    k_gather_mp<<<10000, 256, 0, stream>>>(hin, mp_p0, mp_c0, rs + 160000, z0, CNU);
    k_gather_mp<<<10000, 256, 0, stream>>>(hin, mp_p1, mp_c1, rs + 240000, z1, CNU);
    k_att<<<1250, 256, 0, stream>>>(z0, z1, rs + 200000, rs + 280000,
                                    w1ti, i_b1, i_W2, misc + 6 + 2*L, CNU);
    k_combine<<<20000, 256, 0, stream>>>(z0, z1, rs + 200000, rs + 280000,
                                         misc + 6 + 2*L, hi, CNU);
  }

  k_emb<<<40000, 256, 0, stream>>>(x2, hu, hi);

  // SSL
  k_sslnorm<<<CB/4, 256, 0, stream>>>(x2, hu, user_idx, 0,   n1ub, n2ub, misc + 12);
  k_sslnorm<<<CB/4, 256, 0, stream>>>(x2, hi, item_idx, CNU, n1ib, n2ib, misc + 14);
  k_alls<<<dim3(32, 16), 256, 0, stream>>>(n1ub, n2ub, alls);
  k_alls<<<dim3(32, 16), 256, 0, stream>>>(n1ib, n2ib, alls + CB);
  k_logsum<<<64, 256, 0, stream>>>(alls, misc);

  k_final<<<1024, 128, 0, stream>>>(hu, user_idx, user_W, user_b, ln_g, ln_b, out);
  k_final<<<1024, 128, 0, stream>>>(hi, item_idx, item_W, item_b, ln_g, ln_b, out + (long long)CB*CD);
  k_final<<<1024, 128, 0, stream>>>(hi, neg_idx,  item_W, item_b, ln_g, ln_b, out + 2LL*CB*CD);
  k_loss<<<1, 1, 0, stream>>>(misc, out + 3LL*CB*CD);
}

// Round 3
// 1569.402 us; speedup vs baseline: 1.6083x; 1.2954x over previous
//
#include <hip/hip_runtime.h>
#include <math.h>

typedef unsigned short u16;
typedef unsigned int u32;
typedef __attribute__((ext_vector_type(8))) short bf16x8;
typedef __attribute__((ext_vector_type(4))) float f32x4;

#define CNU 40000
#define CNN 80000
#define CD  128
#define CEMP 640000
#define CEUI 1600000
#define CB  8192

#define BK_CAP 8064     // per-bucket capacity (mean 5120 UI / 4096 MP; >40 sigma margin)
#define P1_CHUNK 4096   // edges per block in bucket pass 1 (16/thread)

__device__ __forceinline__ float bf2f(u16 b){
  union { u32 u; float f; } v; v.u = ((u32)b) << 16; return v.f;
}
__device__ __forceinline__ u16 f2bf(float f){
  union { float f; u32 u; } v; v.f = f;
  u32 u = v.u + 0x7FFFu + ((v.u >> 16) & 1u);
  return (u16)(u >> 16);
}
__device__ __forceinline__ float lo16f(u32 q){ union { u32 u; float f; } v; v.u = q << 16; return v.f; }
__device__ __forceinline__ float hi16f(u32 q){ union { u32 u; float f; } v; v.u = q & 0xFFFF0000u; return v.f; }

__global__ void k_zero(float* __restrict__ p, long long n){
  long long i = (long long)blockIdx.x*256 + threadIdx.x;
  if (i < n) p[i] = 0.f;
}

__global__ void k_izero(int* __restrict__ p, int n){
  int i = blockIdx.x*256 + threadIdx.x;
  if (i < n) p[i] = 0;
}

__global__ void k_initb(const float* __restrict__ fu, const float* __restrict__ fi,
                        u16* __restrict__ fb){
  int idx = blockIdx.x*256 + threadIdx.x;
  if (idx >= CNN*CD) return;
  float v = (idx < CNU*CD) ? fu[idx] : fi[idx - CNU*CD];
  fb[idx] = f2bf(v);
}

// transpose W1 (f32 [k][j]) -> bf16 [j][k] for MFMA B-operand loads
__global__ void k_w1t(const float* __restrict__ Wu, const float* __restrict__ Wi,
                      u16* __restrict__ Wut, u16* __restrict__ Wit){
  int idx = blockIdx.x*256 + threadIdx.x;
  if (idx >= 16384) return;
  int k = idx >> 7, j = idx & 127;
  Wut[j*128 + k] = f2bf(Wu[idx]);
  Wit[j*128 + k] = f2bf(Wi[idx]);
}

__global__ void k_deg(const int* __restrict__ src, const int* __restrict__ dst,
                      float* __restrict__ dego, float* __restrict__ degi, int E){
  int e = blockIdx.x*256 + threadIdx.x;
  if (e >= E) return;
  atomicAdd(&dego[src[e]], 1.0f);
  atomicAdd(&degi[dst[e]], 1.0f);
}

__global__ void k_rs(float* __restrict__ d, int n){
  int i = blockIdx.x*256 + threadIdx.x;
  if (i >= n) return;
  float v = d[i];
  v = (v > 1.0f) ? v : 1.0f;
  d[i] = rsqrtf(v);
}

__global__ void k_degui(const int* __restrict__ row, float* __restrict__ deg, int E){
  int e = blockIdx.x*256 + threadIdx.x;
  if (e >= E) return;
  atomicAdd(&deg[row[e]], 1.0f);
}

__global__ void k_dinv(float* __restrict__ d, int n){
  int i = blockIdx.x*256 + threadIdx.x;
  if (i >= n) return;
  float v = d[i];
  d[i] = (v > 0.f) ? rsqrtf(v) : 0.f;
}

// ---- CSR build via LDS-aggregated counting sort ----
__global__ void k_bucket1(const int* __restrict__ src, const int* __restrict__ dst,
                          int* __restrict__ gcur, u32* __restrict__ gpairs,
                          int E, int NB){
  __shared__ int cnt[320];
  __shared__ int sbase[320];
  int t = threadIdx.x;
  for (int i = t; i < NB; i += 256) cnt[i] = 0;
  __syncthreads();
  int base = blockIdx.x * P1_CHUNK;
  int r[16], dv[16], sv[16];
  #pragma unroll
  for (int u = 0; u < 16; ++u){
    int e = base + u*256 + t;
    bool ok = (e < E);
    dv[u] = ok ? dst[e] : -1;
    sv[u] = ok ? src[e] : 0;
    if (ok) r[u] = atomicAdd(&cnt[dv[u] >> 8], 1);
  }
  __syncthreads();
  for (int i = t; i < NB; i += 256){
    int c = cnt[i];
    sbase[i] = c ? atomicAdd(&gcur[i], c) : 0;
  }
  __syncthreads();
  #pragma unroll
  for (int u = 0; u < 16; ++u){
    if (dv[u] >= 0){
      int b = dv[u] >> 8;
      int p = sbase[b] + r[u];
      if (p < BK_CAP)
        gpairs[(long long)b*BK_CAP + p] = (u32)sv[u] | ((u32)(dv[u] & 255) << 18);
    }
  }
}

// exclusive scan of <=512 bucket counts (single block)
__global__ void k_scanb(const int* __restrict__ gcur, int* __restrict__ bbase, int NB){
  __shared__ int s[512];
  int t = threadIdx.x;
  int v = (t < NB) ? gcur[t] : 0;
  s[t] = v;
  __syncthreads();
  for (int off = 1; off < 512; off <<= 1){
    int u = (t >= off) ? s[t-off] : 0;
    __syncthreads();
    s[t] += u;
    __syncthreads();
  }
  if (t < NB) bbase[t] = s[t] - v;
}

// Pass 2: one block per bucket; LDS scatter then streaming CSR write + ptr slice.
__global__ void k_bucket2(const u32* __restrict__ gpairs, const int* __restrict__ gcur,
                          const int* __restrict__ bbase, int* __restrict__ csr,
                          int* __restrict__ ptr, int n){
  __shared__ int hist[256];
  __shared__ int excl[256];
  __shared__ int lptr[256];
  __shared__ int lsrc[BK_CAP];
  int b = blockIdx.x, t = threadIdx.x;
  int cnt = gcur[b]; if (cnt > BK_CAP) cnt = BK_CAP;
  int base = bbase[b];
  hist[t] = 0;
  __syncthreads();
  const u32* pp = gpairs + (long long)b*BK_CAP;
  for (int i = t; i < cnt; i += 256) atomicAdd(&hist[(pp[i] >> 18) & 255], 1);
  __syncthreads();
  int h = hist[t];
  lptr[t] = h;
  __syncthreads();
  for (int off = 1; off < 256; off <<= 1){
    int u2 = (t >= off) ? lptr[t-off] : 0;
    __syncthreads();
    lptr[t] += u2;
    __syncthreads();
  }
  excl[t] = lptr[t] - h;
  __syncthreads();
  hist[t] = excl[t];           // reuse hist as running cursor
  __syncthreads();
  for (int i = t; i < cnt; i += 256){
    u32 v = pp[i];
    int d = (v >> 18) & 255;
    int p = atomicAdd(&hist[d], 1);
    lsrc[p] = (int)(v & 0x3FFFFu);
  }
  __syncthreads();
  for (int i = t; i < cnt; i += 256) csr[base + i] = lsrc[i];
  int dg = (b << 8) + t;
  if (dg <= n) ptr[dg] = base + excl[t];
}

// ---- gather: 1 wave/row, lane=(g=edge-slot 0..3, c=16B-chunk 0..15) ----
__global__ void k_gather_mp(const u16* __restrict__ h, const int* __restrict__ ptr,
                            const int* __restrict__ csr_src, const float* __restrict__ rso,
                            u16* __restrict__ z, int n){
  int row = (blockIdx.x*256 + threadIdx.x) >> 6;
  if (row >= n) return;
  int lane = threadIdx.x & 63;
  int g = lane >> 4, c = lane & 15;
  int p = ptr[row], pe = ptr[row+1];
  float a0=0,a1=0,a2=0,a3=0,a4=0,a5=0,a6=0,a7=0;
  const u16* hb = h + (long long)c*8;
  while (p < pe){
    uint4 q[4]; float w[4];
    #pragma unroll
    for (int u = 0; u < 4; ++u){
      int ei = p + u*4 + g;
      int s  = (ei < pe) ? csr_src[ei] : 0;
      w[u]   = (ei < pe) ? rso[s] : 0.f;
      q[u]   = *(const uint4*)(hb + (long long)s*CD);
    }
    #pragma unroll
    for (int u = 0; u < 4; ++u){
      a0 += lo16f(q[u].x)*w[u]; a1 += hi16f(q[u].x)*w[u];
      a2 += lo16f(q[u].y)*w[u]; a3 += hi16f(q[u].y)*w[u];
      a4 += lo16f(q[u].z)*w[u]; a5 += hi16f(q[u].z)*w[u];
      a6 += lo16f(q[u].w)*w[u]; a7 += hi16f(q[u].w)*w[u];
    }
    p += 16;
  }
  #pragma unroll
  for (int m = 16; m <= 32; m <<= 1){
    a0 += __shfl_xor(a0, m); a1 += __shfl_xor(a1, m);
    a2 += __shfl_xor(a2, m); a3 += __shfl_xor(a3, m);
    a4 += __shfl_xor(a4, m); a5 += __shfl_xor(a5, m);
    a6 += __shfl_xor(a6, m); a7 += __shfl_xor(a7, m);
  }
  if (g == 0){
    uint4 o;
    o.x = (u32)f2bf(a0) | ((u32)f2bf(a1) << 16);
    o.y = (u32)f2bf(a2) | ((u32)f2bf(a3) << 16);
    o.z = (u32)f2bf(a4) | ((u32)f2bf(a5) << 16);
    o.w = (u32)f2bf(a6) | ((u32)f2bf(a7) << 16);
    *(uint4*)(z + (long long)row*CD + c*8) = o;
  }
}

__global__ void k_gather_ui(const u16* __restrict__ xin, const int* __restrict__ ptr,
                            const int* __restrict__ csr_src, const float* __restrict__ dinv,
                            u16* __restrict__ xout, int n){
  int row = (blockIdx.x*256 + threadIdx.x) >> 6;
  if (row >= n) return;
  int lane = threadIdx.x & 63;
  int g = lane >> 4, c = lane & 15;
  int p = ptr[row], pe = ptr[row+1];
  float a0=0,a1=0,a2=0,a3=0,a4=0,a5=0,a6=0,a7=0;
  const u16* hb = xin + (long long)c*8;
  while (p < pe){
    uint4 q[4]; float w[4];
    #pragma unroll
    for (int u = 0; u < 4; ++u){
      int ei = p + u*4 + g;
      int s  = (ei < pe) ? csr_src[ei] : 0;
      w[u]   = (ei < pe) ? dinv[s] : 0.f;
      q[u]   = *(const uint4*)(hb + (long long)s*CD);
    }
    #pragma unroll
    for (int u = 0; u < 4; ++u){
      a0 += lo16f(q[u].x)*w[u]; a1 += hi16f(q[u].x)*w[u];
      a2 += lo16f(q[u].y)*w[u]; a3 += hi16f(q[u].y)*w[u];
      a4 += lo16f(q[u].z)*w[u]; a5 += hi16f(q[u].z)*w[u];
      a6 += lo16f(q[u].w)*w[u]; a7 += hi16f(q[u].w)*w[u];
    }
    p += 16;
  }
  #pragma unroll
  for (int m = 16; m <= 32; m <<= 1){
    a0 += __shfl_xor(a0, m); a1 += __shfl_xor(a1, m);
    a2 += __shfl_xor(a2, m); a3 += __shfl_xor(a3, m);
    a4 += __shfl_xor(a4, m); a5 += __shfl_xor(a5, m);
    a6 += __shfl_xor(a6, m); a7 += __shfl_xor(a7, m);
  }
  if (g == 0){
    float wd = dinv[row];
    uint4 o;
    o.x = (u32)f2bf(a0*wd) | ((u32)f2bf(a1*wd) << 16);
    o.y = (u32)f2bf(a2*wd) | ((u32)f2bf(a3*wd) << 16);
    o.z = (u32)f2bf(a4*wd) | ((u32)f2bf(a5*wd) << 16);
    o.w = (u32)f2bf(a6*wd) | ((u32)f2bf(a7*wd) << 16);
    *(uint4*)(xout + (long long)row*CD + c*8) = o;
  }
}

// semantic attention scores via MFMA; block-level reduction -> 1 atomic/block
__global__ void k_att(const u16* __restrict__ z0, const u16* __restrict__ z1,
                      const float* __restrict__ rsi0, const float* __restrict__ rsi1,
                      const u16* __restrict__ W1T, const float* __restrict__ b1,
                      const float* __restrict__ W2, float* __restrict__ s_out, int n){
  __shared__ float wred[4];
  int nb = n >> 6;
  int blk = blockIdx.x;
  int ch = (blk >= nb) ? 1 : 0;
  int rb = (ch ? (blk - nb) : blk) * 64;
  const u16* z = ch ? z1 : z0;
  const float* rsi = ch ? rsi1 : rsi0;
  int wv = threadIdx.x >> 6, lane = threadIdx.x & 63;
  int i0 = rb + wv*16;
  int m = lane & 15, kq = lane >> 4;
  bf16x8 a[4];
  #pragma unroll
  for (int t = 0; t < 4; ++t){
    uint4 q = *(const uint4*)(z + (long long)(i0+m)*CD + t*32 + kq*8);
    a[t] = *(bf16x8*)&q;
  }
  float rsv[4];
  #pragma unroll
  for (int ri = 0; ri < 4; ++ri) rsv[ri] = rsi[i0 + kq*4 + ri];
  float psum = 0.f;
  #pragma unroll
  for (int jt = 0; jt < 8; ++jt){
    f32x4 acc = {0.f,0.f,0.f,0.f};
    #pragma unroll
    for (int t = 0; t < 4; ++t){
      uint4 qb = *(const uint4*)(W1T + (jt*16 + m)*CD + t*32 + kq*8);
      bf16x8 b = *(bf16x8*)&qb;
      acc = __builtin_amdgcn_mfma_f32_16x16x32_bf16(a[t], b, acc, 0, 0, 0);
    }
    int j = jt*16 + m;
    float bb = b1[j], w2 = W2[j];
    #pragma unroll
    for (int ri = 0; ri < 4; ++ri){
      float x = acc[ri]*rsv[ri] + bb;
      x = fminf(fmaxf(x, -15.f), 15.f);
      float t2 = __expf(2.f*x);
      psum += ((t2 - 1.f)/(t2 + 1.f))*w2;
    }
  }
  #pragma unroll
  for (int msk = 1; msk <= 32; msk <<= 1) psum += __shfl_xor(psum, msk);
  if (lane == 0) wred[wv] = psum;
  __syncthreads();
  if (threadIdx.x == 0)
    atomicAdd(&s_out[ch], wred[0] + wred[1] + wred[2] + wred[3]);
}

__global__ void k_combine(const u16* __restrict__ z0, const u16* __restrict__ z1,
                          const float* __restrict__ rsi0, const float* __restrict__ rsi1,
                          const float* __restrict__ s, u16* __restrict__ h, int n){
  int idx = blockIdx.x*256 + threadIdx.x;
  if (idx >= n*CD) return;
  int v = idx >> 7;
  float s0 = s[0]*(1.0f/n), s1 = s[1]*(1.0f/n);
  float m = fmaxf(s0, s1);
  float e0 = __expf(s0 - m), e1 = __expf(s1 - m);
  float r = 1.0f/(e0 + e1);
  h[idx] = f2bf((e0*r)*bf2f(z0[idx])*rsi0[v] + (e1*r)*bf2f(z1[idx])*rsi1[v]);
}

__global__ void k_emb(const u16* __restrict__ x2, u16* __restrict__ h_u,
                      u16* __restrict__ h_i){
  int idx = blockIdx.x*256 + threadIdx.x;
  if (idx >= CNN*CD) return;
  if (idx < CNU*CD) h_u[idx] = f2bf(0.5f*bf2f(h_u[idx]) + 0.5f*bf2f(x2[idx]));
  else { int k = idx - CNU*CD; h_i[k] = f2bf(0.5f*bf2f(h_i[k]) + 0.5f*bf2f(x2[idx])); }
}

// 4 rows/wave, 4 waves/block (grid CB/16); u32 row loads; block-level pos reduction
// -> 512 atomics instead of 8192 same-address atomics (was 107us of serialization).
__global__ void k_sslnorm(const u16* __restrict__ xui, const u16* __restrict__ hemb,
                          const int* __restrict__ idx, int rowoff,
                          u16* __restrict__ n1b, u16* __restrict__ n2b,
                          float* __restrict__ pos_acc){
  __shared__ float wred[4];
  int wv = threadIdx.x >> 6, lane = threadIdx.x & 63;
  int r0 = blockIdx.x*16 + wv*4;
  int g[4]; u32 q1[4], q2[4];
  #pragma unroll
  for (int u = 0; u < 4; ++u){
    g[u] = idx[r0 + u];
    q1[u] = *(const u32*)(xui + (long long)(g[u] + rowoff)*CD + lane*2);
    q2[u] = *(const u32*)(hemb + (long long)g[u]*CD + lane*2);
  }
  float psum = 0.f;
  #pragma unroll
  for (int u = 0; u < 4; ++u){
    float a0 = lo16f(q1[u]), a1 = hi16f(q1[u]);
    float b0 = lo16f(q2[u]), b1 = hi16f(q2[u]);
    float s1 = a0*a0 + a1*a1, s2 = b0*b0 + b1*b1, s12 = a0*b0 + a1*b1;
    #pragma unroll
    for (int msk = 1; msk <= 32; msk <<= 1){
      s1  += __shfl_xor(s1, msk);
      s2  += __shfl_xor(s2, msk);
      s12 += __shfl_xor(s12, msk);
    }
    float i1 = 1.0f / fmaxf(sqrtf(s1), 1e-12f);
    float i2 = 1.0f / fmaxf(sqrtf(s2), 1e-12f);
    *(u32*)(n1b + (long long)(r0+u)*CD + lane*2) = (u32)f2bf(a0*i1) | ((u32)f2bf(a1*i1) << 16);
    *(u32*)(n2b + (long long)(r0+u)*CD + lane*2) = (u32)f2bf(b0*i2) | ((u32)f2bf(b1*i2) << 16);
    psum += s12*i1*i2*2.0f;
  }
  if (lane == 0) wred[wv] = psum;
  __syncthreads();
  if (threadIdx.x == 0)
    atomicAdd(pos_acc, wred[0] + wred[1] + wred[2] + wred[3]);
}

// alls[i] += sum_j exp(2 * n1_i . n2_j) via MFMA; register-blocked 4 i-tiles/wave.
__global__ void k_alls(const u16* __restrict__ n1b, const u16* __restrict__ n2b,
                       float* __restrict__ alls){
  int wv = threadIdx.x >> 6;
  int lane = threadIdx.x & 63;
  int m = lane & 15, kq = lane >> 4;
  int i0 = (blockIdx.x*4 + wv)*64;
  bf16x8 a[4][4];
  #pragma unroll
  for (int c = 0; c < 4; ++c){
    #pragma unroll
    for (int t = 0; t < 4; ++t){
      uint4 q = *(const uint4*)(n1b + (long long)(i0 + c*16 + m)*CD + t*32 + kq*8);
      a[c][t] = *(bf16x8*)&q;
    }
  }
  float es[4][4];
  #pragma unroll
  for (int c = 0; c < 4; ++c)
    #pragma unroll
    for (int ri = 0; ri < 4; ++ri) es[c][ri] = 0.f;

  const u16* jb = n2b + (long long)(blockIdx.y*512 + m)*CD + kq*8;
  uint4 q[4];
  #pragma unroll
  for (int t = 0; t < 4; ++t) q[t] = *(const uint4*)(jb + t*32);
  for (int jt = 0; jt < 32; ++jt){
    uint4 qn[4];
    if (jt < 31){
      const u16* jb2 = jb + (long long)(jt+1)*16*CD;
      #pragma unroll
      for (int t = 0; t < 4; ++t) qn[t] = *(const uint4*)(jb2 + t*32);
    }
    f32x4 ac[4];
    #pragma unroll
    for (int c = 0; c < 4; ++c) ac[c] = (f32x4){0.f,0.f,0.f,0.f};
    #pragma unroll
    for (int t = 0; t < 4; ++t){
      bf16x8 b = *(bf16x8*)&q[t];
      #pragma unroll
      for (int c = 0; c < 4; ++c)
        ac[c] = __builtin_amdgcn_mfma_f32_16x16x32_bf16(a[c][t], b, ac[c], 0, 0, 0);
    }
    #pragma unroll
    for (int c = 0; c < 4; ++c)
      #pragma unroll
      for (int ri = 0; ri < 4; ++ri)
        es[c][ri] += __expf(ac[c][ri]*2.f);
    if (jt < 31){
      #pragma unroll
      for (int t = 0; t < 4; ++t) q[t] = qn[t];
    }
  }
  #pragma unroll
  for (int c = 0; c < 4; ++c){
    #pragma unroll
    for (int ri = 0; ri < 4; ++ri){
      float v = es[c][ri];
      #pragma unroll
      for (int msk = 1; msk <= 8; msk <<= 1) v += __shfl_xor(v, msk);
      if (m == 0) atomicAdd(&alls[i0 + c*16 + kq*4 + ri], v);
    }
  }
}

__global__ void k_logsum(const float* __restrict__ alls, float* __restrict__ misc){
  int i = blockIdx.x*256 + threadIdx.x;
  float v = logf(alls[i]);
  for (int off = 32; off > 0; off >>= 1) v += __shfl_down(v, off);
  if ((threadIdx.x & 63) == 0) atomicAdd(&misc[(i < CB) ? 13 : 15], v);
}

__global__ void k_final(const u16* __restrict__ emb, const int* __restrict__ idx,
                        const float* __restrict__ W, const float* __restrict__ bias,
                        const float* __restrict__ lg, const float* __restrict__ lb,
                        float* __restrict__ outp){
  __shared__ float A[8][128];
  __shared__ float red[8][4];
  int j = threadIdx.x;
  int r0 = blockIdx.x*8;
  for (int r = 0; r < 8; ++r){
    int g = idx[r0 + r];
    A[r][j] = bf2f(emb[(long long)g*CD + j]);
  }
  __syncthreads();
  float acc[8];
  #pragma unroll
  for (int r = 0; r < 8; ++r) acc[r] = 0.f;
  for (int k = 0; k < 128; k += 4){
    float w0 = W[(k+0)*128 + j];
    float w1 = W[(k+1)*128 + j];
    float w2 = W[(k+2)*128 + j];
    float w3 = W[(k+3)*128 + j];
    #pragma unroll
    for (int r = 0; r < 8; ++r){
      float4 a = *(const float4*)&A[r][k];
      acc[r] += a.x*w0 + a.y*w1 + a.z*w2 + a.w*w3;
    }
  }
  float bb = bias[j];
  #pragma unroll
  for (int r = 0; r < 8; ++r){
    float v = acc[r] + bb;
    acc[r] = (v < 0.f) ? 0.f : v;
  }
  int wid = j >> 6, lane = j & 63;
  #pragma unroll
  for (int r = 0; r < 8; ++r){
    float s = acc[r], q = acc[r]*acc[r];
    for (int off = 32; off > 0; off >>= 1){
      s += __shfl_down(s, off); q += __shfl_down(q, off);
    }
    if (lane == 0){ red[r][wid*2] = s; red[r][wid*2+1] = q; }
  }
  __syncthreads();
  float gg = lg[j], be = lb[j];
  #pragma unroll
  for (int r = 0; r < 8; ++r){
    float mu = (red[r][0] + red[r][2]) * (1.0f/128.0f);
    float ms = (red[r][1] + red[r][3]) * (1.0f/128.0f);
    float var = ms - mu*mu;
    float y = (acc[r] - mu) * rsqrtf(var + 1e-5f) * gg + be;
    outp[(long long)(r0 + r)*CD + j] = y;
  }
}

__global__ void k_loss(const float* __restrict__ misc, float* __restrict__ o){
  float lu = (misc[13] - misc[12]) * (1.0f/CB);
  float li = (misc[15] - misc[14]) * (1.0f/CB);
  o[0] = 0.4f*(lu + li);
}

extern "C" void kernel_launch(void* const* d_in, const int* in_sizes, int n_in,
                              void* d_out, int out_size, void* d_ws, size_t ws_size,
                              hipStream_t stream){
  (void)in_sizes; (void)n_in; (void)out_size; (void)ws_size;
  const float* feat_user = (const float*)d_in[0];
  const float* feat_item = (const float*)d_in[1];
  const float* u_W1 = (const float*)d_in[2];
  const float* u_b1 = (const float*)d_in[3];
  const float* u_W2 = (const float*)d_in[4];
  const float* i_W1 = (const float*)d_in[5];
  const float* i_b1 = (const float*)d_in[6];
  const float* i_W2 = (const float*)d_in[7];
  const float* user_W = (const float*)d_in[8];
  const float* user_b = (const float*)d_in[9];
  const float* item_W = (const float*)d_in[10];
  const float* item_b = (const float*)d_in[11];
  const float* ln_g = (const float*)d_in[12];
  const float* ln_b = (const float*)d_in[13];
  const int* ump0s = (const int*)d_in[14]; const int* ump0d = (const int*)d_in[15];
  const int* ump1s = (const int*)d_in[16]; const int* ump1d = (const int*)d_in[17];
  const int* imp0s = (const int*)d_in[18]; const int* imp0d = (const int*)d_in[19];
  const int* imp1s = (const int*)d_in[20]; const int* imp1d = (const int*)d_in[21];
  const int* ui_row = (const int*)d_in[22]; const int* ui_col = (const int*)d_in[23];
  const int* user_idx = (const int*)d_in[24]; const int* item_idx = (const int*)d_in[25];
  const int* neg_idx = (const int*)d_in[26];

  u16* W  = (u16*)d_ws;
  u16* fb = W;                      // 10,240,000 bf16
  u16* hu = W + 10240000LL;
  u16* hi = W + 15360000LL;
  u16* xb = W + 20480000LL;
  u16* x2 = W + 30720000LL;
  u16* z0 = W + 40960000LL;
  u16* z1 = W + 46080000LL;
  float* F   = (float*)(W + 51200000LL);
  float* rs  = F;                   // 320,000
  float* dinv= F + 320000;          // 80,000
  float* alls= F + 400000;          // 16,384
  float* misc= F + 416384;          // 64
  int* I     = (int*)(F + 416448);
  int* mp_p0 = I;                   // 40,001
  int* mp_p1 = I + 40001;           // 40,001
  int* gcur  = I + 80002;           // 320  (bucket cursors/counts)
  int* bbase = I + 80322;           // 320  (bucket exclusive-scan bases)
  int* mp_c0 = I + 120002;          // 640,000
  int* mp_c1 = I + 760002;          // 640,000
  u16* w1tu  = (u16*)(I + 1400128); // 16,384 bf16 (W1^T user)
  u16* w1ti  = w1tu + 16384;        // 16,384 bf16 (W1^T item)
  int* ui_ptr    = (int*)hu;        // overlay (hu/hi dead until first combine)
  int* ui_csr    = ui_ptr + 160001; // 1,600,000 ints
  u32* gpairs    = (u32*)z0;        // overlay: bucket pairs, 313*8064*4B = 10.1MB (z0 dead during builds)
  u16* n1ub = xb;                   // overlay (xb dead after UI hop 3)
  u16* n2ub = xb + (long long)CB*CD;
  u16* n1ib = xb + 2LL*CB*CD;
  u16* n2ib = xb + 3LL*CB*CD;
  float* out = (float*)d_out;

  k_zero<<<(400000 + 255)/256, 256, 0, stream>>>(rs, 400000);
  k_zero<<<(16448 + 255)/256, 256, 0, stream>>>(alls, 16448);

  k_initb<<<40000, 256, 0, stream>>>(feat_user, feat_item, fb);
  k_w1t<<<64, 256, 0, stream>>>(u_W1, i_W1, w1tu, w1ti);

  k_deg<<<2500, 256, 0, stream>>>(ump0s, ump0d, rs + 0,      rs + 40000,  CEMP);
  k_deg<<<2500, 256, 0, stream>>>(ump1s, ump1d, rs + 80000,  rs + 120000, CEMP);
  k_deg<<<2500, 256, 0, stream>>>(imp0s, imp0d, rs + 160000, rs + 200000, CEMP);
  k_deg<<<2500, 256, 0, stream>>>(imp1s, imp1d, rs + 240000, rs + 280000, CEMP);
  k_rs<<<1250, 256, 0, stream>>>(rs, 320000);
  k_degui<<<6250, 256, 0, stream>>>(ui_row, dinv, CEUI);
  k_dinv<<<(CNN + 255)/256, 256, 0, stream>>>(dinv, CNN);

  // UI CSR build (counting sort; NB=313 buckets of 256 dst)
  k_izero<<<2, 256, 0, stream>>>(gcur, 320);
  k_bucket1<<<(CEUI + P1_CHUNK - 1)/P1_CHUNK, 256, 0, stream>>>(ui_col, ui_row, gcur, gpairs, CEUI, 313);
  k_scanb<<<1, 512, 0, stream>>>(gcur, bbase, 313);
  k_bucket2<<<313, 256, 0, stream>>>(gpairs, gcur, bbase, ui_csr, ui_ptr, CNN);

  // UI propagation: fb -> x2 -> xb -> x2
  k_gather_ui<<<20000, 256, 0, stream>>>(fb, ui_ptr, ui_csr, dinv, x2, CNN);
  k_gather_ui<<<20000, 256, 0, stream>>>(x2, ui_ptr, ui_csr, dinv, xb, CNN);
  k_gather_ui<<<20000, 256, 0, stream>>>(xb, ui_ptr, ui_csr, dinv, x2, CNN);

  // HAN user CSRs (NB=157)
  k_izero<<<2, 256, 0, stream>>>(gcur, 320);
  k_bucket1<<<(CEMP + P1_CHUNK - 1)/P1_CHUNK, 256, 0, stream>>>(ump0s, ump0d, gcur, gpairs, CEMP, 157);
  k_scanb<<<1, 512, 0, stream>>>(gcur, bbase, 157);
  k_bucket2<<<157, 256, 0, stream>>>(gpairs, gcur, bbase, mp_c0, mp_p0, CNU);
  k_izero<<<2, 256, 0, stream>>>(gcur, 320);
  k_bucket1<<<(CEMP + P1_CHUNK - 1)/P1_CHUNK, 256, 0, stream>>>(ump1s, ump1d, gcur, gpairs, CEMP, 157);
  k_scanb<<<1, 512, 0, stream>>>(gcur, bbase, 157);
  k_bucket2<<<157, 256, 0, stream>>>(gpairs, gcur, bbase, mp_c1, mp_p1, CNU);
  for (int L = 0; L < 3; ++L){
    const u16* hin = (L == 0) ? fb : hu;
    k_gather_mp<<<10000, 256, 0, stream>>>(hin, mp_p0, mp_c0, rs + 0,     z0, CNU);
    k_gather_mp<<<10000, 256, 0, stream>>>(hin, mp_p1, mp_c1, rs + 80000, z1, CNU);
    k_att<<<1250, 256, 0, stream>>>(z0, z1, rs + 40000, rs + 120000,
                                    w1tu, u_b1, u_W2, misc + 2*L, CNU);
    k_combine<<<20000, 256, 0, stream>>>(z0, z1, rs + 40000, rs + 120000,
                                         misc + 2*L, hu, CNU);
  }
  // HAN item CSRs (z0/z1 dead between loops -> gpairs overlay safe)
  k_izero<<<2, 256, 0, stream>>>(gcur, 320);
  k_bucket1<<<(CEMP + P1_CHUNK - 1)/P1_CHUNK, 256, 0, stream>>>(imp0s, imp0d, gcur, gpairs, CEMP, 157);
  k_scanb<<<1, 512, 0, stream>>>(gcur, bbase, 157);
  k_bucket2<<<157, 256, 0, stream>>>(gpairs, gcur, bbase, mp_c0, mp_p0, CNU);
  k_izero<<<2, 256, 0, stream>>>(gcur, 320);
  k_bucket1<<<(CEMP + P1_CHUNK - 1)/P1_CHUNK, 256, 0, stream>>>(imp1s, imp1d, gcur, gpairs, CEMP, 157);
  k_scanb<<<1, 512, 0, stream>>>(gcur, bbase, 157);
  k_bucket2<<<157, 256, 0, stream>>>(gpairs, gcur, bbase, mp_c1, mp_p1, CNU);
  for (int L = 0; L < 3; ++L){
    const u16* hin = (L == 0) ? (fb + (long long)CNU*CD) : hi;
    k_gather_mp<<<10000, 256, 0, stream>>>(hin, mp_p0, mp_c0, rs + 160000, z0, CNU);
    k_gather_mp<<<10000, 256, 0, stream>>>(hin, mp_p1, mp_c1, rs + 240000, z1, CNU);
    k_att<<<1250, 256, 0, stream>>>(z0, z1, rs + 200000, rs + 280000,
                                    w1ti, i_b1, i_W2, misc + 6 + 2*L, CNU);
    k_combine<<<20000, 256, 0, stream>>>(z0, z1, rs + 200000, rs + 280000,
                                         misc + 6 + 2*L, hi, CNU);
  }

  k_emb<<<40000, 256, 0, stream>>>(x2, hu, hi);

  // SSL
  k_sslnorm<<<CB/16, 256, 0, stream>>>(x2, hu, user_idx, 0,   n1ub, n2ub, misc + 12);
  k_sslnorm<<<CB/16, 256, 0, stream>>>(x2, hi, item_idx, CNU, n1ib, n2ib, misc + 14);
  k_alls<<<dim3(32, 16), 256, 0, stream>>>(n1ub, n2ub, alls);
  k_alls<<<dim3(32, 16), 256, 0, stream>>>(n1ib, n2ib, alls + CB);
  k_logsum<<<64, 256, 0, stream>>>(alls, misc);

  k_final<<<1024, 128, 0, stream>>>(hu, user_idx, user_W, user_b, ln_g, ln_b, out);
  k_final<<<1024, 128, 0, stream>>>(hi, item_idx, item_W, item_b, ln_g, ln_b, out + (long long)CB*CD);
  k_final<<<1024, 128, 0, stream>>>(hi, neg_idx,  item_W, item_b, ln_g, ln_b, out + 2LL*CB*CD);
  k_loss<<<1, 1, 0, stream>>>(misc, out + 3LL*CB*CD);
}

// Round 4
// 1270.114 us; speedup vs baseline: 1.9872x; 1.2356x over previous
//
#include <hip/hip_runtime.h>
#include <math.h>

typedef unsigned short u16;
typedef unsigned int u32;
typedef unsigned char u8;
typedef __attribute__((ext_vector_type(8))) short bf16x8;
typedef __attribute__((ext_vector_type(4))) float f32x4;

#define CNU 40000
#define CNN 80000
#define CD  128
#define CEMP 640000
#define CEUI 1600000
#define CB  8192

#define BK_CAP 8064     // per-bucket capacity (mean 5120 UI / 4096 MP; >40 sigma margin)
#define P1_CHUNK 4096   // edges per block in bucket pass 1 (16/thread)

__device__ __forceinline__ float bf2f(u16 b){
  union { u32 u; float f; } v; v.u = ((u32)b) << 16; return v.f;
}
__device__ __forceinline__ u16 f2bf(float f){
  union { float f; u32 u; } v; v.f = f;
  u32 u = v.u + 0x7FFFu + ((v.u >> 16) & 1u);
  return (u16)(u >> 16);
}
__device__ __forceinline__ float lo16f(u32 q){ union { u32 u; float f; } v; v.u = q << 16; return v.f; }
__device__ __forceinline__ float hi16f(u32 q){ union { u32 u; float f; } v; v.u = q & 0xFFFF0000u; return v.f; }

__global__ void k_zero(float* __restrict__ p, long long n){
  long long i = (long long)blockIdx.x*256 + threadIdx.x;
  if (i < n) p[i] = 0.f;
}

__global__ void k_izero(int* __restrict__ p, int n){
  int i = blockIdx.x*256 + threadIdx.x;
  if (i < n) p[i] = 0;
}

__global__ void k_initb(const float* __restrict__ fu, const float* __restrict__ fi,
                        u16* __restrict__ fb){
  int idx = blockIdx.x*256 + threadIdx.x;
  if (idx >= CNN*CD) return;
  float v = (idx < CNU*CD) ? fu[idx] : fi[idx - CNU*CD];
  fb[idx] = f2bf(v);
}

// transpose W1 (f32 [k][j]) -> bf16 [j][k] for MFMA B-operand loads
__global__ void k_w1t(const float* __restrict__ Wu, const float* __restrict__ Wi,
                      u16* __restrict__ Wut, u16* __restrict__ Wit){
  int idx = blockIdx.x*256 + threadIdx.x;
  if (idx >= 16384) return;
  int k = idx >> 7, j = idx & 127;
  Wut[j*128 + k] = f2bf(Wu[idx]);
  Wit[j*128 + k] = f2bf(Wi[idx]);
}

// ---- CSR build via LDS-aggregated counting sort ----
// Pass 1 (UI variant): dst-keyed pair scatter only.
__global__ void k_bucket1(const int* __restrict__ src, const int* __restrict__ dst,
                          int* __restrict__ gcur, u32* __restrict__ gpairs,
                          int E, int NB){
  __shared__ int cnt[320];
  __shared__ int sbase[320];
  int t = threadIdx.x;
  for (int i = t; i < NB; i += 256) cnt[i] = 0;
  __syncthreads();
  int base = blockIdx.x * P1_CHUNK;
  int r[16], dv[16], sv[16];
  #pragma unroll
  for (int u = 0; u < 16; ++u){
    int e = base + u*256 + t;
    bool ok = (e < E);
    dv[u] = ok ? dst[e] : -1;
    sv[u] = ok ? src[e] : 0;
    if (ok) r[u] = atomicAdd(&cnt[dv[u] >> 8], 1);
  }
  __syncthreads();
  for (int i = t; i < NB; i += 256){
    int c = cnt[i];
    sbase[i] = c ? atomicAdd(&gcur[i], c) : 0;
  }
  __syncthreads();
  #pragma unroll
  for (int u = 0; u < 16; ++u){
    if (dv[u] >= 0){
      int b = dv[u] >> 8;
      int p = sbase[b] + r[u];
      if (p < BK_CAP)
        gpairs[(long long)b*BK_CAP + p] = (u32)sv[u] | ((u32)(dv[u] & 255) << 18);
    }
  }
}

// Pass 1 (MP variant): dst-keyed pair scatter + src-keyed byte scatter (for out-degree).
__global__ void k_bucket1b(const int* __restrict__ src, const int* __restrict__ dst,
                           int* __restrict__ gcur, u32* __restrict__ gpairs,
                           int* __restrict__ gcur2, u8* __restrict__ gbytes,
                           int E, int NB){
  __shared__ int cnt[320], sbase[320], cnt2[320], sbase2[320];
  int t = threadIdx.x;
  for (int i = t; i < NB; i += 256){ cnt[i] = 0; cnt2[i] = 0; }
  __syncthreads();
  int base = blockIdx.x * P1_CHUNK;
  int r[16], r2[16], dv[16], sv[16];
  #pragma unroll
  for (int u = 0; u < 16; ++u){
    int e = base + u*256 + t;
    bool ok = (e < E);
    dv[u] = ok ? dst[e] : -1;
    sv[u] = ok ? src[e] : -1;
    if (ok){
      r[u]  = atomicAdd(&cnt[dv[u] >> 8], 1);
      r2[u] = atomicAdd(&cnt2[sv[u] >> 8], 1);
    }
  }
  __syncthreads();
  for (int i = t; i < NB; i += 256){
    int c  = cnt[i];  sbase[i]  = c  ? atomicAdd(&gcur[i],  c)  : 0;
    int c2 = cnt2[i]; sbase2[i] = c2 ? atomicAdd(&gcur2[i], c2) : 0;
  }
  __syncthreads();
  #pragma unroll
  for (int u = 0; u < 16; ++u){
    if (dv[u] >= 0){
      int b = dv[u] >> 8;
      int p = sbase[b] + r[u];
      if (p < BK_CAP)
        gpairs[(long long)b*BK_CAP + p] = (u32)sv[u] | ((u32)(dv[u] & 255) << 18);
      int b2 = sv[u] >> 8;
      int p2 = sbase2[b2] + r2[u];
      if (p2 < BK_CAP)
        gbytes[(long long)b2*BK_CAP + p2] = (u8)(sv[u] & 255);
    }
  }
}

// exclusive scan of <=512 bucket counts (single block)
__global__ void k_scanb(const int* __restrict__ gcur, int* __restrict__ bbase, int NB){
  __shared__ int s[512];
  int t = threadIdx.x;
  int v = (t < NB) ? gcur[t] : 0;
  s[t] = v;
  __syncthreads();
  for (int off = 1; off < 512; off <<= 1){
    int u = (t >= off) ? s[t-off] : 0;
    __syncthreads();
    s[t] += u;
    __syncthreads();
  }
  if (t < NB) bbase[t] = s[t] - v;
}

// Pass 2: one block per bucket; LDS scatter then streaming CSR write + ptr slice.
// Also emits rs_ind[node] = h>0 ? rsqrt(h) : zval  (in-degree rsqrt, free from LDS hist).
__global__ void k_bucket2(const u32* __restrict__ gpairs, const int* __restrict__ gcur,
                          const int* __restrict__ bbase, int* __restrict__ csr,
                          int* __restrict__ ptr, int n,
                          float* __restrict__ rs_ind, float zval){
  __shared__ int hist[256];
  __shared__ int excl[256];
  __shared__ int lptr[256];
  __shared__ int lsrc[BK_CAP];
  int b = blockIdx.x, t = threadIdx.x;
  int cnt = gcur[b]; if (cnt > BK_CAP) cnt = BK_CAP;
  int base = bbase[b];
  hist[t] = 0;
  __syncthreads();
  const u32* pp = gpairs + (long long)b*BK_CAP;
  for (int i = t; i < cnt; i += 256) atomicAdd(&hist[(pp[i] >> 18) & 255], 1);
  __syncthreads();
  int h = hist[t];
  lptr[t] = h;
  __syncthreads();
  for (int off = 1; off < 256; off <<= 1){
    int u2 = (t >= off) ? lptr[t-off] : 0;
    __syncthreads();
    lptr[t] += u2;
    __syncthreads();
  }
  excl[t] = lptr[t] - h;
  __syncthreads();
  hist[t] = excl[t];           // reuse hist as running cursor
  __syncthreads();
  for (int i = t; i < cnt; i += 256){
    u32 v = pp[i];
    int d = (v >> 18) & 255;
    int p = atomicAdd(&hist[d], 1);
    lsrc[p] = (int)(v & 0x3FFFFu);
  }
  __syncthreads();
  for (int i = t; i < cnt; i += 256) csr[base + i] = lsrc[i];
  int dg = (b << 8) + t;
  if (dg <= n) ptr[dg] = base + excl[t];
  if (dg < n)  rs_ind[dg] = (h > 0) ? rsqrtf((float)h) : zval;
}

// Count-only pass 2 over src byte-buckets -> rsqrt(max(outdeg,1)).
__global__ void k_hist256(const u8* __restrict__ gbytes, const int* __restrict__ gcur2,
                          float* __restrict__ rs_out, int n){
  __shared__ int hist[256];
  int b = blockIdx.x, t = threadIdx.x;
  hist[t] = 0;
  __syncthreads();
  int cnt = gcur2[b]; if (cnt > BK_CAP) cnt = BK_CAP;
  const u8* pp = gbytes + (long long)b*BK_CAP;
  for (int i = t; i < cnt; i += 256) atomicAdd(&hist[pp[i]], 1);
  __syncthreads();
  int dg = (b << 8) + t;
  if (dg < n){
    int h = hist[t];
    rs_out[dg] = (h > 0) ? rsqrtf((float)h) : 1.0f;
  }
}

// ---- gather: 1 wave/row, lane=(g=edge-slot 0..3, c=16B-chunk 0..15) ----
__global__ void k_gather_mp(const u16* __restrict__ h, const int* __restrict__ ptr,
                            const int* __restrict__ csr_src, const float* __restrict__ rso,
                            u16* __restrict__ z, int n){
  int row = (blockIdx.x*256 + threadIdx.x) >> 6;
  if (row >= n) return;
  int lane = threadIdx.x & 63;
  int g = lane >> 4, c = lane & 15;
  int p = ptr[row], pe = ptr[row+1];
  float a0=0,a1=0,a2=0,a3=0,a4=0,a5=0,a6=0,a7=0;
  const u16* hb = h + (long long)c*8;
  while (p < pe){
    uint4 q[4]; float w[4];
    #pragma unroll
    for (int u = 0; u < 4; ++u){
      int ei = p + u*4 + g;
      int s  = (ei < pe) ? csr_src[ei] : 0;
      w[u]   = (ei < pe) ? rso[s] : 0.f;
      q[u]   = *(const uint4*)(hb + (long long)s*CD);
    }
    #pragma unroll
    for (int u = 0; u < 4; ++u){
      a0 += lo16f(q[u].x)*w[u]; a1 += hi16f(q[u].x)*w[u];
      a2 += lo16f(q[u].y)*w[u]; a3 += hi16f(q[u].y)*w[u];
      a4 += lo16f(q[u].z)*w[u]; a5 += hi16f(q[u].z)*w[u];
      a6 += lo16f(q[u].w)*w[u]; a7 += hi16f(q[u].w)*w[u];
    }
    p += 16;
  }
  #pragma unroll
  for (int m = 16; m <= 32; m <<= 1){
    a0 += __shfl_xor(a0, m); a1 += __shfl_xor(a1, m);
    a2 += __shfl_xor(a2, m); a3 += __shfl_xor(a3, m);
    a4 += __shfl_xor(a4, m); a5 += __shfl_xor(a5, m);
    a6 += __shfl_xor(a6, m); a7 += __shfl_xor(a7, m);
  }
  if (g == 0){
    uint4 o;
    o.x = (u32)f2bf(a0) | ((u32)f2bf(a1) << 16);
    o.y = (u32)f2bf(a2) | ((u32)f2bf(a3) << 16);
    o.z = (u32)f2bf(a4) | ((u32)f2bf(a5) << 16);
    o.w = (u32)f2bf(a6) | ((u32)f2bf(a7) << 16);
    *(uint4*)(z + (long long)row*CD + c*8) = o;
  }
}

__global__ void k_gather_ui(const u16* __restrict__ xin, const int* __restrict__ ptr,
                            const int* __restrict__ csr_src, const float* __restrict__ dinv,
                            u16* __restrict__ xout, int n){
  int row = (blockIdx.x*256 + threadIdx.x) >> 6;
  if (row >= n) return;
  int lane = threadIdx.x & 63;
  int g = lane >> 4, c = lane & 15;
  int p = ptr[row], pe = ptr[row+1];
  float a0=0,a1=0,a2=0,a3=0,a4=0,a5=0,a6=0,a7=0;
  const u16* hb = xin + (long long)c*8;
  while (p < pe){
    uint4 q[4]; float w[4];
    #pragma unroll
    for (int u = 0; u < 4; ++u){
      int ei = p + u*4 + g;
      int s  = (ei < pe) ? csr_src[ei] : 0;
      w[u]   = (ei < pe) ? dinv[s] : 0.f;
      q[u]   = *(const uint4*)(hb + (long long)s*CD);
    }
    #pragma unroll
    for (int u = 0; u < 4; ++u){
      a0 += lo16f(q[u].x)*w[u]; a1 += hi16f(q[u].x)*w[u];
      a2 += lo16f(q[u].y)*w[u]; a3 += hi16f(q[u].y)*w[u];
      a4 += lo16f(q[u].z)*w[u]; a5 += hi16f(q[u].z)*w[u];
      a6 += lo16f(q[u].w)*w[u]; a7 += hi16f(q[u].w)*w[u];
    }
    p += 16;
  }
  #pragma unroll
  for (int m = 16; m <= 32; m <<= 1){
    a0 += __shfl_xor(a0, m); a1 += __shfl_xor(a1, m);
    a2 += __shfl_xor(a2, m); a3 += __shfl_xor(a3, m);
    a4 += __shfl_xor(a4, m); a5 += __shfl_xor(a5, m);
    a6 += __shfl_xor(a6, m); a7 += __shfl_xor(a7, m);
  }
  if (g == 0){
    float wd = dinv[row];
    uint4 o;
    o.x = (u32)f2bf(a0*wd) | ((u32)f2bf(a1*wd) << 16);
    o.y = (u32)f2bf(a2*wd) | ((u32)f2bf(a3*wd) << 16);
    o.z = (u32)f2bf(a4*wd) | ((u32)f2bf(a5*wd) << 16);
    o.w = (u32)f2bf(a6*wd) | ((u32)f2bf(a7*wd) << 16);
    *(uint4*)(xout + (long long)row*CD + c*8) = o;
  }
}

// semantic attention scores via MFMA; block-level reduction -> 1 atomic/block
__global__ void k_att(const u16* __restrict__ z0, const u16* __restrict__ z1,
                      const float* __restrict__ rsi0, const float* __restrict__ rsi1,
                      const u16* __restrict__ W1T, const float* __restrict__ b1,
                      const float* __restrict__ W2, float* __restrict__ s_out, int n){
  __shared__ float wred[4];
  int nb = n >> 6;
  int blk = blockIdx.x;
  int ch = (blk >= nb) ? 1 : 0;
  int rb = (ch ? (blk - nb) : blk) * 64;
  const u16* z = ch ? z1 : z0;
  const float* rsi = ch ? rsi1 : rsi0;
  int wv = threadIdx.x >> 6, lane = threadIdx.x & 63;
  int i0 = rb + wv*16;
  int m = lane & 15, kq = lane >> 4;
  bf16x8 a[4];
  #pragma unroll
  for (int t = 0; t < 4; ++t){
    uint4 q = *(const uint4*)(z + (long long)(i0+m)*CD + t*32 + kq*8);
    a[t] = *(bf16x8*)&q;
  }
  float rsv[4];
  #pragma unroll
  for (int ri = 0; ri < 4; ++ri) rsv[ri] = rsi[i0 + kq*4 + ri];
  float psum = 0.f;
  #pragma unroll
  for (int jt = 0; jt < 8; ++jt){
    f32x4 acc = {0.f,0.f,0.f,0.f};
    #pragma unroll
    for (int t = 0; t < 4; ++t){
      uint4 qb = *(const uint4*)(W1T + (jt*16 + m)*CD + t*32 + kq*8);
      bf16x8 b = *(bf16x8*)&qb;
      acc = __builtin_amdgcn_mfma_f32_16x16x32_bf16(a[t], b, acc, 0, 0, 0);
    }
    int j = jt*16 + m;
    float bb = b1[j], w2 = W2[j];
    #pragma unroll
    for (int ri = 0; ri < 4; ++ri){
      float x = acc[ri]*rsv[ri] + bb;
      x = fminf(fmaxf(x, -15.f), 15.f);
      float t2 = __expf(2.f*x);
      psum += ((t2 - 1.f)/(t2 + 1.f))*w2;
    }
  }
  #pragma unroll
  for (int msk = 1; msk <= 32; msk <<= 1) psum += __shfl_xor(psum, msk);
  if (lane == 0) wred[wv] = psum;
  __syncthreads();
  if (threadIdx.x == 0)
    atomicAdd(&s_out[ch], wred[0] + wred[1] + wred[2] + wred[3]);
}

__global__ void k_combine(const u16* __restrict__ z0, const u16* __restrict__ z1,
                          const float* __restrict__ rsi0, const float* __restrict__ rsi1,
                          const float* __restrict__ s, u16* __restrict__ h, int n){
  int idx = blockIdx.x*256 + threadIdx.x;
  if (idx >= n*CD) return;
  int v = idx >> 7;
  float s0 = s[0]*(1.0f/n), s1 = s[1]*(1.0f/n);
  float m = fmaxf(s0, s1);
  float e0 = __expf(s0 - m), e1 = __expf(s1 - m);
  float r = 1.0f/(e0 + e1);
  h[idx] = f2bf((e0*r)*bf2f(z0[idx])*rsi0[v] + (e1*r)*bf2f(z1[idx])*rsi1[v]);
}

__global__ void k_emb(const u16* __restrict__ x2, u16* __restrict__ h_u,
                      u16* __restrict__ h_i){
  int idx = blockIdx.x*256 + threadIdx.x;
  if (idx >= CNN*CD) return;
  if (idx < CNU*CD) h_u[idx] = f2bf(0.5f*bf2f(h_u[idx]) + 0.5f*bf2f(x2[idx]));
  else { int k = idx - CNU*CD; h_i[k] = f2bf(0.5f*bf2f(h_i[k]) + 0.5f*bf2f(x2[idx])); }
}

// 4 rows/wave, 4 waves/block; u32 row loads; block-level pos reduction -> 1 atomic/block
__global__ void k_sslnorm(const u16* __restrict__ xui, const u16* __restrict__ hemb,
                          const int* __restrict__ idx, int rowoff,
                          u16* __restrict__ n1b, u16* __restrict__ n2b,
                          float* __restrict__ pos_acc){
  __shared__ float wred[4];
  int wv = threadIdx.x >> 6, lane = threadIdx.x & 63;
  int r0 = blockIdx.x*16 + wv*4;
  int g[4]; u32 q1[4], q2[4];
  #pragma unroll
  for (int u = 0; u < 4; ++u){
    g[u] = idx[r0 + u];
    q1[u] = *(const u32*)(xui + (long long)(g[u] + rowoff)*CD + lane*2);
    q2[u] = *(const u32*)(hemb + (long long)g[u]*CD + lane*2);
  }
  float psum = 0.f;
  #pragma unroll
  for (int u = 0; u < 4; ++u){
    float a0 = lo16f(q1[u]), a1 = hi16f(q1[u]);
    float b0 = lo16f(q2[u]), b1 = hi16f(q2[u]);
    float s1 = a0*a0 + a1*a1, s2 = b0*b0 + b1*b1, s12 = a0*b0 + a1*b1;
    #pragma unroll
    for (int msk = 1; msk <= 32; msk <<= 1){
      s1  += __shfl_xor(s1, msk);
      s2  += __shfl_xor(s2, msk);
      s12 += __shfl_xor(s12, msk);
    }
    float i1 = 1.0f / fmaxf(sqrtf(s1), 1e-12f);
    float i2 = 1.0f / fmaxf(sqrtf(s2), 1e-12f);
    *(u32*)(n1b + (long long)(r0+u)*CD + lane*2) = (u32)f2bf(a0*i1) | ((u32)f2bf(a1*i1) << 16);
    *(u32*)(n2b + (long long)(r0+u)*CD + lane*2) = (u32)f2bf(b0*i2) | ((u32)f2bf(b1*i2) << 16);
    psum += s12*i1*i2*2.0f;
  }
  if (lane == 0) wred[wv] = psum;
  __syncthreads();
  if (threadIdx.x == 0)
    atomicAdd(pos_acc, wred[0] + wred[1] + wred[2] + wred[3]);
}

// alls[i] += sum_j exp(2 * n1_i . n2_j) via MFMA; register-blocked 4 i-tiles/wave.
__global__ void k_alls(const u16* __restrict__ n1b, const u16* __restrict__ n2b,
                       float* __restrict__ alls){
  int wv = threadIdx.x >> 6;
  int lane = threadIdx.x & 63;
  int m = lane & 15, kq = lane >> 4;
  int i0 = (blockIdx.x*4 + wv)*64;
  bf16x8 a[4][4];
  #pragma unroll
  for (int c = 0; c < 4; ++c){
    #pragma unroll
    for (int t = 0; t < 4; ++t){
      uint4 q = *(const uint4*)(n1b + (long long)(i0 + c*16 + m)*CD + t*32 + kq*8);
      a[c][t] = *(bf16x8*)&q;
    }
  }
  float es[4][4];
  #pragma unroll
  for (int c = 0; c < 4; ++c)
    #pragma unroll
    for (int ri = 0; ri < 4; ++ri) es[c][ri] = 0.f;

  const u16* jb = n2b + (long long)(blockIdx.y*512 + m)*CD + kq*8;
  uint4 q[4];
  #pragma unroll
  for (int t = 0; t < 4; ++t) q[t] = *(const uint4*)(jb + t*32);
  for (int jt = 0; jt < 32; ++jt){
    uint4 qn[4];
    if (jt < 31){
      const u16* jb2 = jb + (long long)(jt+1)*16*CD;
      #pragma unroll
      for (int t = 0; t < 4; ++t) qn[t] = *(const uint4*)(jb2 + t*32);
    }
    f32x4 ac[4];
    #pragma unroll
    for (int c = 0; c < 4; ++c) ac[c] = (f32x4){0.f,0.f,0.f,0.f};
    #pragma unroll
    for (int t = 0; t < 4; ++t){
      bf16x8 b = *(bf16x8*)&q[t];
      #pragma unroll
      for (int c = 0; c < 4; ++c)
        ac[c] = __builtin_amdgcn_mfma_f32_16x16x32_bf16(a[c][t], b, ac[c], 0, 0, 0);
    }
    #pragma unroll
    for (int c = 0; c < 4; ++c)
      #pragma unroll
      for (int ri = 0; ri < 4; ++ri)
        es[c][ri] += __expf(ac[c][ri]*2.f);
    if (jt < 31){
      #pragma unroll
      for (int t = 0; t < 4; ++t) q[t] = qn[t];
    }
  }
  #pragma unroll
  for (int c = 0; c < 4; ++c){
    #pragma unroll
    for (int ri = 0; ri < 4; ++ri){
      float v = es[c][ri];
      #pragma unroll
      for (int msk = 1; msk <= 8; msk <<= 1) v += __shfl_xor(v, msk);
      if (m == 0) atomicAdd(&alls[i0 + c*16 + kq*4 + ri], v);
    }
  }
}

__global__ void k_logsum(const float* __restrict__ alls, float* __restrict__ misc){
  int i = blockIdx.x*256 + threadIdx.x;
  float v = logf(alls[i]);
  for (int off = 32; off > 0; off >>= 1) v += __shfl_down(v, off);
  if ((threadIdx.x & 63) == 0) atomicAdd(&misc[(i < CB) ? 13 : 15], v);
}

__global__ void k_final(const u16* __restrict__ emb, const int* __restrict__ idx,
                        const float* __restrict__ W, const float* __restrict__ bias,
                        const float* __restrict__ lg, const float* __restrict__ lb,
                        float* __restrict__ outp){
  __shared__ float A[8][128];
  __shared__ float red[8][4];
  int j = threadIdx.x;
  int r0 = blockIdx.x*8;
  for (int r = 0; r < 8; ++r){
    int g = idx[r0 + r];
    A[r][j] = bf2f(emb[(long long)g*CD + j]);
  }
  __syncthreads();
  float acc[8];
  #pragma unroll
  for (int r = 0; r < 8; ++r) acc[r] = 0.f;
  for (int k = 0; k < 128; k += 4){
    float w0 = W[(k+0)*128 + j];
    float w1 = W[(k+1)*128 + j];
    float w2 = W[(k+2)*128 + j];
    float w3 = W[(k+3)*128 + j];
    #pragma unroll
    for (int r = 0; r < 8; ++r){
      float4 a = *(const float4*)&A[r][k];
      acc[r] += a.x*w0 + a.y*w1 + a.z*w2 + a.w*w3;
    }
  }
  float bb = bias[j];
  #pragma unroll
  for (int r = 0; r < 8; ++r){
    float v = acc[r] + bb;
    acc[r] = (v < 0.f) ? 0.f : v;
  }
  int wid = j >> 6, lane = j & 63;
  #pragma unroll
  for (int r = 0; r < 8; ++r){
    float s = acc[r], q = acc[r]*acc[r];
    for (int off = 32; off > 0; off >>= 1){
      s += __shfl_down(s, off); q += __shfl_down(q, off);
    }
    if (lane == 0){ red[r][wid*2] = s; red[r][wid*2+1] = q; }
  }
  __syncthreads();
  float gg = lg[j], be = lb[j];
  #pragma unroll
  for (int r = 0; r < 8; ++r){
    float mu = (red[r][0] + red[r][2]) * (1.0f/128.0f);
    float ms = (red[r][1] + red[r][3]) * (1.0f/128.0f);
    float var = ms - mu*mu;
    float y = (acc[r] - mu) * rsqrtf(var + 1e-5f) * gg + be;
    outp[(long long)(r0 + r)*CD + j] = y;
  }
}

__global__ void k_loss(const float* __restrict__ misc, float* __restrict__ o){
  float lu = (misc[13] - misc[12]) * (1.0f/CB);
  float li = (misc[15] - misc[14]) * (1.0f/CB);
  o[0] = 0.4f*(lu + li);
}

extern "C" void kernel_launch(void* const* d_in, const int* in_sizes, int n_in,
                              void* d_out, int out_size, void* d_ws, size_t ws_size,
                              hipStream_t stream){
  (void)in_sizes; (void)n_in; (void)out_size; (void)ws_size;
  const float* feat_user = (const float*)d_in[0];
  const float* feat_item = (const float*)d_in[1];
  const float* u_W1 = (const float*)d_in[2];
  const float* u_b1 = (const float*)d_in[3];
  const float* u_W2 = (const float*)d_in[4];
  const float* i_W1 = (const float*)d_in[5];
  const float* i_b1 = (const float*)d_in[6];
  const float* i_W2 = (const float*)d_in[7];
  const float* user_W = (const float*)d_in[8];
  const float* user_b = (const float*)d_in[9];
  const float* item_W = (const float*)d_in[10];
  const float* item_b = (const float*)d_in[11];
  const float* ln_g = (const float*)d_in[12];
  const float* ln_b = (const float*)d_in[13];
  const int* ump0s = (const int*)d_in[14]; const int* ump0d = (const int*)d_in[15];
  const int* ump1s = (const int*)d_in[16]; const int* ump1d = (const int*)d_in[17];
  const int* imp0s = (const int*)d_in[18]; const int* imp0d = (const int*)d_in[19];
  const int* imp1s = (const int*)d_in[20]; const int* imp1d = (const int*)d_in[21];
  const int* ui_row = (const int*)d_in[22]; const int* ui_col = (const int*)d_in[23];
  const int* user_idx = (const int*)d_in[24]; const int* item_idx = (const int*)d_in[25];
  const int* neg_idx = (const int*)d_in[26];

  u16* W  = (u16*)d_ws;
  u16* fb = W;                      // 10,240,000 bf16
  u16* hu = W + 10240000LL;
  u16* hi = W + 15360000LL;
  u16* xb = W + 20480000LL;
  u16* x2 = W + 30720000LL;
  u16* z0 = W + 40960000LL;
  u16* z1 = W + 46080000LL;
  float* F   = (float*)(W + 51200000LL);
  float* rs  = F;                   // 320,000 (4x outdeg rsqrt + 4x indeg rsqrt)
  float* dinv= F + 320000;          // 80,000
  float* alls= F + 400000;          // 16,384
  float* misc= F + 416384;          // 64
  int* I     = (int*)(F + 416448);
  int* mp_p0 = I;                   // 40,001
  int* mp_p1 = I + 40001;           // 40,001
  int* gcur  = I + 80002;           // 320  (dst bucket cursors)
  int* bbase = I + 80322;           // 320  (dst bucket scan bases)
  int* gcur2 = I + 80642;           // 320  (src byte-bucket cursors)
  int* mp_c0 = I + 120002;          // 640,000
  int* mp_c1 = I + 760002;          // 640,000
  u16* w1tu  = (u16*)(I + 1400128); // 16,384 bf16 (W1^T user)
  u16* w1ti  = w1tu + 16384;        // 16,384 bf16 (W1^T item)
  int* ui_ptr    = (int*)hu;        // overlay (hu/hi dead until first combine)
  int* ui_csr    = ui_ptr + 160001; // 1,600,000 ints
  u32* gpairs    = (u32*)z0;        // overlay: 313*8064*4B = 10.1MB (z0 dead during builds)
  u8*  gbytes    = (u8*)z1;         // overlay: 157*8064 B = 1.27MB (z1 dead during builds)
  u16* n1ub = xb;                   // overlay (xb dead after UI hop 3)
  u16* n2ub = xb + (long long)CB*CD;
  u16* n1ib = xb + 2LL*CB*CD;
  u16* n2ib = xb + 3LL*CB*CD;
  float* out = (float*)d_out;

  k_zero<<<(16448 + 255)/256, 256, 0, stream>>>(alls, 16448);

  k_initb<<<40000, 256, 0, stream>>>(feat_user, feat_item, fb);
  k_w1t<<<64, 256, 0, stream>>>(u_W1, i_W1, w1tu, w1ti);

  // UI CSR build (counting sort; NB=313 buckets of 256 dst); dinv emitted by pass 2.
  k_izero<<<4, 256, 0, stream>>>(gcur, 960);
  k_bucket1<<<(CEUI + P1_CHUNK - 1)/P1_CHUNK, 256, 0, stream>>>(ui_col, ui_row, gcur, gpairs, CEUI, 313);
  k_scanb<<<1, 512, 0, stream>>>(gcur, bbase, 313);
  k_bucket2<<<313, 256, 0, stream>>>(gpairs, gcur, bbase, ui_csr, ui_ptr, CNN, dinv, 0.0f);

  // UI propagation: fb -> x2 -> xb -> x2
  k_gather_ui<<<20000, 256, 0, stream>>>(fb, ui_ptr, ui_csr, dinv, x2, CNN);
  k_gather_ui<<<20000, 256, 0, stream>>>(x2, ui_ptr, ui_csr, dinv, xb, CNN);
  k_gather_ui<<<20000, 256, 0, stream>>>(xb, ui_ptr, ui_csr, dinv, x2, CNN);

  // HAN user CSRs (NB=157); indeg rsqrt from pass 2, outdeg rsqrt from byte hist.
  k_izero<<<4, 256, 0, stream>>>(gcur, 960);
  k_bucket1b<<<(CEMP + P1_CHUNK - 1)/P1_CHUNK, 256, 0, stream>>>(ump0s, ump0d, gcur, gpairs, gcur2, gbytes, CEMP, 157);
  k_scanb<<<1, 512, 0, stream>>>(gcur, bbase, 157);
  k_bucket2<<<157, 256, 0, stream>>>(gpairs, gcur, bbase, mp_c0, mp_p0, CNU, rs + 40000, 1.0f);
  k_hist256<<<157, 256, 0, stream>>>(gbytes, gcur2, rs + 0, CNU);
  k_izero<<<4, 256, 0, stream>>>(gcur, 960);
  k_bucket1b<<<(CEMP + P1_CHUNK - 1)/P1_CHUNK, 256, 0, stream>>>(ump1s, ump1d, gcur, gpairs, gcur2, gbytes, CEMP, 157);
  k_scanb<<<1, 512, 0, stream>>>(gcur, bbase, 157);
  k_bucket2<<<157, 256, 0, stream>>>(gpairs, gcur, bbase, mp_c1, mp_p1, CNU, rs + 120000, 1.0f);
  k_hist256<<<157, 256, 0, stream>>>(gbytes, gcur2, rs + 80000, CNU);
  for (int L = 0; L < 3; ++L){
    const u16* hin = (L == 0) ? fb : hu;
    k_gather_mp<<<10000, 256, 0, stream>>>(hin, mp_p0, mp_c0, rs + 0,     z0, CNU);
    k_gather_mp<<<10000, 256, 0, stream>>>(hin, mp_p1, mp_c1, rs + 80000, z1, CNU);
    k_att<<<1250, 256, 0, stream>>>(z0, z1, rs + 40000, rs + 120000,
                                    w1tu, u_b1, u_W2, misc + 2*L, CNU);
    k_combine<<<20000, 256, 0, stream>>>(z0, z1, rs + 40000, rs + 120000,
                                         misc + 2*L, hu, CNU);
  }
  // HAN item CSRs (z0/z1 dead between loops -> overlays safe)
  k_izero<<<4, 256, 0, stream>>>(gcur, 960);
  k_bucket1b<<<(CEMP + P1_CHUNK - 1)/P1_CHUNK, 256, 0, stream>>>(imp0s, imp0d, gcur, gpairs, gcur2, gbytes, CEMP, 157);
  k_scanb<<<1, 512, 0, stream>>>(gcur, bbase, 157);
  k_bucket2<<<157, 256, 0, stream>>>(gpairs, gcur, bbase, mp_c0, mp_p0, CNU, rs + 200000, 1.0f);
  k_hist256<<<157, 256, 0, stream>>>(gbytes, gcur2, rs + 160000, CNU);
  k_izero<<<4, 256, 0, stream>>>(gcur, 960);
  k_bucket1b<<<(CEMP + P1_CHUNK - 1)/P1_CHUNK, 256, 0, stream>>>(imp1s, imp1d, gcur, gpairs, gcur2, gbytes, CEMP, 157);
  k_scanb<<<1, 512, 0, stream>>>(gcur, bbase, 157);
  k_bucket2<<<157, 256, 0, stream>>>(gpairs, gcur, bbase, mp_c1, mp_p1, CNU, rs + 280000, 1.0f);
  k_hist256<<<157, 256, 0, stream>>>(gbytes, gcur2, rs + 240000, CNU);
  for (int L = 0; L < 3; ++L){
    const u16* hin = (L == 0) ? (fb + (long long)CNU*CD) : hi;
    k_gather_mp<<<10000, 256, 0, stream>>>(hin, mp_p0, mp_c0, rs + 160000, z0, CNU);
    k_gather_mp<<<10000, 256, 0, stream>>>(hin, mp_p1, mp_c1, rs + 240000, z1, CNU);
    k_att<<<1250, 256, 0, stream>>>(z0, z1, rs + 200000, rs + 280000,
                                    w1ti, i_b1, i_W2, misc + 6 + 2*L, CNU);
    k_combine<<<20000, 256, 0, stream>>>(z0, z1, rs + 200000, rs + 280000,
                                         misc + 6 + 2*L, hi, CNU);
  }

  k_emb<<<40000, 256, 0, stream>>>(x2, hu, hi);

  // SSL
  k_sslnorm<<<CB/16, 256, 0, stream>>>(x2, hu, user_idx, 0,   n1ub, n2ub, misc + 12);
  k_sslnorm<<<CB/16, 256, 0, stream>>>(x2, hi, item_idx, CNU, n1ib, n2ib, misc + 14);
  k_alls<<<dim3(32, 16), 256, 0, stream>>>(n1ub, n2ub, alls);
  k_alls<<<dim3(32, 16), 256, 0, stream>>>(n1ib, n2ib, alls + CB);
  k_logsum<<<64, 256, 0, stream>>>(alls, misc);

  k_final<<<1024, 128, 0, stream>>>(hu, user_idx, user_W, user_b, ln_g, ln_b, out);
  k_final<<<1024, 128, 0, stream>>>(hi, item_idx, item_W, item_b, ln_g, ln_b, out + (long long)CB*CD);
  k_final<<<1024, 128, 0, stream>>>(hi, neg_idx,  item_W, item_b, ln_g, ln_b, out + 2LL*CB*CD);
  k_loss<<<1, 1, 0, stream>>>(misc, out + 3LL*CB*CD);
}

// Round 6
// 1243.789 us; speedup vs baseline: 2.0293x; 1.0212x over previous
//
#include <hip/hip_runtime.h>
#include <math.h>

typedef unsigned short u16;
typedef unsigned int u32;
typedef unsigned char u8;
typedef __attribute__((ext_vector_type(8))) short bf16x8;
typedef __attribute__((ext_vector_type(4))) float f32x4;

#define CNU 40000
#define CNN 80000
#define CD  128
#define CEMP 640000
#define CEUI 1600000
#define CB  8192

#define BK_CAP 8064     // per-bucket capacity (mean 5120 UI / 4096 MP; >40 sigma margin)
#define P1_CHUNK 4096   // edges per block in bucket pass 1 (16/thread)

__device__ __forceinline__ float bf2f(u16 b){
  union { u32 u; float f; } v; v.u = ((u32)b) << 16; return v.f;
}
__device__ __forceinline__ u16 f2bf(float f){
  union { float f; u32 u; } v; v.f = f;
  u32 u = v.u + 0x7FFFu + ((v.u >> 16) & 1u);
  return (u16)(u >> 16);
}
__device__ __forceinline__ float lo16f(u32 q){ union { u32 u; float f; } v; v.u = q << 16; return v.f; }
__device__ __forceinline__ float hi16f(u32 q){ union { u32 u; float f; } v; v.u = q & 0xFFFF0000u; return v.f; }

__global__ void k_zero(float* __restrict__ p, long long n){
  long long i = (long long)blockIdx.x*256 + threadIdx.x;
  if (i < n) p[i] = 0.f;
}

__global__ void k_izero(int* __restrict__ p, int n){
  int i = blockIdx.x*256 + threadIdx.x;
  if (i < n) p[i] = 0;
}

__global__ void k_initb(const float* __restrict__ fu, const float* __restrict__ fi,
                        u16* __restrict__ fb){
  int idx = blockIdx.x*256 + threadIdx.x;
  if (idx >= CNN*CD) return;
  float v = (idx < CNU*CD) ? fu[idx] : fi[idx - CNU*CD];
  fb[idx] = f2bf(v);
}

// transpose W1 (f32 [k][j]) -> bf16 [j][k] for MFMA B-operand loads
__global__ void k_w1t(const float* __restrict__ Wu, const float* __restrict__ Wi,
                      u16* __restrict__ Wut, u16* __restrict__ Wit){
  int idx = blockIdx.x*256 + threadIdx.x;
  if (idx >= 16384) return;
  int k = idx >> 7, j = idx & 127;
  Wut[j*128 + k] = f2bf(Wu[idx]);
  Wit[j*128 + k] = f2bf(Wi[idx]);
}

// ---- CSR build via LDS-aggregated counting sort ----
// Pass 1 (UI variant): dst-keyed pair scatter only.
__global__ void k_bucket1(const int* __restrict__ src, const int* __restrict__ dst,
                          int* __restrict__ gcur, u32* __restrict__ gpairs,
                          int E, int NB){
  __shared__ int cnt[320];
  __shared__ int sbase[320];
  int t = threadIdx.x;
  for (int i = t; i < NB; i += 256) cnt[i] = 0;
  __syncthreads();
  int base = blockIdx.x * P1_CHUNK;
  int r[16], dv[16], sv[16];
  #pragma unroll
  for (int u = 0; u < 16; ++u){
    int e = base + u*256 + t;
    bool ok = (e < E);
    dv[u] = ok ? dst[e] : -1;
    sv[u] = ok ? src[e] : 0;
    if (ok) r[u] = atomicAdd(&cnt[dv[u] >> 8], 1);
  }
  __syncthreads();
  for (int i = t; i < NB; i += 256){
    int c = cnt[i];
    sbase[i] = c ? atomicAdd(&gcur[i], c) : 0;
  }
  __syncthreads();
  #pragma unroll
  for (int u = 0; u < 16; ++u){
    if (dv[u] >= 0){
      int b = dv[u] >> 8;
      int p = sbase[b] + r[u];
      if (p < BK_CAP)
        gpairs[(long long)b*BK_CAP + p] = (u32)sv[u] | ((u32)(dv[u] & 255) << 18);
    }
  }
}

// Pass 1 (MP variant): dst-keyed pair scatter + src-keyed byte scatter (for out-degree).
__global__ void k_bucket1b(const int* __restrict__ src, const int* __restrict__ dst,
                           int* __restrict__ gcur, u32* __restrict__ gpairs,
                           int* __restrict__ gcur2, u8* __restrict__ gbytes,
                           int E, int NB){
  __shared__ int cnt[320], sbase[320], cnt2[320], sbase2[320];
  int t = threadIdx.x;
  for (int i = t; i < NB; i += 256){ cnt[i] = 0; cnt2[i] = 0; }
  __syncthreads();
  int base = blockIdx.x * P1_CHUNK;
  int r[16], r2[16], dv[16], sv[16];
  #pragma unroll
  for (int u = 0; u < 16; ++u){
    int e = base + u*256 + t;
    bool ok = (e < E);
    dv[u] = ok ? dst[e] : -1;
    sv[u] = ok ? src[e] : -1;
    if (ok){
      r[u]  = atomicAdd(&cnt[dv[u] >> 8], 1);
      r2[u] = atomicAdd(&cnt2[sv[u] >> 8], 1);
    }
  }
  __syncthreads();
  for (int i = t; i < NB; i += 256){
    int c  = cnt[i];  sbase[i]  = c  ? atomicAdd(&gcur[i],  c)  : 0;
    int c2 = cnt2[i]; sbase2[i] = c2 ? atomicAdd(&gcur2[i], c2) : 0;
  }
  __syncthreads();
  #pragma unroll
  for (int u = 0; u < 16; ++u){
    if (dv[u] >= 0){
      int b = dv[u] >> 8;
      int p = sbase[b] + r[u];
      if (p < BK_CAP)
        gpairs[(long long)b*BK_CAP + p] = (u32)sv[u] | ((u32)(dv[u] & 255) << 18);
      int b2 = sv[u] >> 8;
      int p2 = sbase2[b2] + r2[u];
      if (p2 < BK_CAP)
        gbytes[(long long)b2*BK_CAP + p2] = (u8)(sv[u] & 255);
    }
  }
}

// exclusive scan of <=512 bucket counts (single block)
__global__ void k_scanb(const int* __restrict__ gcur, int* __restrict__ bbase, int NB){
  __shared__ int s[512];
  int t = threadIdx.x;
  int v = (t < NB) ? gcur[t] : 0;
  s[t] = v;
  __syncthreads();
  for (int off = 1; off < 512; off <<= 1){
    int u = (t >= off) ? s[t-off] : 0;
    __syncthreads();
    s[t] += u;
    __syncthreads();
  }
  if (t < NB) bbase[t] = s[t] - v;
}

// Count-only pass over src byte-buckets -> u16 out-degree table (for csr weight packing).
__global__ void k_odeg(const u8* __restrict__ gbytes, const int* __restrict__ gcur2,
                       u16* __restrict__ odeg, int n){
  __shared__ int hist[256];
  int b = blockIdx.x, t = threadIdx.x;
  hist[t] = 0;
  __syncthreads();
  int cnt = gcur2[b]; if (cnt > BK_CAP) cnt = BK_CAP;
  const u8* pp = gbytes + (long long)b*BK_CAP;
  for (int i = t; i < cnt; i += 256) atomicAdd(&hist[pp[i]], 1);
  __syncthreads();
  int dg = (b << 8) + t;
  if (dg < n) odeg[dg] = (u16)hist[t];
}

// Pass 2: one block per bucket; LDS scatter then streaming CSR write + ptr slice.
// Emits rs_ind[node] = h>0 ? rsqrt(h) : zval (in-degree rsqrt from LDS hist).
// If odeg != nullptr, packs csr entries as (outdeg[src] << 16) | src  (src < 65536).
__global__ void k_bucket2(const u32* __restrict__ gpairs, const int* __restrict__ gcur,
                          const int* __restrict__ bbase, int* __restrict__ csr,
                          int* __restrict__ ptr, int n,
                          float* __restrict__ rs_ind, float zval,
                          const u16* __restrict__ odeg){
  __shared__ int hist[256];
  __shared__ int excl[256];
  __shared__ int lptr[256];
  __shared__ int lsrc[BK_CAP];
  int b = blockIdx.x, t = threadIdx.x;
  int cnt = gcur[b]; if (cnt > BK_CAP) cnt = BK_CAP;
  int base = bbase[b];
  hist[t] = 0;
  __syncthreads();
  const u32* pp = gpairs + (long long)b*BK_CAP;
  for (int i = t; i < cnt; i += 256) atomicAdd(&hist[(pp[i] >> 18) & 255], 1);
  __syncthreads();
  int h = hist[t];
  lptr[t] = h;
  __syncthreads();
  for (int off = 1; off < 256; off <<= 1){
    int u2 = (t >= off) ? lptr[t-off] : 0;
    __syncthreads();
    lptr[t] += u2;
    __syncthreads();
  }
  excl[t] = lptr[t] - h;
  __syncthreads();
  hist[t] = excl[t];           // reuse hist as running cursor
  __syncthreads();
  for (int i = t; i < cnt; i += 256){
    u32 v = pp[i];
    int d = (v >> 18) & 255;
    int p = atomicAdd(&hist[d], 1);
    lsrc[p] = (int)(v & 0x3FFFFu);
  }
  __syncthreads();
  if (odeg){
    for (int i = t; i < cnt; i += 256){
      int s = lsrc[i];
      csr[base + i] = (int)((u32)s | ((u32)odeg[s] << 16));
    }
  } else {
    for (int i = t; i < cnt; i += 256) csr[base + i] = lsrc[i];
  }
  int dg = (b << 8) + t;
  if (dg <= n) ptr[dg] = base + excl[t];
  if (dg < n)  rs_ind[dg] = (h > 0) ? rsqrtf((float)h) : zval;
}

// ---- gather: 1 wave/row, lane=(g=edge-slot 0..3, c=16B-chunk 0..15) ----
// MP variant: csr entries packed (outdeg<<16 | src); w = rsqrt(outdeg) decoded in-reg.
// Main loop unpredicated; single masked tail iteration.
__global__ void k_gather_mp(const u16* __restrict__ h, const int* __restrict__ ptr,
                            const u32* __restrict__ csr, u16* __restrict__ z, int n){
  int row = (blockIdx.x*256 + threadIdx.x) >> 6;
  if (row >= n) return;
  int lane = threadIdx.x & 63;
  int g = lane >> 4, c = lane & 15;
  int p = ptr[row], pe = ptr[row+1];
  float a0=0,a1=0,a2=0,a3=0,a4=0,a5=0,a6=0,a7=0;
  const u16* hb = h + (long long)c*8;
  int pm = p + ((pe - p) & ~15);
  while (p < pm){
    uint4 q[4]; float w[4];
    #pragma unroll
    for (int u = 0; u < 4; ++u){
      u32 e = csr[p + u*4 + g];
      w[u] = rsqrtf((float)(e >> 16));
      q[u] = *(const uint4*)(hb + (long long)(e & 0xFFFFu)*CD);
    }
    #pragma unroll
    for (int u = 0; u < 4; ++u){
      a0 += lo16f(q[u].x)*w[u]; a1 += hi16f(q[u].x)*w[u];
      a2 += lo16f(q[u].y)*w[u]; a3 += hi16f(q[u].y)*w[u];
      a4 += lo16f(q[u].z)*w[u]; a5 += hi16f(q[u].z)*w[u];
      a6 += lo16f(q[u].w)*w[u]; a7 += hi16f(q[u].w)*w[u];
    }
    p += 16;
  }
  if (p < pe){
    uint4 q[4]; float w[4];
    #pragma unroll
    for (int u = 0; u < 4; ++u){
      int ei = p + u*4 + g;
      bool ok = (ei < pe);
      u32 e = ok ? csr[ei] : 0u;
      w[u] = ok ? rsqrtf((float)(e >> 16)) : 0.f;
      q[u] = *(const uint4*)(hb + (long long)(e & 0xFFFFu)*CD);
    }
    #pragma unroll
    for (int u = 0; u < 4; ++u){
      a0 += lo16f(q[u].x)*w[u]; a1 += hi16f(q[u].x)*w[u];
      a2 += lo16f(q[u].y)*w[u]; a3 += hi16f(q[u].y)*w[u];
      a4 += lo16f(q[u].z)*w[u]; a5 += hi16f(q[u].z)*w[u];
      a6 += lo16f(q[u].w)*w[u]; a7 += hi16f(q[u].w)*w[u];
    }
  }
  #pragma unroll
  for (int m = 16; m <= 32; m <<= 1){
    a0 += __shfl_xor(a0, m); a1 += __shfl_xor(a1, m);
    a2 += __shfl_xor(a2, m); a3 += __shfl_xor(a3, m);
    a4 += __shfl_xor(a4, m); a5 += __shfl_xor(a5, m);
    a6 += __shfl_xor(a6, m); a7 += __shfl_xor(a7, m);
  }
  if (g == 0){
    uint4 o;
    o.x = (u32)f2bf(a0) | ((u32)f2bf(a1) << 16);
    o.y = (u32)f2bf(a2) | ((u32)f2bf(a3) << 16);
    o.z = (u32)f2bf(a4) | ((u32)f2bf(a5) << 16);
    o.w = (u32)f2bf(a6) | ((u32)f2bf(a7) << 16);
    *(uint4*)(z + (long long)row*CD + c*8) = o;
  }
}

// UI variant: per-edge w = dinv[src]; main/tail split.
__global__ void k_gather_ui(const u16* __restrict__ xin, const int* __restrict__ ptr,
                            const int* __restrict__ csr_src, const float* __restrict__ dinv,
                            u16* __restrict__ xout, int n){
  int row = (blockIdx.x*256 + threadIdx.x) >> 6;
  if (row >= n) return;
  int lane = threadIdx.x & 63;
  int g = lane >> 4, c = lane & 15;
  int p = ptr[row], pe = ptr[row+1];
  float a0=0,a1=0,a2=0,a3=0,a4=0,a5=0,a6=0,a7=0;
  const u16* hb = xin + (long long)c*8;
  int pm = p + ((pe - p) & ~15);
  while (p < pm){
    uint4 q[4]; float w[4];
    #pragma unroll
    for (int u = 0; u < 4; ++u){
      int s = csr_src[p + u*4 + g];
      w[u] = dinv[s];
      q[u] = *(const uint4*)(hb + (long long)s*CD);
    }
    #pragma unroll
    for (int u = 0; u < 4; ++u){
      a0 += lo16f(q[u].x)*w[u]; a1 += hi16f(q[u].x)*w[u];
      a2 += lo16f(q[u].y)*w[u]; a3 += hi16f(q[u].y)*w[u];
      a4 += lo16f(q[u].z)*w[u]; a5 += hi16f(q[u].z)*w[u];
      a6 += lo16f(q[u].w)*w[u]; a7 += hi16f(q[u].w)*w[u];
    }
    p += 16;
  }
  if (p < pe){
    uint4 q[4]; float w[4];
    #pragma unroll
    for (int u = 0; u < 4; ++u){
      int ei = p + u*4 + g;
      bool ok = (ei < pe);
      int s  = ok ? csr_src[ei] : 0;
      w[u]   = ok ? dinv[s] : 0.f;
      q[u]   = *(const uint4*)(hb + (long long)s*CD);
    }
    #pragma unroll
    for (int u = 0; u < 4; ++u){
      a0 += lo16f(q[u].x)*w[u]; a1 += hi16f(q[u].x)*w[u];
      a2 += lo16f(q[u].y)*w[u]; a3 += hi16f(q[u].y)*w[u];
      a4 += lo16f(q[u].z)*w[u]; a5 += hi16f(q[u].z)*w[u];
      a6 += lo16f(q[u].w)*w[u]; a7 += hi16f(q[u].w)*w[u];
    }
  }
  #pragma unroll
  for (int m = 16; m <= 32; m <<= 1){
    a0 += __shfl_xor(a0, m); a1 += __shfl_xor(a1, m);
    a2 += __shfl_xor(a2, m); a3 += __shfl_xor(a3, m);
    a4 += __shfl_xor(a4, m); a5 += __shfl_xor(a5, m);
    a6 += __shfl_xor(a6, m); a7 += __shfl_xor(a7, m);
  }
  if (g == 0){
    float wd = dinv[row];
    uint4 o;
    o.x = (u32)f2bf(a0*wd) | ((u32)f2bf(a1*wd) << 16);
    o.y = (u32)f2bf(a2*wd) | ((u32)f2bf(a3*wd) << 16);
    o.z = (u32)f2bf(a4*wd) | ((u32)f2bf(a5*wd) << 16);
    o.w = (u32)f2bf(a6*wd) | ((u32)f2bf(a7*wd) << 16);
    *(uint4*)(xout + (long long)row*CD + c*8) = o;
  }
}

// semantic attention scores via MFMA; block-level reduction -> 1 atomic/block
__global__ void k_att(const u16* __restrict__ z0, const u16* __restrict__ z1,
                      const float* __restrict__ rsi0, const float* __restrict__ rsi1,
                      const u16* __restrict__ W1T, const float* __restrict__ b1,
                      const float* __restrict__ W2, float* __restrict__ s_out, int n){
  __shared__ float wred[4];
  int nb = n >> 6;
  int blk = blockIdx.x;
  int ch = (blk >= nb) ? 1 : 0;
  int rb = (ch ? (blk - nb) : blk) * 64;
  const u16* z = ch ? z1 : z0;
  const float* rsi = ch ? rsi1 : rsi0;
  int wv = threadIdx.x >> 6, lane = threadIdx.x & 63;
  int i0 = rb + wv*16;
  int m = lane & 15, kq = lane >> 4;
  bf16x8 a[4];
  #pragma unroll
  for (int t = 0; t < 4; ++t){
    uint4 q = *(const uint4*)(z + (long long)(i0+m)*CD + t*32 + kq*8);
    a[t] = *(bf16x8*)&q;
  }
  float rsv[4];
  #pragma unroll
  for (int ri = 0; ri < 4; ++ri) rsv[ri] = rsi[i0 + kq*4 + ri];
  float psum = 0.f;
  #pragma unroll
  for (int jt = 0; jt < 8; ++jt){
    f32x4 acc = {0.f,0.f,0.f,0.f};
    #pragma unroll
    for (int t = 0; t < 4; ++t){
      uint4 qb = *(const uint4*)(W1T + (jt*16 + m)*CD + t*32 + kq*8);
      bf16x8 b = *(bf16x8*)&qb;
      acc = __builtin_amdgcn_mfma_f32_16x16x32_bf16(a[t], b, acc, 0, 0, 0);
    }
    int j = jt*16 + m;
    float bb = b1[j], w2 = W2[j];
    #pragma unroll
    for (int ri = 0; ri < 4; ++ri){
      float x = acc[ri]*rsv[ri] + bb;
      x = fminf(fmaxf(x, -15.f), 15.f);
      float t2 = __expf(2.f*x);
      psum += ((t2 - 1.f)/(t2 + 1.f))*w2;
    }
  }
  #pragma unroll
  for (int msk = 1; msk <= 32; msk <<= 1) psum += __shfl_xor(psum, msk);
  if (lane == 0) wred[wv] = psum;
  __syncthreads();
  if (threadIdx.x == 0)
    atomicAdd(&s_out[ch], wred[0] + wred[1] + wred[2] + wred[3]);
}

__global__ void k_combine(const u16* __restrict__ z0, const u16* __restrict__ z1,
                          const float* __restrict__ rsi0, const float* __restrict__ rsi1,
                          const float* __restrict__ s, u16* __restrict__ h, int n){
  int idx = blockIdx.x*256 + threadIdx.x;
  if (idx >= n*CD) return;
  int v = idx >> 7;
  float s0 = s[0]*(1.0f/n), s1 = s[1]*(1.0f/n);
  float m = fmaxf(s0, s1);
  float e0 = __expf(s0 - m), e1 = __expf(s1 - m);
  float r = 1.0f/(e0 + e1);
  h[idx] = f2bf((e0*r)*bf2f(z0[idx])*rsi0[v] + (e1*r)*bf2f(z1[idx])*rsi1[v]);
}

__global__ void k_emb(const u16* __restrict__ x2, u16* __restrict__ h_u,
                      u16* __restrict__ h_i){
  int idx = blockIdx.x*256 + threadIdx.x;
  if (idx >= CNN*CD) return;
  if (idx < CNU*CD) h_u[idx] = f2bf(0.5f*bf2f(h_u[idx]) + 0.5f*bf2f(x2[idx]));
  else { int k = idx - CNU*CD; h_i[k] = f2bf(0.5f*bf2f(h_i[k]) + 0.5f*bf2f(x2[idx])); }
}

// 4 rows/wave, 4 waves/block; u32 row loads; block-level pos reduction -> 1 atomic/block
__global__ void k_sslnorm(const u16* __restrict__ xui, const u16* __restrict__ hemb,
                          const int* __restrict__ idx, int rowoff,
                          u16* __restrict__ n1b, u16* __restrict__ n2b,
                          float* __restrict__ pos_acc){
  __shared__ float wred[4];
  int wv = threadIdx.x >> 6, lane = threadIdx.x & 63;
  int r0 = blockIdx.x*16 + wv*4;
  int g[4]; u32 q1[4], q2[4];
  #pragma unroll
  for (int u = 0; u < 4; ++u){
    g[u] = idx[r0 + u];
    q1[u] = *(const u32*)(xui + (long long)(g[u] + rowoff)*CD + lane*2);
    q2[u] = *(const u32*)(hemb + (long long)g[u]*CD + lane*2);
  }
  float psum = 0.f;
  #pragma unroll
  for (int u = 0; u < 4; ++u){
    float a0 = lo16f(q1[u]), a1 = hi16f(q1[u]);
    float b0 = lo16f(q2[u]), b1 = hi16f(q2[u]);
    float s1 = a0*a0 + a1*a1, s2 = b0*b0 + b1*b1, s12 = a0*b0 + a1*b1;
    #pragma unroll
    for (int msk = 1; msk <= 32; msk <<= 1){
      s1  += __shfl_xor(s1, msk);
      s2  += __shfl_xor(s2, msk);
      s12 += __shfl_xor(s12, msk);
    }
    float i1 = 1.0f / fmaxf(sqrtf(s1), 1e-12f);
    float i2 = 1.0f / fmaxf(sqrtf(s2), 1e-12f);
    *(u32*)(n1b + (long long)(r0+u)*CD + lane*2) = (u32)f2bf(a0*i1) | ((u32)f2bf(a1*i1) << 16);
    *(u32*)(n2b + (long long)(r0+u)*CD + lane*2) = (u32)f2bf(b0*i2) | ((u32)f2bf(b1*i2) << 16);
    psum += s12*i1*i2*2.0f;
  }
  if (lane == 0) wred[wv] = psum;
  __syncthreads();
  if (threadIdx.x == 0)
    atomicAdd(pos_acc, wred[0] + wred[1] + wred[2] + wred[3]);
}

// alls[i] += sum_j exp(2 * n1_i . n2_j) via MFMA; register-blocked 4 i-tiles/wave.
__global__ void __launch_bounds__(256, 2)
k_alls(const u16* __restrict__ n1b, const u16* __restrict__ n2b,
       float* __restrict__ alls){
  int wv = threadIdx.x >> 6;
  int lane = threadIdx.x & 63;
  int m = lane & 15, kq = lane >> 4;
  int i0 = (blockIdx.x*4 + wv)*64;
  bf16x8 a[4][4];
  #pragma unroll
  for (int c = 0; c < 4; ++c){
    #pragma unroll
    for (int t = 0; t < 4; ++t){
      uint4 q = *(const uint4*)(n1b + (long long)(i0 + c*16 + m)*CD + t*32 + kq*8);
      a[c][t] = *(bf16x8*)&q;
    }
  }
  float es[4][4];
  #pragma unroll
  for (int c = 0; c < 4; ++c)
    #pragma unroll
    for (int ri = 0; ri < 4; ++ri) es[c][ri] = 0.f;

  const u16* jb = n2b + (long long)(blockIdx.y*512 + m)*CD + kq*8;
  uint4 q[4];
  #pragma unroll
  for (int t = 0; t < 4; ++t) q[t] = *(const uint4*)(jb + t*32);
  for (int jt = 0; jt < 32; ++jt){
    uint4 qn[4];
    if (jt < 31){
      const u16* jb2 = jb + (long long)(jt+1)*16*CD;
      #pragma unroll
      for (int t = 0; t < 4; ++t) qn[t] = *(const uint4*)(jb2 + t*32);
    }
    f32x4 ac[4];
    #pragma unroll
    for (int c = 0; c < 4; ++c) ac[c] = (f32x4){0.f,0.f,0.f,0.f};
    #pragma unroll
    for (int t = 0; t < 4; ++t){
      bf16x8 b = *(bf16x8*)&q[t];
      #pragma unroll
      for (int c = 0; c < 4; ++c)
        ac[c] = __builtin_amdgcn_mfma_f32_16x16x32_bf16(a[c][t], b, ac[c], 0, 0, 0);
    }
    #pragma unroll
    for (int c = 0; c < 4; ++c)
      #pragma unroll
      for (int ri = 0; ri < 4; ++ri)
        es[c][ri] += __expf(ac[c][ri]*2.f);
    if (jt < 31){
      #pragma unroll
      for (int t = 0; t < 4; ++t) q[t] = qn[t];
    }
  }
  #pragma unroll
  for (int c = 0; c < 4; ++c){
    #pragma unroll
    for (int ri = 0; ri < 4; ++ri){
      float v = es[c][ri];
      #pragma unroll
      for (int msk = 1; msk <= 8; msk <<= 1) v += __shfl_xor(v, msk);
      if (m == 0) atomicAdd(&alls[i0 + c*16 + kq*4 + ri], v);
    }
  }
}

__global__ void k_logsum(const float* __restrict__ alls, float* __restrict__ misc){
  int i = blockIdx.x*256 + threadIdx.x;
  float v = logf(alls[i]);
  for (int off = 32; off > 0; off >>= 1) v += __shfl_down(v, off);
  if ((threadIdx.x & 63) == 0) atomicAdd(&misc[(i < CB) ? 13 : 15], v);
}

__global__ void k_final(const u16* __restrict__ emb, const int* __restrict__ idx,
                        const float* __restrict__ W, const float* __restrict__ bias,
                        const float* __restrict__ lg, const float* __restrict__ lb,
                        float* __restrict__ outp){
  __shared__ float A[8][128];
  __shared__ float red[8][4];
  int j = threadIdx.x;
  int r0 = blockIdx.x*8;
  for (int r = 0; r < 8; ++r){
    int g = idx[r0 + r];
    A[r][j] = bf2f(emb[(long long)g*CD + j]);
  }
  __syncthreads();
  float acc[8];
  #pragma unroll
  for (int r = 0; r < 8; ++r) acc[r] = 0.f;
  for (int k = 0; k < 128; k += 4){
    float w0 = W[(k+0)*128 + j];
    float w1 = W[(k+1)*128 + j];
    float w2 = W[(k+2)*128 + j];
    float w3 = W[(k+3)*128 + j];
    #pragma unroll
    for (int r = 0; r < 8; ++r){
      float4 a = *(const float4*)&A[r][k];
      acc[r] += a.x*w0 + a.y*w1 + a.z*w2 + a.w*w3;
    }
  }
  float bb = bias[j];
  #pragma unroll
  for (int r = 0; r < 8; ++r){
    float v = acc[r] + bb;
    acc[r] = (v < 0.f) ? 0.f : v;
  }
  int wid = j >> 6, lane = j & 63;
  #pragma unroll
  for (int r = 0; r < 8; ++r){
    float s = acc[r], q = acc[r]*acc[r];
    for (int off = 32; off > 0; off >>= 1){
      s += __shfl_down(s, off); q += __shfl_down(q, off);
    }
    if (lane == 0){ red[r][wid*2] = s; red[r][wid*2+1] = q; }
  }
  __syncthreads();
  float gg = lg[j], be = lb[j];
  #pragma unroll
  for (int r = 0; r < 8; ++r){
    float mu = (red[r][0] + red[r][2]) * (1.0f/128.0f);
    float ms = (red[r][1] + red[r][3]) * (1.0f/128.0f);
    float var = ms - mu*mu;
    float y = (acc[r] - mu) * rsqrtf(var + 1e-5f) * gg + be;
    outp[(long long)(r0 + r)*CD + j] = y;
  }
}

__global__ void k_loss(const float* __restrict__ misc, float* __restrict__ o){
  float lu = (misc[13] - misc[12]) * (1.0f/CB);
  float li = (misc[15] - misc[14]) * (1.0f/CB);
  o[0] = 0.4f*(lu + li);
}

extern "C" void kernel_launch(void* const* d_in, const int* in_sizes, int n_in,
                              void* d_out, int out_size, void* d_ws, size_t ws_size,
                              hipStream_t stream){
  (void)in_sizes; (void)n_in; (void)out_size; (void)ws_size;
  const float* feat_user = (const float*)d_in[0];
  const float* feat_item = (const float*)d_in[1];
  const float* u_W1 = (const float*)d_in[2];
  const float* u_b1 = (const float*)d_in[3];
  const float* u_W2 = (const float*)d_in[4];
  const float* i_W1 = (const float*)d_in[5];
  const float* i_b1 = (const float*)d_in[6];
  const float* i_W2 = (const float*)d_in[7];
  const float* user_W = (const float*)d_in[8];
  const float* user_b = (const float*)d_in[9];
  const float* item_W = (const float*)d_in[10];
  const float* item_b = (const float*)d_in[11];
  const float* ln_g = (const float*)d_in[12];
  const float* ln_b = (const float*)d_in[13];
  const int* ump0s = (const int*)d_in[14]; const int* ump0d = (const int*)d_in[15];
  const int* ump1s = (const int*)d_in[16]; const int* ump1d = (const int*)d_in[17];
  const int* imp0s = (const int*)d_in[18]; const int* imp0d = (const int*)d_in[19];
  const int* imp1s = (const int*)d_in[20]; const int* imp1d = (const int*)d_in[21];
  const int* ui_row = (const int*)d_in[22]; const int* ui_col = (const int*)d_in[23];
  const int* user_idx = (const int*)d_in[24]; const int* item_idx = (const int*)d_in[25];
  const int* neg_idx = (const int*)d_in[26];

  u16* W  = (u16*)d_ws;
  u16* fb = W;                      // 10,240,000 bf16
  u16* hu = W + 10240000LL;
  u16* hi = W + 15360000LL;
  u16* xb = W + 20480000LL;
  u16* x2 = W + 30720000LL;
  u16* z0 = W + 40960000LL;
  u16* z1 = W + 46080000LL;
  float* F   = (float*)(W + 51200000LL);
  float* rs  = F;                   // 320,000 (indeg rsqrt tables; low 80KB doubles as odeg scratch)
  float* dinv= F + 320000;          // 80,000
  float* alls= F + 400000;          // 16,384
  float* misc= F + 416384;          // 64
  int* I     = (int*)(F + 416448);
  int* mp_p0 = I;                   // 40,001
  int* mp_p1 = I + 40001;           // 40,001
  int* gcur  = I + 80002;           // 320  (dst bucket cursors)
  int* bbase = I + 80322;           // 320  (dst bucket scan bases)
  int* gcur2 = I + 80642;           // 320  (src byte-bucket cursors)
  int* mp_c0 = I + 120002;          // 640,000
  int* mp_c1 = I + 760002;          // 640,000
  u16* w1tu  = (u16*)(I + 1400128); // 16,384 bf16 (W1^T user)
  u16* w1ti  = w1tu + 16384;        // 16,384 bf16 (W1^T item)
  u16* odeg  = (u16*)rs;            // 40,000 u16 scratch (first 80KB of rs; indeg tables start at rs+40000)
  int* ui_ptr    = (int*)hu;        // overlay (hu/hi dead until first combine)
  int* ui_csr    = ui_ptr + 160001; // 1,600,000 ints
  u32* gpairs    = (u32*)z0;        // overlay: 313*8064*4B = 10.1MB (z0 dead during builds)
  u8*  gbytes    = (u8*)z1;         // overlay: 157*8064 B = 1.27MB (z1 dead during builds)
  u16* n1ub = xb;                   // overlay (xb dead after UI hop 3)
  u16* n2ub = xb + (long long)CB*CD;
  u16* n1ib = xb + 2LL*CB*CD;
  u16* n2ib = xb + 3LL*CB*CD;
  float* out = (float*)d_out;

  k_zero<<<(16448 + 255)/256, 256, 0, stream>>>(alls, 16448);

  k_initb<<<40000, 256, 0, stream>>>(feat_user, feat_item, fb);
  k_w1t<<<64, 256, 0, stream>>>(u_W1, i_W1, w1tu, w1ti);

  // UI CSR build (counting sort; NB=313 buckets of 256 dst); dinv emitted by pass 2.
  k_izero<<<4, 256, 0, stream>>>(gcur, 960);
  k_bucket1<<<(CEUI + P1_CHUNK - 1)/P1_CHUNK, 256, 0, stream>>>(ui_col, ui_row, gcur, gpairs, CEUI, 313);
  k_scanb<<<1, 512, 0, stream>>>(gcur, bbase, 313);
  k_bucket2<<<313, 256, 0, stream>>>(gpairs, gcur, bbase, ui_csr, ui_ptr, CNN, dinv, 0.0f, nullptr);

  // UI propagation: fb -> x2 -> xb -> x2
  k_gather_ui<<<20000, 256, 0, stream>>>(fb, ui_ptr, ui_csr, dinv, x2, CNN);
  k_gather_ui<<<20000, 256, 0, stream>>>(x2, ui_ptr, ui_csr, dinv, xb, CNN);
  k_gather_ui<<<20000, 256, 0, stream>>>(xb, ui_ptr, ui_csr, dinv, x2, CNN);

  // HAN user CSRs (NB=157); outdeg packed into csr, indeg rsqrt from pass 2.
  k_izero<<<4, 256, 0, stream>>>(gcur, 960);
  k_bucket1b<<<(CEMP + P1_CHUNK - 1)/P1_CHUNK, 256, 0, stream>>>(ump0s, ump0d, gcur, gpairs, gcur2, gbytes, CEMP, 157);
  k_scanb<<<1, 512, 0, stream>>>(gcur, bbase, 157);
  k_odeg<<<157, 256, 0, stream>>>(gbytes, gcur2, odeg, CNU);
  k_bucket2<<<157, 256, 0, stream>>>(gpairs, gcur, bbase, mp_c0, mp_p0, CNU, rs + 40000, 1.0f, odeg);
  k_izero<<<4, 256, 0, stream>>>(gcur, 960);
  k_bucket1b<<<(CEMP + P1_CHUNK - 1)/P1_CHUNK, 256, 0, stream>>>(ump1s, ump1d, gcur, gpairs, gcur2, gbytes, CEMP, 157);
  k_scanb<<<1, 512, 0, stream>>>(gcur, bbase, 157);
  k_odeg<<<157, 256, 0, stream>>>(gbytes, gcur2, odeg, CNU);
  k_bucket2<<<157, 256, 0, stream>>>(gpairs, gcur, bbase, mp_c1, mp_p1, CNU, rs + 120000, 1.0f, odeg);
  for (int L = 0; L < 3; ++L){
    const u16* hin = (L == 0) ? fb : hu;
    k_gather_mp<<<10000, 256, 0, stream>>>(hin, mp_p0, (const u32*)mp_c0, z0, CNU);
    k_gather_mp<<<10000, 256, 0, stream>>>(hin, mp_p1, (const u32*)mp_c1, z1, CNU);
    k_att<<<1250, 256, 0, stream>>>(z0, z1, rs + 40000, rs + 120000,
                                    w1tu, u_b1, u_W2, misc + 2*L, CNU);
    k_combine<<<20000, 256, 0, stream>>>(z0, z1, rs + 40000, rs + 120000,
                                         misc + 2*L, hu, CNU);
  }
  // HAN item CSRs (z0/z1 dead between loops -> overlays safe)
  k_izero<<<4, 256, 0, stream>>>(gcur, 960);
  k_bucket1b<<<(CEMP + P1_CHUNK - 1)/P1_CHUNK, 256, 0, stream>>>(imp0s, imp0d, gcur, gpairs, gcur2, gbytes, CEMP, 157);
  k_scanb<<<1, 512, 0, stream>>>(gcur, bbase, 157);
  k_odeg<<<157, 256, 0, stream>>>(gbytes, gcur2, odeg, CNU);
  k_bucket2<<<157, 256, 0, stream>>>(gpairs, gcur, bbase, mp_c0, mp_p0, CNU, rs + 200000, 1.0f, odeg);
  k_izero<<<4, 256, 0, stream>>>(gcur, 960);
  k_bucket1b<<<(CEMP + P1_CHUNK - 1)/P1_CHUNK, 256, 0, stream>>>(imp1s, imp1d, gcur, gpairs, gcur2, gbytes, CEMP, 157);
  k_scanb<<<1, 512, 0, stream>>>(gcur, bbase, 157);
  k_odeg<<<157, 256, 0, stream>>>(gbytes, gcur2, odeg, CNU);
  k_bucket2<<<157, 256, 0, stream>>>(gpairs, gcur, bbase, mp_c1, mp_p1, CNU, rs + 280000, 1.0f, odeg);
  for (int L = 0; L < 3; ++L){
    const u16* hin = (L == 0) ? (fb + (long long)CNU*CD) : hi;
    k_gather_mp<<<10000, 256, 0, stream>>>(hin, mp_p0, (const u32*)mp_c0, z0, CNU);
    k_gather_mp<<<10000, 256, 0, stream>>>(hin, mp_p1, (const u32*)mp_c1, z1, CNU);
    k_att<<<1250, 256, 0, stream>>>(z0, z1, rs + 200000, rs + 280000,
                                    w1ti, i_b1, i_W2, misc + 6 + 2*L, CNU);
    k_combine<<<20000, 256, 0, stream>>>(z0, z1, rs + 200000, rs + 280000,
                                         misc + 6 + 2*L, hi, CNU);
  }

  k_emb<<<40000, 256, 0, stream>>>(x2, hu, hi);

  // SSL
  k_sslnorm<<<CB/16, 256, 0, stream>>>(x2, hu, user_idx, 0,   n1ub, n2ub, misc + 12);
  k_sslnorm<<<CB/16, 256, 0, stream>>>(x2, hi, item_idx, CNU, n1ib, n2ib, misc + 14);
  k_alls<<<dim3(32, 16), 256, 0, stream>>>(n1ub, n2ub, alls);
  k_alls<<<dim3(32, 16), 256, 0, stream>>>(n1ib, n2ib, alls + CB);
  k_logsum<<<64, 256, 0, stream>>>(alls, misc);

  k_final<<<1024, 128, 0, stream>>>(hu, user_idx, user_W, user_b, ln_g, ln_b, out);
  k_final<<<1024, 128, 0, stream>>>(hi, item_idx, item_W, item_b, ln_g, ln_b, out + (long long)CB*CD);
  k_final<<<1024, 128, 0, stream>>>(hi, neg_idx,  item_W, item_b, ln_g, ln_b, out + 2LL*CB*CD);
  k_loss<<<1, 1, 0, stream>>>(misc, out + 3LL*CB*CD);
}

// Round 7
// 1127.925 us; speedup vs baseline: 2.2378x; 1.1027x over previous
//
#include <hip/hip_runtime.h>
#include <math.h>

typedef unsigned short u16;
typedef unsigned int u32;
typedef unsigned char u8;
typedef __attribute__((ext_vector_type(8))) short bf16x8;
typedef __attribute__((ext_vector_type(4))) float f32x4;

#define CNU 40000
#define CNN 80000
#define CD  128
#define CEMP 640000
#define CEUI 1600000
#define CB  8192

#define BK_CAP 8064     // per-bucket capacity (mean 5120 UI / 4096 MP; >40 sigma margin)
#define P1_CHUNK 4096   // edges per block in bucket pass 1 (16/thread)
#define NB_MP 157       // MP bucket count (40000/256 rounded up)

__device__ __forceinline__ float bf2f(u16 b){
  union { u32 u; float f; } v; v.u = ((u32)b) << 16; return v.f;
}
__device__ __forceinline__ u16 f2bf(float f){
  union { float f; u32 u; } v; v.f = f;
  u32 u = v.u + 0x7FFFu + ((v.u >> 16) & 1u);
  return (u16)(u >> 16);
}
__device__ __forceinline__ float lo16f(u32 q){ union { u32 u; float f; } v; v.u = q << 16; return v.f; }
__device__ __forceinline__ float hi16f(u32 q){ union { u32 u; float f; } v; v.u = q & 0xFFFF0000u; return v.f; }

__global__ void k_zero(float* __restrict__ p, long long n){
  long long i = (long long)blockIdx.x*256 + threadIdx.x;
  if (i < n) p[i] = 0.f;
}

__global__ void k_izero(int* __restrict__ p, int n){
  int i = blockIdx.x*256 + threadIdx.x;
  if (i < n) p[i] = 0;
}

// fused: feature f32->bf16 cast (blocks 0..39999) + W1 transpose (blocks 40000..40063)
__global__ void k_initb(const float* __restrict__ fu, const float* __restrict__ fi,
                        u16* __restrict__ fb,
                        const float* __restrict__ Wu, const float* __restrict__ Wi,
                        u16* __restrict__ Wut, u16* __restrict__ Wit){
  int b = blockIdx.x;
  if (b < 40000){
    int idx = b*256 + threadIdx.x;
    float v = (idx < CNU*CD) ? fu[idx] : fi[idx - CNU*CD];
    fb[idx] = f2bf(v);
  } else {
    int idx = (b - 40000)*256 + threadIdx.x;
    if (idx < 16384){
      int k = idx >> 7, j = idx & 127;
      Wut[j*128 + k] = f2bf(Wu[idx]);
      Wit[j*128 + k] = f2bf(Wi[idx]);
    }
  }
}

// ---- CSR build via LDS-aggregated counting sort ----
// Pass 1 (UI variant): dst-keyed pair scatter only.
__global__ void k_bucket1(const int* __restrict__ src, const int* __restrict__ dst,
                          int* __restrict__ gcur, u32* __restrict__ gpairs,
                          int E, int NB){
  __shared__ int cnt[320];
  __shared__ int sbase[320];
  int t = threadIdx.x;
  for (int i = t; i < NB; i += 256) cnt[i] = 0;
  __syncthreads();
  int base = blockIdx.x * P1_CHUNK;
  int r[16], dv[16], sv[16];
  #pragma unroll
  for (int u = 0; u < 16; ++u){
    int e = base + u*256 + t;
    bool ok = (e < E);
    dv[u] = ok ? dst[e] : -1;
    sv[u] = ok ? src[e] : 0;
    if (ok) r[u] = atomicAdd(&cnt[dv[u] >> 8], 1);
  }
  __syncthreads();
  for (int i = t; i < NB; i += 256){
    int c = cnt[i];
    sbase[i] = c ? atomicAdd(&gcur[i], c) : 0;
  }
  __syncthreads();
  #pragma unroll
  for (int u = 0; u < 16; ++u){
    if (dv[u] >= 0){
      int b = dv[u] >> 8;
      int p = sbase[b] + r[u];
      if (p < BK_CAP)
        gpairs[(long long)b*BK_CAP + p] = (u32)sv[u] | ((u32)(dv[u] & 255) << 18);
    }
  }
}

// Pass 1 (MP, 2-graph batched): dst-keyed pair scatter + src-keyed byte scatter.
// blockIdx.y = graph id (0/1).
__global__ void k_bucket1b2(const int* __restrict__ s0, const int* __restrict__ d0,
                            const int* __restrict__ s1, const int* __restrict__ d1,
                            int* __restrict__ gcur, u32* __restrict__ gpairs,
                            int* __restrict__ gcur2, u8* __restrict__ gbytes){
  __shared__ int cnt[320], sbase[320], cnt2[320], sbase2[320];
  int g = blockIdx.y;
  const int* src = g ? s1 : s0;
  const int* dst = g ? d1 : d0;
  int* gc  = gcur  + g*320;
  int* gc2 = gcur2 + g*320;
  u32* gp  = gpairs + (long long)g*NB_MP*BK_CAP;
  u8*  gb  = gbytes + (long long)g*NB_MP*BK_CAP;
  int t = threadIdx.x;
  for (int i = t; i < NB_MP; i += 256){ cnt[i] = 0; cnt2[i] = 0; }
  __syncthreads();
  int base = blockIdx.x * P1_CHUNK;
  int r[16], r2[16], dv[16], sv[16];
  #pragma unroll
  for (int u = 0; u < 16; ++u){
    int e = base + u*256 + t;
    bool ok = (e < CEMP);
    dv[u] = ok ? dst[e] : -1;
    sv[u] = ok ? src[e] : -1;
    if (ok){
      r[u]  = atomicAdd(&cnt[dv[u] >> 8], 1);
      r2[u] = atomicAdd(&cnt2[sv[u] >> 8], 1);
    }
  }
  __syncthreads();
  for (int i = t; i < NB_MP; i += 256){
    int c  = cnt[i];  sbase[i]  = c  ? atomicAdd(&gc[i],  c)  : 0;
    int c2 = cnt2[i]; sbase2[i] = c2 ? atomicAdd(&gc2[i], c2) : 0;
  }
  __syncthreads();
  #pragma unroll
  for (int u = 0; u < 16; ++u){
    if (dv[u] >= 0){
      int b = dv[u] >> 8;
      int p = sbase[b] + r[u];
      if (p < BK_CAP)
        gp[(long long)b*BK_CAP + p] = (u32)sv[u] | ((u32)(dv[u] & 255) << 18);
      int b2 = sv[u] >> 8;
      int p2 = sbase2[b2] + r2[u];
      if (p2 < BK_CAP)
        gb[(long long)b2*BK_CAP + p2] = (u8)(sv[u] & 255);
    }
  }
}

// exclusive scan of bucket counts; one block per graph slice (stride 320).
__global__ void k_scanb(const int* __restrict__ gcur, int* __restrict__ bbase, int NB){
  __shared__ int s[512];
  int g = blockIdx.x;
  const int* gc = gcur + g*320;
  int* bb = bbase + g*320;
  int t = threadIdx.x;
  int v = (t < NB) ? gc[t] : 0;
  s[t] = v;
  __syncthreads();
  for (int off = 1; off < 512; off <<= 1){
    int u = (t >= off) ? s[t-off] : 0;
    __syncthreads();
    s[t] += u;
    __syncthreads();
  }
  if (t < NB) bb[t] = s[t] - v;
}

// Count-only pass over src byte-buckets -> u16 out-degree table; blockIdx.y = graph.
__global__ void k_odeg2(const u8* __restrict__ gbytes, const int* __restrict__ gcur2,
                        u16* __restrict__ odeg){
  __shared__ int hist[256];
  int g = blockIdx.y;
  int b = blockIdx.x, t = threadIdx.x;
  hist[t] = 0;
  __syncthreads();
  int cnt = gcur2[g*320 + b]; if (cnt > BK_CAP) cnt = BK_CAP;
  const u8* pp = gbytes + (long long)(g*NB_MP + b)*BK_CAP;
  for (int i = t; i < cnt; i += 256) atomicAdd(&hist[pp[i]], 1);
  __syncthreads();
  int dg = (b << 8) + t;
  if (dg < CNU) odeg[g*CNU + dg] = (u16)hist[t];
}

// Pass 2 (UI): one block per bucket; LDS scatter then streaming CSR write + ptr slice.
// Emits rs_ind[node] = h>0 ? rsqrt(h) : zval.
__global__ void k_bucket2(const u32* __restrict__ gpairs, const int* __restrict__ gcur,
                          const int* __restrict__ bbase, int* __restrict__ csr,
                          int* __restrict__ ptr, int n,
                          float* __restrict__ rs_ind, float zval){
  __shared__ int hist[256];
  __shared__ int excl[256];
  __shared__ int lptr[256];
  __shared__ int lsrc[BK_CAP];
  int b = blockIdx.x, t = threadIdx.x;
  int cnt = gcur[b]; if (cnt > BK_CAP) cnt = BK_CAP;
  int base = bbase[b];
  hist[t] = 0;
  __syncthreads();
  const u32* pp = gpairs + (long long)b*BK_CAP;
  for (int i = t; i < cnt; i += 256) atomicAdd(&hist[(pp[i] >> 18) & 255], 1);
  __syncthreads();
  int h = hist[t];
  lptr[t] = h;
  __syncthreads();
  for (int off = 1; off < 256; off <<= 1){
    int u2 = (t >= off) ? lptr[t-off] : 0;
    __syncthreads();
    lptr[t] += u2;
    __syncthreads();
  }
  excl[t] = lptr[t] - h;
  __syncthreads();
  hist[t] = excl[t];
  __syncthreads();
  for (int i = t; i < cnt; i += 256){
    u32 v = pp[i];
    int d = (v >> 18) & 255;
    int p = atomicAdd(&hist[d], 1);
    lsrc[p] = (int)(v & 0x3FFFFu);
  }
  __syncthreads();
  for (int i = t; i < cnt; i += 256) csr[base + i] = lsrc[i];
  int dg = (b << 8) + t;
  if (dg <= n) ptr[dg] = base + excl[t];
  if (dg < n)  rs_ind[dg] = (h > 0) ? rsqrtf((float)h) : zval;
}

// Pass 2 (MP, 2-graph batched): packs csr entries (outdeg<<16 | src); blockIdx.y = graph.
__global__ void k_bucket2b(const u32* __restrict__ gpairs, const int* __restrict__ gcur,
                           const int* __restrict__ bbase, int* __restrict__ csr_base,
                           int* __restrict__ ptr_base, float* __restrict__ rs_base,
                           const u16* __restrict__ odeg){
  __shared__ int hist[256];
  __shared__ int excl[256];
  __shared__ int lptr[256];
  __shared__ int lsrc[BK_CAP];
  int g = blockIdx.y;
  int b = blockIdx.x, t = threadIdx.x;
  int cnt = gcur[g*320 + b]; if (cnt > BK_CAP) cnt = BK_CAP;
  int base = bbase[g*320 + b];
  int* csr = csr_base + (long long)g*CEMP;
  int* ptr = ptr_base + g*(CNU+1);
  float* rs_ind = rs_base + g*80000;
  const u16* od = odeg + g*CNU;
  hist[t] = 0;
  __syncthreads();
  const u32* pp = gpairs + (long long)(g*NB_MP + b)*BK_CAP;
  for (int i = t; i < cnt; i += 256) atomicAdd(&hist[(pp[i] >> 18) & 255], 1);
  __syncthreads();
  int h = hist[t];
  lptr[t] = h;
  __syncthreads();
  for (int off = 1; off < 256; off <<= 1){
    int u2 = (t >= off) ? lptr[t-off] : 0;
    __syncthreads();
    lptr[t] += u2;
    __syncthreads();
  }
  excl[t] = lptr[t] - h;
  __syncthreads();
  hist[t] = excl[t];
  __syncthreads();
  for (int i = t; i < cnt; i += 256){
    u32 v = pp[i];
    int d = (v >> 18) & 255;
    int p = atomicAdd(&hist[d], 1);
    lsrc[p] = (int)(v & 0x3FFFFu);
  }
  __syncthreads();
  for (int i = t; i < cnt; i += 256){
    int s = lsrc[i];
    csr[base + i] = (int)((u32)s | ((u32)od[s] << 16));
  }
  int dg = (b << 8) + t;
  if (dg <= CNU) ptr[dg] = base + excl[t];
  if (dg < CNU)  rs_ind[dg] = (h > 0) ? rsqrtf((float)h) : 1.0f;
}

// ---- gather: 1 wave/row, lane=(g=edge-slot 0..3, c=16B-chunk 0..15) ----
// MP pair variant: blockIdx.y selects metapath (ptr/csr/z). Packed csr (outdeg<<16|src).
__global__ void k_gather_mp2(const u16* __restrict__ h,
                             const int* __restrict__ p0, const int* __restrict__ p1,
                             const u32* __restrict__ c0, const u32* __restrict__ c1,
                             u16* __restrict__ z0o, u16* __restrict__ z1o, int n){
  int row = (blockIdx.x*256 + threadIdx.x) >> 6;
  if (row >= n) return;
  int y = blockIdx.y;
  const int* ptr = y ? p1 : p0;
  const u32* csr = y ? c1 : c0;
  u16* z = y ? z1o : z0o;
  int lane = threadIdx.x & 63;
  int g = lane >> 4, c = lane & 15;
  int p = ptr[row], pe = ptr[row+1];
  float a0=0,a1=0,a2=0,a3=0,a4=0,a5=0,a6=0,a7=0;
  const u16* hb = h + (long long)c*8;
  int pm = p + ((pe - p) & ~15);
  while (p < pm){
    uint4 q[4]; float w[4];
    #pragma unroll
    for (int u = 0; u < 4; ++u){
      u32 e = csr[p + u*4 + g];
      w[u] = rsqrtf((float)(e >> 16));
      q[u] = *(const uint4*)(hb + (long long)(e & 0xFFFFu)*CD);
    }
    #pragma unroll
    for (int u = 0; u < 4; ++u){
      a0 += lo16f(q[u].x)*w[u]; a1 += hi16f(q[u].x)*w[u];
      a2 += lo16f(q[u].y)*w[u]; a3 += hi16f(q[u].y)*w[u];
      a4 += lo16f(q[u].z)*w[u]; a5 += hi16f(q[u].z)*w[u];
      a6 += lo16f(q[u].w)*w[u]; a7 += hi16f(q[u].w)*w[u];
    }
    p += 16;
  }
  if (p < pe){
    uint4 q[4]; float w[4];
    #pragma unroll
    for (int u = 0; u < 4; ++u){
      int ei = p + u*4 + g;
      bool ok = (ei < pe);
      u32 e = ok ? csr[ei] : 0u;
      w[u] = ok ? rsqrtf((float)(e >> 16)) : 0.f;
      q[u] = *(const uint4*)(hb + (long long)(e & 0xFFFFu)*CD);
    }
    #pragma unroll
    for (int u = 0; u < 4; ++u){
      a0 += lo16f(q[u].x)*w[u]; a1 += hi16f(q[u].x)*w[u];
      a2 += lo16f(q[u].y)*w[u]; a3 += hi16f(q[u].y)*w[u];
      a4 += lo16f(q[u].z)*w[u]; a5 += hi16f(q[u].z)*w[u];
      a6 += lo16f(q[u].w)*w[u]; a7 += hi16f(q[u].w)*w[u];
    }
  }
  #pragma unroll
  for (int m = 16; m <= 32; m <<= 1){
    a0 += __shfl_xor(a0, m); a1 += __shfl_xor(a1, m);
    a2 += __shfl_xor(a2, m); a3 += __shfl_xor(a3, m);
    a4 += __shfl_xor(a4, m); a5 += __shfl_xor(a5, m);
    a6 += __shfl_xor(a6, m); a7 += __shfl_xor(a7, m);
  }
  if (g == 0){
    uint4 o;
    o.x = (u32)f2bf(a0) | ((u32)f2bf(a1) << 16);
    o.y = (u32)f2bf(a2) | ((u32)f2bf(a3) << 16);
    o.z = (u32)f2bf(a4) | ((u32)f2bf(a5) << 16);
    o.w = (u32)f2bf(a6) | ((u32)f2bf(a7) << 16);
    *(uint4*)(z + (long long)row*CD + c*8) = o;
  }
}

// UI variant: per-edge w = dinv[src]; main/tail split.
__global__ void k_gather_ui(const u16* __restrict__ xin, const int* __restrict__ ptr,
                            const int* __restrict__ csr_src, const float* __restrict__ dinv,
                            u16* __restrict__ xout, int n){
  int row = (blockIdx.x*256 + threadIdx.x) >> 6;
  if (row >= n) return;
  int lane = threadIdx.x & 63;
  int g = lane >> 4, c = lane & 15;
  int p = ptr[row], pe = ptr[row+1];
  float a0=0,a1=0,a2=0,a3=0,a4=0,a5=0,a6=0,a7=0;
  const u16* hb = xin + (long long)c*8;
  int pm = p + ((pe - p) & ~15);
  while (p < pm){
    uint4 q[4]; float w[4];
    #pragma unroll
    for (int u = 0; u < 4; ++u){
      int s = csr_src[p + u*4 + g];
      w[u] = dinv[s];
      q[u] = *(const uint4*)(hb + (long long)s*CD);
    }
    #pragma unroll
    for (int u = 0; u < 4; ++u){
      a0 += lo16f(q[u].x)*w[u]; a1 += hi16f(q[u].x)*w[u];
      a2 += lo16f(q[u].y)*w[u]; a3 += hi16f(q[u].y)*w[u];
      a4 += lo16f(q[u].z)*w[u]; a5 += hi16f(q[u].z)*w[u];
      a6 += lo16f(q[u].w)*w[u]; a7 += hi16f(q[u].w)*w[u];
    }
    p += 16;
  }
  if (p < pe){
    uint4 q[4]; float w[4];
    #pragma unroll
    for (int u = 0; u < 4; ++u){
      int ei = p + u*4 + g;
      bool ok = (ei < pe);
      int s  = ok ? csr_src[ei] : 0;
      w[u]   = ok ? dinv[s] : 0.f;
      q[u]   = *(const uint4*)(hb + (long long)s*CD);
    }
    #pragma unroll
    for (int u = 0; u < 4; ++u){
      a0 += lo16f(q[u].x)*w[u]; a1 += hi16f(q[u].x)*w[u];
      a2 += lo16f(q[u].y)*w[u]; a3 += hi16f(q[u].y)*w[u];
      a4 += lo16f(q[u].z)*w[u]; a5 += hi16f(q[u].z)*w[u];
      a6 += lo16f(q[u].w)*w[u]; a7 += hi16f(q[u].w)*w[u];
    }
  }
  #pragma unroll
  for (int m = 16; m <= 32; m <<= 1){
    a0 += __shfl_xor(a0, m); a1 += __shfl_xor(a1, m);
    a2 += __shfl_xor(a2, m); a3 += __shfl_xor(a3, m);
    a4 += __shfl_xor(a4, m); a5 += __shfl_xor(a5, m);
    a6 += __shfl_xor(a6, m); a7 += __shfl_xor(a7, m);
  }
  if (g == 0){
    float wd = dinv[row];
    uint4 o;
    o.x = (u32)f2bf(a0*wd) | ((u32)f2bf(a1*wd) << 16);
    o.y = (u32)f2bf(a2*wd) | ((u32)f2bf(a3*wd) << 16);
    o.z = (u32)f2bf(a4*wd) | ((u32)f2bf(a5*wd) << 16);
    o.w = (u32)f2bf(a6*wd) | ((u32)f2bf(a7*wd) << 16);
    *(uint4*)(xout + (long long)row*CD + c*8) = o;
  }
}

// semantic attention scores via MFMA; block-level reduction -> 1 atomic/block
__global__ void k_att(const u16* __restrict__ z0, const u16* __restrict__ z1,
                      const float* __restrict__ rsi0, const float* __restrict__ rsi1,
                      const u16* __restrict__ W1T, const float* __restrict__ b1,
                      const float* __restrict__ W2, float* __restrict__ s_out, int n){
  __shared__ float wred[4];
  int nb = n >> 6;
  int blk = blockIdx.x;
  int ch = (blk >= nb) ? 1 : 0;
  int rb = (ch ? (blk - nb) : blk) * 64;
  const u16* z = ch ? z1 : z0;
  const float* rsi = ch ? rsi1 : rsi0;
  int wv = threadIdx.x >> 6, lane = threadIdx.x & 63;
  int i0 = rb + wv*16;
  int m = lane & 15, kq = lane >> 4;
  bf16x8 a[4];
  #pragma unroll
  for (int t = 0; t < 4; ++t){
    uint4 q = *(const uint4*)(z + (long long)(i0+m)*CD + t*32 + kq*8);
    a[t] = *(bf16x8*)&q;
  }
  float rsv[4];
  #pragma unroll
  for (int ri = 0; ri < 4; ++ri) rsv[ri] = rsi[i0 + kq*4 + ri];
  float psum = 0.f;
  #pragma unroll
  for (int jt = 0; jt < 8; ++jt){
    f32x4 acc = {0.f,0.f,0.f,0.f};
    #pragma unroll
    for (int t = 0; t < 4; ++t){
      uint4 qb = *(const uint4*)(W1T + (jt*16 + m)*CD + t*32 + kq*8);
      bf16x8 b = *(bf16x8*)&qb;
      acc = __builtin_amdgcn_mfma_f32_16x16x32_bf16(a[t], b, acc, 0, 0, 0);
    }
    int j = jt*16 + m;
    float bb = b1[j], w2 = W2[j];
    #pragma unroll
    for (int ri = 0; ri < 4; ++ri){
      float x = acc[ri]*rsv[ri] + bb;
      x = fminf(fmaxf(x, -15.f), 15.f);
      float t2 = __expf(2.f*x);
      psum += ((t2 - 1.f)/(t2 + 1.f))*w2;
    }
  }
  #pragma unroll
  for (int msk = 1; msk <= 32; msk <<= 1) psum += __shfl_xor(psum, msk);
  if (lane == 0) wred[wv] = psum;
  __syncthreads();
  if (threadIdx.x == 0)
    atomicAdd(&s_out[ch], wred[0] + wred[1] + wred[2] + wred[3]);
}

__global__ void k_combine(const u16* __restrict__ z0, const u16* __restrict__ z1,
                          const float* __restrict__ rsi0, const float* __restrict__ rsi1,
                          const float* __restrict__ s, u16* __restrict__ h, int n){
  int idx = blockIdx.x*256 + threadIdx.x;
  if (idx >= n*CD) return;
  int v = idx >> 7;
  float s0 = s[0]*(1.0f/n), s1 = s[1]*(1.0f/n);
  float m = fmaxf(s0, s1);
  float e0 = __expf(s0 - m), e1 = __expf(s1 - m);
  float r = 1.0f/(e0 + e1);
  h[idx] = f2bf((e0*r)*bf2f(z0[idx])*rsi0[v] + (e1*r)*bf2f(z1[idx])*rsi1[v]);
}

__global__ void k_emb(const u16* __restrict__ x2, u16* __restrict__ h_u,
                      u16* __restrict__ h_i){
  int idx = blockIdx.x*256 + threadIdx.x;
  if (idx >= CNN*CD) return;
  if (idx < CNU*CD) h_u[idx] = f2bf(0.5f*bf2f(h_u[idx]) + 0.5f*bf2f(x2[idx]));
  else { int k = idx - CNU*CD; h_i[k] = f2bf(0.5f*bf2f(h_i[k]) + 0.5f*bf2f(x2[idx])); }
}

// both SSL sides in one launch; blockIdx.y = side (0=user,1=item)
__global__ void k_sslnorm2(const u16* __restrict__ x2, const u16* __restrict__ hu,
                           const u16* __restrict__ hi,
                           const int* __restrict__ uidx, const int* __restrict__ iidx,
                           u16* __restrict__ nbase, float* __restrict__ misc){
  __shared__ float wred[4];
  int side = blockIdx.y;
  const int* idx = side ? iidx : uidx;
  const u16* hemb = side ? hi : hu;
  int rowoff = side ? CNU : 0;
  u16* n1b = nbase + (long long)side*2*CB*CD;
  u16* n2b = n1b + (long long)CB*CD;
  float* pos_acc = misc + 12 + 2*side;
  int wv = threadIdx.x >> 6, lane = threadIdx.x & 63;
  int r0 = blockIdx.x*16 + wv*4;
  int g[4]; u32 q1[4], q2[4];
  #pragma unroll
  for (int u = 0; u < 4; ++u){
    g[u] = idx[r0 + u];
    q1[u] = *(const u32*)(x2 + (long long)(g[u] + rowoff)*CD + lane*2);
    q2[u] = *(const u32*)(hemb + (long long)g[u]*CD + lane*2);
  }
  float psum = 0.f;
  #pragma unroll
  for (int u = 0; u < 4; ++u){
    float a0 = lo16f(q1[u]), a1 = hi16f(q1[u]);
    float b0 = lo16f(q2[u]), b1 = hi16f(q2[u]);
    float s1 = a0*a0 + a1*a1, s2 = b0*b0 + b1*b1, s12 = a0*b0 + a1*b1;
    #pragma unroll
    for (int msk = 1; msk <= 32; msk <<= 1){
      s1  += __shfl_xor(s1, msk);
      s2  += __shfl_xor(s2, msk);
      s12 += __shfl_xor(s12, msk);
    }
    float i1 = 1.0f / fmaxf(sqrtf(s1), 1e-12f);
    float i2 = 1.0f / fmaxf(sqrtf(s2), 1e-12f);
    *(u32*)(n1b + (long long)(r0+u)*CD + lane*2) = (u32)f2bf(a0*i1) | ((u32)f2bf(a1*i1) << 16);
    *(u32*)(n2b + (long long)(r0+u)*CD + lane*2) = (u32)f2bf(b0*i2) | ((u32)f2bf(b1*i2) << 16);
    psum += s12*i1*i2*2.0f;
  }
  if (lane == 0) wred[wv] = psum;
  __syncthreads();
  if (threadIdx.x == 0)
    atomicAdd(pos_acc, wred[0] + wred[1] + wred[2] + wred[3]);
}

// alls[i] += sum_j exp(2 * n1_i . n2_j); blockIdx.z = side.
__global__ void __launch_bounds__(256, 2)
k_alls2(const u16* __restrict__ nbase, float* __restrict__ alls){
  int side = blockIdx.z;
  const u16* n1b = nbase + (long long)side*2*CB*CD;
  const u16* n2b = n1b + (long long)CB*CD;
  float* al = alls + side*CB;
  int wv = threadIdx.x >> 6;
  int lane = threadIdx.x & 63;
  int m = lane & 15, kq = lane >> 4;
  int i0 = (blockIdx.x*4 + wv)*64;
  bf16x8 a[4][4];
  #pragma unroll
  for (int c = 0; c < 4; ++c){
    #pragma unroll
    for (int t = 0; t < 4; ++t){
      uint4 q = *(const uint4*)(n1b + (long long)(i0 + c*16 + m)*CD + t*32 + kq*8);
      a[c][t] = *(bf16x8*)&q;
    }
  }
  float es[4][4];
  #pragma unroll
  for (int c = 0; c < 4; ++c)
    #pragma unroll
    for (int ri = 0; ri < 4; ++ri) es[c][ri] = 0.f;

  const u16* jb = n2b + (long long)(blockIdx.y*512 + m)*CD + kq*8;
  uint4 q[4];
  #pragma unroll
  for (int t = 0; t < 4; ++t) q[t] = *(const uint4*)(jb + t*32);
  for (int jt = 0; jt < 32; ++jt){
    uint4 qn[4];
    if (jt < 31){
      const u16* jb2 = jb + (long long)(jt+1)*16*CD;
      #pragma unroll
      for (int t = 0; t < 4; ++t) qn[t] = *(const uint4*)(jb2 + t*32);
    }
    f32x4 ac[4];
    #pragma unroll
    for (int c = 0; c < 4; ++c) ac[c] = (f32x4){0.f,0.f,0.f,0.f};
    #pragma unroll
    for (int t = 0; t < 4; ++t){
      bf16x8 b = *(bf16x8*)&q[t];
      #pragma unroll
      for (int c = 0; c < 4; ++c)
        ac[c] = __builtin_amdgcn_mfma_f32_16x16x32_bf16(a[c][t], b, ac[c], 0, 0, 0);
    }
    #pragma unroll
    for (int c = 0; c < 4; ++c)
      #pragma unroll
      for (int ri = 0; ri < 4; ++ri)
        es[c][ri] += __expf(ac[c][ri]*2.f);
    if (jt < 31){
      #pragma unroll
      for (int t = 0; t < 4; ++t) q[t] = qn[t];
    }
  }
  #pragma unroll
  for (int c = 0; c < 4; ++c){
    #pragma unroll
    for (int ri = 0; ri < 4; ++ri){
      float v = es[c][ri];
      #pragma unroll
      for (int msk = 1; msk <= 8; msk <<= 1) v += __shfl_xor(v, msk);
      if (m == 0) atomicAdd(&al[i0 + c*16 + kq*4 + ri], v);
    }
  }
}

__global__ void k_logsum(const float* __restrict__ alls, float* __restrict__ misc){
  int i = blockIdx.x*256 + threadIdx.x;
  float v = logf(alls[i]);
  for (int off = 32; off > 0; off >>= 1) v += __shfl_down(v, off);
  if ((threadIdx.x & 63) == 0) atomicAdd(&misc[(i < CB) ? 13 : 15], v);
}

// all 3 output GEMM+LN slabs in one launch; blockIdx.y = slab.
__global__ void k_final3(const u16* __restrict__ hu, const u16* __restrict__ hi,
                         const int* __restrict__ uidx, const int* __restrict__ iidx,
                         const int* __restrict__ nidx,
                         const float* __restrict__ uW, const float* __restrict__ ub,
                         const float* __restrict__ iW, const float* __restrict__ ib,
                         const float* __restrict__ lg, const float* __restrict__ lb,
                         float* __restrict__ outp){
  __shared__ float A[8][128];
  __shared__ float red[8][4];
  int y = blockIdx.y;
  const u16* emb = (y == 0) ? hu : hi;
  const int* idx = (y == 0) ? uidx : ((y == 1) ? iidx : nidx);
  const float* W = (y == 0) ? uW : iW;
  const float* bias = (y == 0) ? ub : ib;
  float* outb = outp + (long long)y*CB*CD;
  int j = threadIdx.x;
  int r0 = blockIdx.x*8;
  for (int r = 0; r < 8; ++r){
    int g = idx[r0 + r];
    A[r][j] = bf2f(emb[(long long)g*CD + j]);
  }
  __syncthreads();
  float acc[8];
  #pragma unroll
  for (int r = 0; r < 8; ++r) acc[r] = 0.f;
  for (int k = 0; k < 128; k += 4){
    float w0 = W[(k+0)*128 + j];
    float w1 = W[(k+1)*128 + j];
    float w2 = W[(k+2)*128 + j];
    float w3 = W[(k+3)*128 + j];
    #pragma unroll
    for (int r = 0; r < 8; ++r){
      float4 a = *(const float4*)&A[r][k];
      acc[r] += a.x*w0 + a.y*w1 + a.z*w2 + a.w*w3;
    }
  }
  float bb = bias[j];
  #pragma unroll
  for (int r = 0; r < 8; ++r){
    float v = acc[r] + bb;
    acc[r] = (v < 0.f) ? 0.f : v;
  }
  int wid = j >> 6, lane = j & 63;
  #pragma unroll
  for (int r = 0; r < 8; ++r){
    float s = acc[r], q = acc[r]*acc[r];
    for (int off = 32; off > 0; off >>= 1){
      s += __shfl_down(s, off); q += __shfl_down(q, off);
    }
    if (lane == 0){ red[r][wid*2] = s; red[r][wid*2+1] = q; }
  }
  __syncthreads();
  float gg = lg[j], be = lb[j];
  #pragma unroll
  for (int r = 0; r < 8; ++r){
    float mu = (red[r][0] + red[r][2]) * (1.0f/128.0f);
    float ms = (red[r][1] + red[r][3]) * (1.0f/128.0f);
    float var = ms - mu*mu;
    float yv = (acc[r] - mu) * rsqrtf(var + 1e-5f) * gg + be;
    outb[(long long)(r0 + r)*CD + j] = yv;
  }
}

__global__ void k_loss(const float* __restrict__ misc, float* __restrict__ o){
  float lu = (misc[13] - misc[12]) * (1.0f/CB);
  float li = (misc[15] - misc[14]) * (1.0f/CB);
  o[0] = 0.4f*(lu + li);
}

extern "C" void kernel_launch(void* const* d_in, const int* in_sizes, int n_in,
                              void* d_out, int out_size, void* d_ws, size_t ws_size,
                              hipStream_t stream){
  (void)in_sizes; (void)n_in; (void)out_size; (void)ws_size;
  const float* feat_user = (const float*)d_in[0];
  const float* feat_item = (const float*)d_in[1];
  const float* u_W1 = (const float*)d_in[2];
  const float* u_b1 = (const float*)d_in[3];
  const float* u_W2 = (const float*)d_in[4];
  const float* i_W1 = (const float*)d_in[5];
  const float* i_b1 = (const float*)d_in[6];
  const float* i_W2 = (const float*)d_in[7];
  const float* user_W = (const float*)d_in[8];
  const float* user_b = (const float*)d_in[9];
  const float* item_W = (const float*)d_in[10];
  const float* item_b = (const float*)d_in[11];
  const float* ln_g = (const float*)d_in[12];
  const float* ln_b = (const float*)d_in[13];
  const int* ump0s = (const int*)d_in[14]; const int* ump0d = (const int*)d_in[15];
  const int* ump1s = (const int*)d_in[16]; const int* ump1d = (const int*)d_in[17];
  const int* imp0s = (const int*)d_in[18]; const int* imp0d = (const int*)d_in[19];
  const int* imp1s = (const int*)d_in[20]; const int* imp1d = (const int*)d_in[21];
  const int* ui_row = (const int*)d_in[22]; const int* ui_col = (const int*)d_in[23];
  const int* user_idx = (const int*)d_in[24]; const int* item_idx = (const int*)d_in[25];
  const int* neg_idx = (const int*)d_in[26];

  u16* W  = (u16*)d_ws;
  u16* fb = W;                      // 10,240,000 bf16
  u16* hu = W + 10240000LL;
  u16* hi = W + 15360000LL;
  u16* xb = W + 20480000LL;
  u16* x2 = W + 30720000LL;
  u16* z0 = W + 40960000LL;
  u16* z1 = W + 46080000LL;
  float* F   = (float*)(W + 51200000LL);
  float* rs  = F;                   // 320,000 (indeg tables at +40000..; [0..40000) = odeg u16 scratch x2)
  float* dinv= F + 320000;          // 80,000
  float* alls= F + 400000;          // 16,384
  float* misc= F + 416384;          // 64
  int* I     = (int*)(F + 416448);
  int* mp_p0 = I;                   // 2 x 40,001 (batched pair: p0, p1 contiguous)
  int* gcur  = I + 80002;           // 640 (2 graphs x 320)
  int* bbase = I + 80642;           // 640
  int* gcur2 = I + 81282;           // 640
  int* mp_c0 = I + 120002;          // 2 x 640,000 (batched pair: c0, c1 contiguous)
  u16* w1tu  = (u16*)(I + 1400128); // 16,384 bf16 (W1^T user)
  u16* w1ti  = w1tu + 16384;        // 16,384 bf16 (W1^T item)
  u16* odeg  = (u16*)rs;            // 2 x 40,000 u16 scratch (rs[0..40000) floats)
  int* mp_p1 = mp_p0 + (CNU+1);
  int* mp_c1 = mp_c0 + CEMP;
  int* ui_ptr    = (int*)hu;        // overlay (hu/hi dead until first combine)
  int* ui_csr    = ui_ptr + 160001; // 1,600,000 ints
  u32* gpairsU   = (u32*)z0;        // UI build: 313*8064*4B = 10.1MB (z0 dead during builds)
  u32* gpairs2   = (u32*)xb;        // MP batched pair: 2*157*8064*4B = 10.1MB (xb dead after UI hop 3)
  u8*  gbytes2   = (u8*)z1;         // MP batched pair: 2*157*8064 B = 2.5MB (z1 dead during builds)
  u16* nbase = xb;                  // SSL overlay: n1u,n2u,n1i,n2i (xb dead after MP builds done... SSL after loops)
  float* out = (float*)d_out;

  k_zero<<<(16448 + 255)/256, 256, 0, stream>>>(alls, 16448);
  k_initb<<<40064, 256, 0, stream>>>(feat_user, feat_item, fb, u_W1, i_W1, w1tu, w1ti);

  // UI CSR build (counting sort; NB=313 buckets of 256 dst); dinv emitted by pass 2.
  k_izero<<<8, 256, 0, stream>>>(gcur, 1920);
  k_bucket1<<<(CEUI + P1_CHUNK - 1)/P1_CHUNK, 256, 0, stream>>>(ui_col, ui_row, gcur, gpairsU, CEUI, 313);
  k_scanb<<<1, 512, 0, stream>>>(gcur, bbase, 313);
  k_bucket2<<<313, 256, 0, stream>>>(gpairsU, gcur, bbase, ui_csr, ui_ptr, CNN, dinv, 0.0f);

  // UI propagation: fb -> x2 -> xb -> x2   (xb free after this)
  k_gather_ui<<<20000, 256, 0, stream>>>(fb, ui_ptr, ui_csr, dinv, x2, CNN);
  k_gather_ui<<<20000, 256, 0, stream>>>(x2, ui_ptr, ui_csr, dinv, xb, CNN);
  k_gather_ui<<<20000, 256, 0, stream>>>(xb, ui_ptr, ui_csr, dinv, x2, CNN);

  dim3 mpgrid((CEMP + P1_CHUNK - 1)/P1_CHUNK, 2);
  // user MP pair build (batched): outdeg packed into csr, indeg rsqrt -> rs+40000/+120000
  k_izero<<<8, 256, 0, stream>>>(gcur, 1920);
  k_bucket1b2<<<mpgrid, 256, 0, stream>>>(ump0s, ump0d, ump1s, ump1d, gcur, gpairs2, gcur2, gbytes2);
  k_scanb<<<2, 512, 0, stream>>>(gcur, bbase, NB_MP);
  k_odeg2<<<dim3(NB_MP, 2), 256, 0, stream>>>(gbytes2, gcur2, odeg);
  k_bucket2b<<<dim3(NB_MP, 2), 256, 0, stream>>>(gpairs2, gcur, bbase, mp_c0, mp_p0, rs + 40000, odeg);
  for (int L = 0; L < 3; ++L){
    const u16* hin = (L == 0) ? fb : hu;
    k_gather_mp2<<<dim3(10000, 2), 256, 0, stream>>>(hin, mp_p0, mp_p1,
                  (const u32*)mp_c0, (const u32*)mp_c1, z0, z1, CNU);
    k_att<<<1250, 256, 0, stream>>>(z0, z1, rs + 40000, rs + 120000,
                                    w1tu, u_b1, u_W2, misc + 2*L, CNU);
    k_combine<<<20000, 256, 0, stream>>>(z0, z1, rs + 40000, rs + 120000,
                                         misc + 2*L, hu, CNU);
  }
  // item MP pair build (z0/z1/xb dead between loops -> overlays safe)
  k_izero<<<8, 256, 0, stream>>>(gcur, 1920);
  k_bucket1b2<<<mpgrid, 256, 0, stream>>>(imp0s, imp0d, imp1s, imp1d, gcur, gpairs2, gcur2, gbytes2);
  k_scanb<<<2, 512, 0, stream>>>(gcur, bbase, NB_MP);
  k_odeg2<<<dim3(NB_MP, 2), 256, 0, stream>>>(gbytes2, gcur2, odeg);
  k_bucket2b<<<dim3(NB_MP, 2), 256, 0, stream>>>(gpairs2, gcur, bbase, mp_c0, mp_p0, rs + 200000, odeg);
  for (int L = 0; L < 3; ++L){
    const u16* hin = (L == 0) ? (fb + (long long)CNU*CD) : hi;
    k_gather_mp2<<<dim3(10000, 2), 256, 0, stream>>>(hin, mp_p0, mp_p1,
                  (const u32*)mp_c0, (const u32*)mp_c1, z0, z1, CNU);
    k_att<<<1250, 256, 0, stream>>>(z0, z1, rs + 200000, rs + 280000,
                                    w1ti, i_b1, i_W2, misc + 6 + 2*L, CNU);
    k_combine<<<20000, 256, 0, stream>>>(z0, z1, rs + 200000, rs + 280000,
                                         misc + 6 + 2*L, hi, CNU);
  }

  k_emb<<<40000, 256, 0, stream>>>(x2, hu, hi);

  // SSL (both sides per launch)
  k_sslnorm2<<<dim3(CB/16, 2), 256, 0, stream>>>(x2, hu, hi, user_idx, item_idx, nbase, misc);
  k_alls2<<<dim3(32, 16, 2), 256, 0, stream>>>(nbase, alls);
  k_logsum<<<64, 256, 0, stream>>>(alls, misc);

  k_final3<<<dim3(1024, 3), 128, 0, stream>>>(hu, hi, user_idx, item_idx, neg_idx,
                                              user_W, user_b, item_W, item_b,
                                              ln_g, ln_b, out);
  k_loss<<<1, 1, 0, stream>>>(misc, out + 3LL*CB*CD);
}

// Round 8
// 1035.146 us; speedup vs baseline: 2.4383x; 1.0896x over previous
//
#include <hip/hip_runtime.h>
#include <math.h>

typedef unsigned short u16;
typedef unsigned int u32;
typedef unsigned char u8;
typedef __attribute__((ext_vector_type(8))) short bf16x8;
typedef __attribute__((ext_vector_type(4))) float f32x4;

#define CNU 40000
#define CNN 80000
#define CD  128
#define CEMP 640000
#define CEUI 1600000
#define CB  8192

#define BK_CAP 8064     // per-bucket capacity (mean 5120 UI / 4096 MP; >40 sigma margin)
#define P1_CHUNK 4096   // edges per block in bucket pass 1 (16/thread)
#define NB_MP 157       // MP bucket count (40000/256 rounded up)

__device__ __forceinline__ float bf2f(u16 b){
  union { u32 u; float f; } v; v.u = ((u32)b) << 16; return v.f;
}
__device__ __forceinline__ u16 f2bf(float f){
  union { float f; u32 u; } v; v.f = f;
  u32 u = v.u + 0x7FFFu + ((v.u >> 16) & 1u);
  return (u16)(u >> 16);
}
__device__ __forceinline__ float lo16f(u32 q){ union { u32 u; float f; } v; v.u = q << 16; return v.f; }
__device__ __forceinline__ float hi16f(u32 q){ union { u32 u; float f; } v; v.u = q & 0xFFFF0000u; return v.f; }

__global__ void k_zero(float* __restrict__ p, long long n){
  long long i = (long long)blockIdx.x*256 + threadIdx.x;
  if (i < n) p[i] = 0.f;
}

__global__ void k_izero(int* __restrict__ p, int n){
  int i = blockIdx.x*256 + threadIdx.x;
  if (i < n) p[i] = 0;
}

// fused: feature f32->bf16 cast (blocks 0..39999) + W1 transpose (blocks 40000..40063)
__global__ void k_initb(const float* __restrict__ fu, const float* __restrict__ fi,
                        u16* __restrict__ fb,
                        const float* __restrict__ Wu, const float* __restrict__ Wi,
                        u16* __restrict__ Wut, u16* __restrict__ Wit){
  int b = blockIdx.x;
  if (b < 40000){
    int idx = b*256 + threadIdx.x;
    float v = (idx < CNU*CD) ? fu[idx] : fi[idx - CNU*CD];
    fb[idx] = f2bf(v);
  } else {
    int idx = (b - 40000)*256 + threadIdx.x;
    if (idx < 16384){
      int k = idx >> 7, j = idx & 127;
      Wut[j*128 + k] = f2bf(Wu[idx]);
      Wit[j*128 + k] = f2bf(Wi[idx]);
    }
  }
}

// ---- CSR build via LDS-aggregated counting sort ----
// Pass 1 (UI variant): dst-keyed pair scatter only.
__global__ void k_bucket1(const int* __restrict__ src, const int* __restrict__ dst,
                          int* __restrict__ gcur, u32* __restrict__ gpairs,
                          int E, int NB){
  __shared__ int cnt[320];
  __shared__ int sbase[320];
  int t = threadIdx.x;
  for (int i = t; i < NB; i += 256) cnt[i] = 0;
  __syncthreads();
  int base = blockIdx.x * P1_CHUNK;
  int r[16], dv[16], sv[16];
  #pragma unroll
  for (int u = 0; u < 16; ++u){
    int e = base + u*256 + t;
    bool ok = (e < E);
    dv[u] = ok ? dst[e] : -1;
    sv[u] = ok ? src[e] : 0;
    if (ok) r[u] = atomicAdd(&cnt[dv[u] >> 8], 1);
  }
  __syncthreads();
  for (int i = t; i < NB; i += 256){
    int c = cnt[i];
    sbase[i] = c ? atomicAdd(&gcur[i], c) : 0;
  }
  __syncthreads();
  #pragma unroll
  for (int u = 0; u < 16; ++u){
    if (dv[u] >= 0){
      int b = dv[u] >> 8;
      int p = sbase[b] + r[u];
      if (p < BK_CAP)
        gpairs[(long long)b*BK_CAP + p] = (u32)sv[u] | ((u32)(dv[u] & 255) << 18);
    }
  }
}

// Pass 1 (MP, 4-graph batched): dst-keyed pair scatter + src-keyed byte scatter.
// blockIdx.y = graph id (0..3).
__global__ void k_bucket1b4(const int* __restrict__ s0, const int* __restrict__ d0,
                            const int* __restrict__ s1, const int* __restrict__ d1,
                            const int* __restrict__ s2, const int* __restrict__ d2,
                            const int* __restrict__ s3, const int* __restrict__ d3,
                            int* __restrict__ gcur, u32* __restrict__ gpairs,
                            int* __restrict__ gcur2, u8* __restrict__ gbytes){
  __shared__ int cnt[320], sbase[320], cnt2[320], sbase2[320];
  int g = blockIdx.y;
  const int* src = (g==0) ? s0 : (g==1) ? s1 : (g==2) ? s2 : s3;
  const int* dst = (g==0) ? d0 : (g==1) ? d1 : (g==2) ? d2 : d3;
  int* gc  = gcur  + g*320;
  int* gc2 = gcur2 + g*320;
  u32* gp  = gpairs + (long long)g*NB_MP*BK_CAP;
  u8*  gb  = gbytes + (long long)g*NB_MP*BK_CAP;
  int t = threadIdx.x;
  for (int i = t; i < NB_MP; i += 256){ cnt[i] = 0; cnt2[i] = 0; }
  __syncthreads();
  int base = blockIdx.x * P1_CHUNK;
  int r[16], r2[16], dv[16], sv[16];
  #pragma unroll
  for (int u = 0; u < 16; ++u){
    int e = base + u*256 + t;
    bool ok = (e < CEMP);
    dv[u] = ok ? dst[e] : -1;
    sv[u] = ok ? src[e] : -1;
    if (ok){
      r[u]  = atomicAdd(&cnt[dv[u] >> 8], 1);
      r2[u] = atomicAdd(&cnt2[sv[u] >> 8], 1);
    }
  }
  __syncthreads();
  for (int i = t; i < NB_MP; i += 256){
    int c  = cnt[i];  sbase[i]  = c  ? atomicAdd(&gc[i],  c)  : 0;
    int c2 = cnt2[i]; sbase2[i] = c2 ? atomicAdd(&gc2[i], c2) : 0;
  }
  __syncthreads();
  #pragma unroll
  for (int u = 0; u < 16; ++u){
    if (dv[u] >= 0){
      int b = dv[u] >> 8;
      int p = sbase[b] + r[u];
      if (p < BK_CAP)
        gp[(long long)b*BK_CAP + p] = (u32)sv[u] | ((u32)(dv[u] & 255) << 18);
      int b2 = sv[u] >> 8;
      int p2 = sbase2[b2] + r2[u];
      if (p2 < BK_CAP)
        gb[(long long)b2*BK_CAP + p2] = (u8)(sv[u] & 255);
    }
  }
}

// exclusive scan of bucket counts; blockIdx.x = graph slice (stride 320).
__global__ void k_scanb(const int* __restrict__ gcur, int* __restrict__ bbase, int NB){
  __shared__ int s[512];
  int g = blockIdx.x;
  const int* gc = gcur + g*320;
  int* bb = bbase + g*320;
  int t = threadIdx.x;
  int v = (t < NB) ? gc[t] : 0;
  s[t] = v;
  __syncthreads();
  for (int off = 1; off < 512; off <<= 1){
    int u = (t >= off) ? s[t-off] : 0;
    __syncthreads();
    s[t] += u;
    __syncthreads();
  }
  if (t < NB) bb[t] = s[t] - v;
}

// Count-only pass over src byte-buckets -> u16 out-degree table; blockIdx.y = graph.
__global__ void k_odeg4(const u8* __restrict__ gbytes, const int* __restrict__ gcur2,
                        u16* __restrict__ odeg){
  __shared__ int hist[256];
  int g = blockIdx.y;
  int b = blockIdx.x, t = threadIdx.x;
  hist[t] = 0;
  __syncthreads();
  int cnt = gcur2[g*320 + b]; if (cnt > BK_CAP) cnt = BK_CAP;
  const u8* pp = gbytes + (long long)(g*NB_MP + b)*BK_CAP;
  for (int i = t; i < cnt; i += 256) atomicAdd(&hist[pp[i]], 1);
  __syncthreads();
  int dg = (b << 8) + t;
  if (dg < CNU) odeg[g*CNU + dg] = (u16)hist[t];
}

// Pass 2 (UI): one block per bucket; LDS scatter then streaming CSR write + ptr slice.
__global__ void k_bucket2(const u32* __restrict__ gpairs, const int* __restrict__ gcur,
                          const int* __restrict__ bbase, int* __restrict__ csr,
                          int* __restrict__ ptr, int n,
                          float* __restrict__ rs_ind, float zval){
  __shared__ int hist[256];
  __shared__ int excl[256];
  __shared__ int lptr[256];
  __shared__ int lsrc[BK_CAP];
  int b = blockIdx.x, t = threadIdx.x;
  int cnt = gcur[b]; if (cnt > BK_CAP) cnt = BK_CAP;
  int base = bbase[b];
  hist[t] = 0;
  __syncthreads();
  const u32* pp = gpairs + (long long)b*BK_CAP;
  for (int i = t; i < cnt; i += 256) atomicAdd(&hist[(pp[i] >> 18) & 255], 1);
  __syncthreads();
  int h = hist[t];
  lptr[t] = h;
  __syncthreads();
  for (int off = 1; off < 256; off <<= 1){
    int u2 = (t >= off) ? lptr[t-off] : 0;
    __syncthreads();
    lptr[t] += u2;
    __syncthreads();
  }
  excl[t] = lptr[t] - h;
  __syncthreads();
  hist[t] = excl[t];
  __syncthreads();
  for (int i = t; i < cnt; i += 256){
    u32 v = pp[i];
    int d = (v >> 18) & 255;
    int p = atomicAdd(&hist[d], 1);
    lsrc[p] = (int)(v & 0x3FFFFu);
  }
  __syncthreads();
  for (int i = t; i < cnt; i += 256) csr[base + i] = lsrc[i];
  int dg = (b << 8) + t;
  if (dg <= n) ptr[dg] = base + excl[t];
  if (dg < n)  rs_ind[dg] = (h > 0) ? rsqrtf((float)h) : zval;
}

// Pass 2 (MP, 4-graph batched): packs csr entries (outdeg<<16 | src); blockIdx.y = graph.
__global__ void k_bucket2b4(const u32* __restrict__ gpairs, const int* __restrict__ gcur,
                            const int* __restrict__ bbase, int* __restrict__ csr_base,
                            int* __restrict__ ptr_base, float* __restrict__ rs40k,
                            const u16* __restrict__ odeg){
  __shared__ int hist[256];
  __shared__ int excl[256];
  __shared__ int lptr[256];
  __shared__ int lsrc[BK_CAP];
  int g = blockIdx.y;
  int b = blockIdx.x, t = threadIdx.x;
  int cnt = gcur[g*320 + b]; if (cnt > BK_CAP) cnt = BK_CAP;
  int base = bbase[g*320 + b];
  int* csr = csr_base + (long long)g*CEMP;
  int* ptr = ptr_base + g*(CNU+1);
  float* rs_ind = rs40k + g*80000;
  const u16* od = odeg + g*CNU;
  hist[t] = 0;
  __syncthreads();
  const u32* pp = gpairs + (long long)(g*NB_MP + b)*BK_CAP;
  for (int i = t; i < cnt; i += 256) atomicAdd(&hist[(pp[i] >> 18) & 255], 1);
  __syncthreads();
  int h = hist[t];
  lptr[t] = h;
  __syncthreads();
  for (int off = 1; off < 256; off <<= 1){
    int u2 = (t >= off) ? lptr[t-off] : 0;
    __syncthreads();
    lptr[t] += u2;
    __syncthreads();
  }
  excl[t] = lptr[t] - h;
  __syncthreads();
  hist[t] = excl[t];
  __syncthreads();
  for (int i = t; i < cnt; i += 256){
    u32 v = pp[i];
    int d = (v >> 18) & 255;
    int p = atomicAdd(&hist[d], 1);
    lsrc[p] = (int)(v & 0x3FFFFu);
  }
  __syncthreads();
  for (int i = t; i < cnt; i += 256){
    int s = lsrc[i];
    csr[base + i] = (int)((u32)s | ((u32)od[s] << 16));
  }
  int dg = (b << 8) + t;
  if (dg <= CNU) ptr[dg] = base + excl[t];
  if (dg < CNU)  rs_ind[dg] = (h > 0) ? rsqrtf((float)h) : 1.0f;
}

// ---- gather: 1 wave/row, lane=(g=edge-slot 0..3, c=16B-chunk 0..15) ----
// MP 4-way variant: blockIdx.y = graph (0,1=user mp0/mp1; 2,3=item mp0/mp1).
__global__ void k_gather_mp4(const u16* __restrict__ fb, const u16* __restrict__ hu,
                             const u16* __restrict__ hi, int L,
                             const int* __restrict__ ptr_base, const u32* __restrict__ csr_base,
                             u16* __restrict__ z0base, u16* __restrict__ z2base){
  int row = (blockIdx.x*256 + threadIdx.x) >> 6;
  if (row >= CNU) return;
  int y = blockIdx.y;
  int side = y >> 1;
  const u16* h = (L == 0) ? (fb + (long long)side*CNU*CD) : (side ? hi : hu);
  const int* ptr = ptr_base + y*(CNU+1);
  const u32* csr = csr_base + (long long)y*CEMP;
  u16* z = (y < 2) ? (z0base + (long long)y*CNU*CD) : (z2base + (long long)(y-2)*CNU*CD);
  int lane = threadIdx.x & 63;
  int g = lane >> 4, c = lane & 15;
  int p = ptr[row], pe = ptr[row+1];
  float a0=0,a1=0,a2=0,a3=0,a4=0,a5=0,a6=0,a7=0;
  const u16* hb = h + (long long)c*8;
  int pm = p + ((pe - p) & ~15);
  while (p < pm){
    uint4 q[4]; float w[4];
    #pragma unroll
    for (int u = 0; u < 4; ++u){
      u32 e = csr[p + u*4 + g];
      w[u] = rsqrtf((float)(e >> 16));
      q[u] = *(const uint4*)(hb + (long long)(e & 0xFFFFu)*CD);
    }
    #pragma unroll
    for (int u = 0; u < 4; ++u){
      a0 += lo16f(q[u].x)*w[u]; a1 += hi16f(q[u].x)*w[u];
      a2 += lo16f(q[u].y)*w[u]; a3 += hi16f(q[u].y)*w[u];
      a4 += lo16f(q[u].z)*w[u]; a5 += hi16f(q[u].z)*w[u];
      a6 += lo16f(q[u].w)*w[u]; a7 += hi16f(q[u].w)*w[u];
    }
    p += 16;
  }
  if (p < pe){
    uint4 q[4]; float w[4];
    #pragma unroll
    for (int u = 0; u < 4; ++u){
      int ei = p + u*4 + g;
      bool ok = (ei < pe);
      u32 e = ok ? csr[ei] : 0u;
      w[u] = ok ? rsqrtf((float)(e >> 16)) : 0.f;
      q[u] = *(const uint4*)(hb + (long long)(e & 0xFFFFu)*CD);
    }
    #pragma unroll
    for (int u = 0; u < 4; ++u){
      a0 += lo16f(q[u].x)*w[u]; a1 += hi16f(q[u].x)*w[u];
      a2 += lo16f(q[u].y)*w[u]; a3 += hi16f(q[u].y)*w[u];
      a4 += lo16f(q[u].z)*w[u]; a5 += hi16f(q[u].z)*w[u];
      a6 += lo16f(q[u].w)*w[u]; a7 += hi16f(q[u].w)*w[u];
    }
  }
  #pragma unroll
  for (int m = 16; m <= 32; m <<= 1){
    a0 += __shfl_xor(a0, m); a1 += __shfl_xor(a1, m);
    a2 += __shfl_xor(a2, m); a3 += __shfl_xor(a3, m);
    a4 += __shfl_xor(a4, m); a5 += __shfl_xor(a5, m);
    a6 += __shfl_xor(a6, m); a7 += __shfl_xor(a7, m);
  }
  if (g == 0){
    uint4 o;
    o.x = (u32)f2bf(a0) | ((u32)f2bf(a1) << 16);
    o.y = (u32)f2bf(a2) | ((u32)f2bf(a3) << 16);
    o.z = (u32)f2bf(a4) | ((u32)f2bf(a5) << 16);
    o.w = (u32)f2bf(a6) | ((u32)f2bf(a7) << 16);
    *(uint4*)(z + (long long)row*CD + c*8) = o;
  }
}

// UI variant: per-edge w = dinv[src]; main/tail split.
__global__ void k_gather_ui(const u16* __restrict__ xin, const int* __restrict__ ptr,
                            const int* __restrict__ csr_src, const float* __restrict__ dinv,
                            u16* __restrict__ xout, int n){
  int row = (blockIdx.x*256 + threadIdx.x) >> 6;
  if (row >= n) return;
  int lane = threadIdx.x & 63;
  int g = lane >> 4, c = lane & 15;
  int p = ptr[row], pe = ptr[row+1];
  float a0=0,a1=0,a2=0,a3=0,a4=0,a5=0,a6=0,a7=0;
  const u16* hb = xin + (long long)c*8;
  int pm = p + ((pe - p) & ~15);
  while (p < pm){
    uint4 q[4]; float w[4];
    #pragma unroll
    for (int u = 0; u < 4; ++u){
      int s = csr_src[p + u*4 + g];
      w[u] = dinv[s];
      q[u] = *(const uint4*)(hb + (long long)s*CD);
    }
    #pragma unroll
    for (int u = 0; u < 4; ++u){
      a0 += lo16f(q[u].x)*w[u]; a1 += hi16f(q[u].x)*w[u];
      a2 += lo16f(q[u].y)*w[u]; a3 += hi16f(q[u].y)*w[u];
      a4 += lo16f(q[u].z)*w[u]; a5 += hi16f(q[u].z)*w[u];
      a6 += lo16f(q[u].w)*w[u]; a7 += hi16f(q[u].w)*w[u];
    }
    p += 16;
  }
  if (p < pe){
    uint4 q[4]; float w[4];
    #pragma unroll
    for (int u = 0; u < 4; ++u){
      int ei = p + u*4 + g;
      bool ok = (ei < pe);
      int s  = ok ? csr_src[ei] : 0;
      w[u]   = ok ? dinv[s] : 0.f;
      q[u]   = *(const uint4*)(hb + (long long)s*CD);
    }
    #pragma unroll
    for (int u = 0; u < 4; ++u){
      a0 += lo16f(q[u].x)*w[u]; a1 += hi16f(q[u].x)*w[u];
      a2 += lo16f(q[u].y)*w[u]; a3 += hi16f(q[u].y)*w[u];
      a4 += lo16f(q[u].z)*w[u]; a5 += hi16f(q[u].z)*w[u];
      a6 += lo16f(q[u].w)*w[u]; a7 += hi16f(q[u].w)*w[u];
    }
  }
  #pragma unroll
  for (int m = 16; m <= 32; m <<= 1){
    a0 += __shfl_xor(a0, m); a1 += __shfl_xor(a1, m);
    a2 += __shfl_xor(a2, m); a3 += __shfl_xor(a3, m);
    a4 += __shfl_xor(a4, m); a5 += __shfl_xor(a5, m);
    a6 += __shfl_xor(a6, m); a7 += __shfl_xor(a7, m);
  }
  if (g == 0){
    float wd = dinv[row];
    uint4 o;
    o.x = (u32)f2bf(a0*wd) | ((u32)f2bf(a1*wd) << 16);
    o.y = (u32)f2bf(a2*wd) | ((u32)f2bf(a3*wd) << 16);
    o.z = (u32)f2bf(a4*wd) | ((u32)f2bf(a5*wd) << 16);
    o.w = (u32)f2bf(a6*wd) | ((u32)f2bf(a7*wd) << 16);
    *(uint4*)(xout + (long long)row*CD + c*8) = o;
  }
}

// semantic attention scores via MFMA; blockIdx.y = side; 1 atomic/block.
__global__ void k_att2(const u16* __restrict__ z0, const u16* __restrict__ z1,
                       const u16* __restrict__ z2, const u16* __restrict__ z3,
                       const float* __restrict__ rs40k,
                       const u16* __restrict__ W1Tu, const u16* __restrict__ W1Ti,
                       const float* __restrict__ b1u, const float* __restrict__ b1i,
                       const float* __restrict__ W2u, const float* __restrict__ W2i,
                       float* __restrict__ misc, int L){
  __shared__ float wred[4];
  int side = blockIdx.y;
  const u16* za = side ? z2 : z0;
  const u16* zb = side ? z3 : z1;
  const float* rsi0 = rs40k + side*160000;
  const float* rsi1 = rsi0 + 80000;
  const u16* W1T = side ? W1Ti : W1Tu;
  const float* b1 = side ? b1i : b1u;
  const float* W2 = side ? W2i : W2u;
  float* s_out = misc + side*6 + 2*L;
  int nb = CNU >> 6;
  int blk = blockIdx.x;
  int ch = (blk >= nb) ? 1 : 0;
  int rb = (ch ? (blk - nb) : blk) * 64;
  const u16* z = ch ? zb : za;
  const float* rsi = ch ? rsi1 : rsi0;
  int wv = threadIdx.x >> 6, lane = threadIdx.x & 63;
  int i0 = rb + wv*16;
  int m = lane & 15, kq = lane >> 4;
  bf16x8 a[4];
  #pragma unroll
  for (int t = 0; t < 4; ++t){
    uint4 q = *(const uint4*)(z + (long long)(i0+m)*CD + t*32 + kq*8);
    a[t] = *(bf16x8*)&q;
  }
  float rsv[4];
  #pragma unroll
  for (int ri = 0; ri < 4; ++ri) rsv[ri] = rsi[i0 + kq*4 + ri];
  float psum = 0.f;
  #pragma unroll
  for (int jt = 0; jt < 8; ++jt){
    f32x4 acc = {0.f,0.f,0.f,0.f};
    #pragma unroll
    for (int t = 0; t < 4; ++t){
      uint4 qb = *(const uint4*)(W1T + (jt*16 + m)*CD + t*32 + kq*8);
      bf16x8 b = *(bf16x8*)&qb;
      acc = __builtin_amdgcn_mfma_f32_16x16x32_bf16(a[t], b, acc, 0, 0, 0);
    }
    int j = jt*16 + m;
    float bb = b1[j], w2 = W2[j];
    #pragma unroll
    for (int ri = 0; ri < 4; ++ri){
      float x = acc[ri]*rsv[ri] + bb;
      x = fminf(fmaxf(x, -15.f), 15.f);
      float t2 = __expf(2.f*x);
      psum += ((t2 - 1.f)/(t2 + 1.f))*w2;
    }
  }
  #pragma unroll
  for (int msk = 1; msk <= 32; msk <<= 1) psum += __shfl_xor(psum, msk);
  if (lane == 0) wred[wv] = psum;
  __syncthreads();
  if (threadIdx.x == 0)
    atomicAdd(s_out, wred[0] + wred[1] + wred[2] + wred[3]);
}

// blockIdx.y = side; combine z-pair into h (hu or hi).
__global__ void k_combine2(const u16* __restrict__ z0, const u16* __restrict__ z1,
                           const u16* __restrict__ z2, const u16* __restrict__ z3,
                           const float* __restrict__ rs40k,
                           const float* __restrict__ misc, int L,
                           u16* __restrict__ hu, u16* __restrict__ hi){
  int side = blockIdx.y;
  const u16* za = side ? z2 : z0;
  const u16* zb = side ? z3 : z1;
  const float* rsi0 = rs40k + side*160000;
  const float* rsi1 = rsi0 + 80000;
  const float* s = misc + side*6 + 2*L;
  u16* h = side ? hi : hu;
  int idx = blockIdx.x*256 + threadIdx.x;
  int v = idx >> 7;
  float s0 = s[0]*(1.0f/CNU), s1 = s[1]*(1.0f/CNU);
  float m = fmaxf(s0, s1);
  float e0 = __expf(s0 - m), e1 = __expf(s1 - m);
  float r = 1.0f/(e0 + e1);
  h[idx] = f2bf((e0*r)*bf2f(za[idx])*rsi0[v] + (e1*r)*bf2f(zb[idx])*rsi1[v]);
}

__global__ void k_emb(const u16* __restrict__ x2, u16* __restrict__ h_u,
                      u16* __restrict__ h_i){
  int idx = blockIdx.x*256 + threadIdx.x;
  if (idx >= CNN*CD) return;
  if (idx < CNU*CD) h_u[idx] = f2bf(0.5f*bf2f(h_u[idx]) + 0.5f*bf2f(x2[idx]));
  else { int k = idx - CNU*CD; h_i[k] = f2bf(0.5f*bf2f(h_i[k]) + 0.5f*bf2f(x2[idx])); }
}

// both SSL sides in one launch; blockIdx.y = side (0=user,1=item)
__global__ void k_sslnorm2(const u16* __restrict__ x2, const u16* __restrict__ hu,
                           const u16* __restrict__ hi,
                           const int* __restrict__ uidx, const int* __restrict__ iidx,
                           u16* __restrict__ nbase, float* __restrict__ misc){
  __shared__ float wred[4];
  int side = blockIdx.y;
  const int* idx = side ? iidx : uidx;
  const u16* hemb = side ? hi : hu;
  int rowoff = side ? CNU : 0;
  u16* n1b = nbase + (long long)side*2*CB*CD;
  u16* n2b = n1b + (long long)CB*CD;
  float* pos_acc = misc + 12 + 2*side;
  int wv = threadIdx.x >> 6, lane = threadIdx.x & 63;
  int r0 = blockIdx.x*16 + wv*4;
  int g[4]; u32 q1[4], q2[4];
  #pragma unroll
  for (int u = 0; u < 4; ++u){
    g[u] = idx[r0 + u];
    q1[u] = *(const u32*)(x2 + (long long)(g[u] + rowoff)*CD + lane*2);
    q2[u] = *(const u32*)(hemb + (long long)g[u]*CD + lane*2);
  }
  float psum = 0.f;
  #pragma unroll
  for (int u = 0; u < 4; ++u){
    float a0 = lo16f(q1[u]), a1 = hi16f(q1[u]);
    float b0 = lo16f(q2[u]), b1 = hi16f(q2[u]);
    float s1 = a0*a0 + a1*a1, s2 = b0*b0 + b1*b1, s12 = a0*b0 + a1*b1;
    #pragma unroll
    for (int msk = 1; msk <= 32; msk <<= 1){
      s1  += __shfl_xor(s1, msk);
      s2  += __shfl_xor(s2, msk);
      s12 += __shfl_xor(s12, msk);
    }
    float i1 = 1.0f / fmaxf(sqrtf(s1), 1e-12f);
    float i2 = 1.0f / fmaxf(sqrtf(s2), 1e-12f);
    *(u32*)(n1b + (long long)(r0+u)*CD + lane*2) = (u32)f2bf(a0*i1) | ((u32)f2bf(a1*i1) << 16);
    *(u32*)(n2b + (long long)(r0+u)*CD + lane*2) = (u32)f2bf(b0*i2) | ((u32)f2bf(b1*i2) << 16);
    psum += s12*i1*i2*2.0f;
  }
  if (lane == 0) wred[wv] = psum;
  __syncthreads();
  if (threadIdx.x == 0)
    atomicAdd(pos_acc, wred[0] + wred[1] + wred[2] + wred[3]);
}

// alls[i] += sum_j exp(2 * n1_i . n2_j); LDS-staged B (double-buffered, XOR-swizzled),
// 2 i-tiles/wave (low VGPR), grid (64,16,2). blockIdx.z = side.
__global__ void __launch_bounds__(256)
k_alls3(const u16* __restrict__ nbase, float* __restrict__ alls){
  __shared__ uint4 ldsb[2][256];
  int side = blockIdx.z;
  const u16* n1b = nbase + (long long)side*2*CB*CD;
  const u16* n2b = n1b + (long long)CB*CD;
  float* al = alls + side*CB;
  int wv = threadIdx.x >> 6, lane = threadIdx.x & 63;
  int m = lane & 15, kq = lane >> 4;
  int i0 = (blockIdx.x*8 + wv*2)*16;
  bf16x8 a[2][4];
  #pragma unroll
  for (int c = 0; c < 2; ++c){
    #pragma unroll
    for (int t = 0; t < 4; ++t){
      uint4 q = *(const uint4*)(n1b + (long long)(i0 + c*16 + m)*CD + t*32 + kq*8);
      a[c][t] = *(bf16x8*)&q;
    }
  }
  float es0[4] = {0.f,0.f,0.f,0.f};
  float es1[4] = {0.f,0.f,0.f,0.f};
  int j0 = blockIdx.y*512;
  int sr = threadIdx.x >> 4, sc = threadIdx.x & 15;
  const u16* sp = n2b + (long long)(j0 + sr)*CD + sc*8;
  int se = sr*16 + (sc ^ (sr & 7));
  uint4 v = *(const uint4*)sp;
  for (int jt = 0; jt < 32; ++jt){
    ldsb[jt & 1][se] = v;
    if (jt < 31) v = *(const uint4*)(sp + (long long)(jt+1)*16*CD);
    __syncthreads();
    f32x4 ac0 = {0.f,0.f,0.f,0.f}, ac1 = {0.f,0.f,0.f,0.f};
    #pragma unroll
    for (int t = 0; t < 4; ++t){
      int cc = 4*t + kq;
      uint4 bq = ldsb[jt & 1][m*16 + (cc ^ (m & 7))];
      bf16x8 b = *(bf16x8*)&bq;
      ac0 = __builtin_amdgcn_mfma_f32_16x16x32_bf16(a[0][t], b, ac0, 0, 0, 0);
      ac1 = __builtin_amdgcn_mfma_f32_16x16x32_bf16(a[1][t], b, ac1, 0, 0, 0);
    }
    #pragma unroll
    for (int ri = 0; ri < 4; ++ri){
      es0[ri] += __expf(ac0[ri]*2.f);
      es1[ri] += __expf(ac1[ri]*2.f);
    }
  }
  #pragma unroll
  for (int ri = 0; ri < 4; ++ri){
    float v0 = es0[ri], v1 = es1[ri];
    #pragma unroll
    for (int msk = 1; msk <= 8; msk <<= 1){
      v0 += __shfl_xor(v0, msk);
      v1 += __shfl_xor(v1, msk);
    }
    if (m == 0){
      atomicAdd(&al[i0 + kq*4 + ri], v0);
      atomicAdd(&al[i0 + 16 + kq*4 + ri], v1);
    }
  }
}

__global__ void k_logsum(const float* __restrict__ alls, float* __restrict__ misc){
  int i = blockIdx.x*256 + threadIdx.x;
  float v = logf(alls[i]);
  for (int off = 32; off > 0; off >>= 1) v += __shfl_down(v, off);
  if ((threadIdx.x & 63) == 0) atomicAdd(&misc[(i < CB) ? 13 : 15], v);
}

// all 3 output GEMM+LN slabs in one launch; blockIdx.y = slab.
__global__ void k_final3(const u16* __restrict__ hu, const u16* __restrict__ hi,
                         const int* __restrict__ uidx, const int* __restrict__ iidx,
                         const int* __restrict__ nidx,
                         const float* __restrict__ uW, const float* __restrict__ ub,
                         const float* __restrict__ iW, const float* __restrict__ ib,
                         const float* __restrict__ lg, const float* __restrict__ lb,
                         float* __restrict__ outp){
  __shared__ float A[8][128];
  __shared__ float red[8][4];
  int y = blockIdx.y;
  const u16* emb = (y == 0) ? hu : hi;
  const int* idx = (y == 0) ? uidx : ((y == 1) ? iidx : nidx);
  const float* W = (y == 0) ? uW : iW;
  const float* bias = (y == 0) ? ub : ib;
  float* outb = outp + (long long)y*CB*CD;
  int j = threadIdx.x;
  int r0 = blockIdx.x*8;
  for (int r = 0; r < 8; ++r){
    int g = idx[r0 + r];
    A[r][j] = bf2f(emb[(long long)g*CD + j]);
  }
  __syncthreads();
  float acc[8];
  #pragma unroll
  for (int r = 0; r < 8; ++r) acc[r] = 0.f;
  for (int k = 0; k < 128; k += 4){
    float w0 = W[(k+0)*128 + j];
    float w1 = W[(k+1)*128 + j];
    float w2 = W[(k+2)*128 + j];
    float w3 = W[(k+3)*128 + j];
    #pragma unroll
    for (int r = 0; r < 8; ++r){
      float4 a = *(const float4*)&A[r][k];
      acc[r] += a.x*w0 + a.y*w1 + a.z*w2 + a.w*w3;
    }
  }
  float bb = bias[j];
  #pragma unroll
  for (int r = 0; r < 8; ++r){
    float v = acc[r] + bb;
    acc[r] = (v < 0.f) ? 0.f : v;
  }
  int wid = j >> 6, lane = j & 63;
  #pragma unroll
  for (int r = 0; r < 8; ++r){
    float s = acc[r], q = acc[r]*acc[r];
    for (int off = 32; off > 0; off >>= 1){
      s += __shfl_down(s, off); q += __shfl_down(q, off);
    }
    if (lane == 0){ red[r][wid*2] = s; red[r][wid*2+1] = q; }
  }
  __syncthreads();
  float gg = lg[j], be = lb[j];
  #pragma unroll
  for (int r = 0; r < 8; ++r){
    float mu = (red[r][0] + red[r][2]) * (1.0f/128.0f);
    float ms = (red[r][1] + red[r][3]) * (1.0f/128.0f);
    float var = ms - mu*mu;
    float yv = (acc[r] - mu) * rsqrtf(var + 1e-5f) * gg + be;
    outb[(long long)(r0 + r)*CD + j] = yv;
  }
}

__global__ void k_loss(const float* __restrict__ misc, float* __restrict__ o){
  float lu = (misc[13] - misc[12]) * (1.0f/CB);
  float li = (misc[15] - misc[14]) * (1.0f/CB);
  o[0] = 0.4f*(lu + li);
}

extern "C" void kernel_launch(void* const* d_in, const int* in_sizes, int n_in,
                              void* d_out, int out_size, void* d_ws, size_t ws_size,
                              hipStream_t stream){
  (void)in_sizes; (void)n_in; (void)out_size; (void)ws_size;
  const float* feat_user = (const float*)d_in[0];
  const float* feat_item = (const float*)d_in[1];
  const float* u_W1 = (const float*)d_in[2];
  const float* u_b1 = (const float*)d_in[3];
  const float* u_W2 = (const float*)d_in[4];
  const float* i_W1 = (const float*)d_in[5];
  const float* i_b1 = (const float*)d_in[6];
  const float* i_W2 = (const float*)d_in[7];
  const float* user_W = (const float*)d_in[8];
  const float* user_b = (const float*)d_in[9];
  const float* item_W = (const float*)d_in[10];
  const float* item_b = (const float*)d_in[11];
  const float* ln_g = (const float*)d_in[12];
  const float* ln_b = (const float*)d_in[13];
  const int* ump0s = (const int*)d_in[14]; const int* ump0d = (const int*)d_in[15];
  const int* ump1s = (const int*)d_in[16]; const int* ump1d = (const int*)d_in[17];
  const int* imp0s = (const int*)d_in[18]; const int* imp0d = (const int*)d_in[19];
  const int* imp1s = (const int*)d_in[20]; const int* imp1d = (const int*)d_in[21];
  const int* ui_row = (const int*)d_in[22]; const int* ui_col = (const int*)d_in[23];
  const int* user_idx = (const int*)d_in[24]; const int* item_idx = (const int*)d_in[25];
  const int* neg_idx = (const int*)d_in[26];

  u16* W  = (u16*)d_ws;
  u16* fb = W;                      // 10,240,000 bf16
  u16* hu = W + 10240000LL;
  u16* hi = W + 15360000LL;
  u16* xb = W + 20480000LL;         // UI intermediate; MP-build gbytes+odeg; later z2/z3; later SSL nbase
  u16* x2 = W + 30720000LL;
  u16* z0 = W + 40960000LL;
  u16* z1 = W + 46080000LL;
  float* F   = (float*)(W + 51200000LL);
  float* rs  = F;                   // 320,000 (indeg tables at +40000 + y*80000)
  float* dinv= F + 320000;          // 80,000
  float* alls= F + 400000;          // 16,384
  float* misc= F + 416384;          // 64
  int* I     = (int*)(F + 416448);
  int* mp_p  = I;                   // 4 x 40,001
  int* gcur  = I + 160004;          // 1280 (4 x 320)
  int* bbase = I + 161284;          // 1280
  int* gcur2 = I + 162564;          // 1280
  int* mp_c  = I + 163844;          // 4 x 640,000
  u16* w1tu  = (u16*)(I + 2723844); // 16,384 bf16 (W1^T user)
  u16* w1ti  = w1tu + 16384;        // 16,384 bf16 (W1^T item)
  int* ui_ptr    = (int*)hu;        // overlay (hu/hi dead until first combine)
  int* ui_csr    = ui_ptr + 160001; // 1,600,000 ints
  u32* gpairsU   = (u32*)z0;        // UI build: 313*8064*4B = 10.09MB (z0 dead during builds)
  u32* gpairs4   = (u32*)z0;        // MP build: 4*157*8064*4B = 20.26MB over z0+z1 (dead during builds)
  u8*  gbytes4   = (u8*)xb;         // MP build: 4*157*8064 = 5.06MB (xb dead after UI hops)
  u16* odeg4     = xb + 2540000LL;  // 4 x 40,000 u16 (after gbytes4; still inside xb)
  u16* z2 = xb;                     // layer-loop z for item side (xb free during loops)
  u16* z3 = xb + 5120000LL;
  u16* nbase = xb;                  // SSL overlay (z2/z3 dead after loops)
  float* out = (float*)d_out;

  k_zero<<<(16448 + 255)/256, 256, 0, stream>>>(alls, 16448);
  k_initb<<<40064, 256, 0, stream>>>(feat_user, feat_item, fb, u_W1, i_W1, w1tu, w1ti);

  // UI CSR build (counting sort; NB=313 buckets of 256 dst); dinv emitted by pass 2.
  k_izero<<<15, 256, 0, stream>>>(gcur, 3840);
  k_bucket1<<<(CEUI + P1_CHUNK - 1)/P1_CHUNK, 256, 0, stream>>>(ui_col, ui_row, gcur, gpairsU, CEUI, 313);
  k_scanb<<<1, 512, 0, stream>>>(gcur, bbase, 313);
  k_bucket2<<<313, 256, 0, stream>>>(gpairsU, gcur, bbase, ui_csr, ui_ptr, CNN, dinv, 0.0f);

  // UI propagation: fb -> x2 -> xb -> x2   (xb free after this)
  k_gather_ui<<<20000, 256, 0, stream>>>(fb, ui_ptr, ui_csr, dinv, x2, CNN);
  k_gather_ui<<<20000, 256, 0, stream>>>(x2, ui_ptr, ui_csr, dinv, xb, CNN);
  k_gather_ui<<<20000, 256, 0, stream>>>(xb, ui_ptr, ui_csr, dinv, x2, CNN);

  // All 4 MP CSRs in one batched build (y = graph: user mp0, user mp1, item mp0, item mp1)
  k_izero<<<15, 256, 0, stream>>>(gcur, 3840);
  k_bucket1b4<<<dim3((CEMP + P1_CHUNK - 1)/P1_CHUNK, 4), 256, 0, stream>>>(
      ump0s, ump0d, ump1s, ump1d, imp0s, imp0d, imp1s, imp1d,
      gcur, gpairs4, gcur2, gbytes4);
  k_scanb<<<4, 512, 0, stream>>>(gcur, bbase, NB_MP);
  k_odeg4<<<dim3(NB_MP, 4), 256, 0, stream>>>(gbytes4, gcur2, odeg4);
  k_bucket2b4<<<dim3(NB_MP, 4), 256, 0, stream>>>(gpairs4, gcur, bbase, mp_c, mp_p, rs + 40000, odeg4);

  // merged user+item HAN layers (independent chains -> joint launches)
  for (int L = 0; L < 3; ++L){
    k_gather_mp4<<<dim3(10000, 4), 256, 0, stream>>>(fb, hu, hi, L, mp_p, (const u32*)mp_c, z0, z2);
    k_att2<<<dim3(1250, 2), 256, 0, stream>>>(z0, z1, z2, z3, rs + 40000,
                                              w1tu, w1ti, u_b1, i_b1, u_W2, i_W2, misc, L);
    k_combine2<<<dim3(20000, 2), 256, 0, stream>>>(z0, z1, z2, z3, rs + 40000, misc, L, hu, hi);
  }

  k_emb<<<40000, 256, 0, stream>>>(x2, hu, hi);

  // SSL (both sides per launch)
  k_sslnorm2<<<dim3(CB/16, 2), 256, 0, stream>>>(x2, hu, hi, user_idx, item_idx, nbase, misc);
  k_alls3<<<dim3(64, 16, 2), 256, 0, stream>>>(nbase, alls);
  k_logsum<<<64, 256, 0, stream>>>(alls, misc);

  k_final3<<<dim3(1024, 3), 128, 0, stream>>>(hu, hi, user_idx, item_idx, neg_idx,
                                              user_W, user_b, item_W, item_b,
                                              ln_g, ln_b, out);
  k_loss<<<1, 1, 0, stream>>>(misc, out + 3LL*CB*CD);
}

// Round 9
// 864.829 us; speedup vs baseline: 2.9185x; 1.1969x over previous
//
#include <hip/hip_runtime.h>
#include <math.h>

typedef unsigned short u16;
typedef unsigned int u32;
typedef unsigned char u8;
typedef __attribute__((ext_vector_type(8))) short bf16x8;
typedef __attribute__((ext_vector_type(4))) float f32x4;

#define CNU 40000
#define CNN 80000
#define CD  128
#define CEMP 640000
#define CEUI 1600000
#define CB  8192

#define BK_CAP 8064     // per-bucket capacity (mean 5120 UI / 4096 MP; >40 sigma margin)
#define P1_CHUNK 4096   // edges per block in bucket pass 1 (16/thread)
#define NB_MP 157       // MP bucket count (40000/256 rounded up)

__device__ __forceinline__ float bf2f(u16 b){
  union { u32 u; float f; } v; v.u = ((u32)b) << 16; return v.f;
}
__device__ __forceinline__ u16 f2bf(float f){
  union { float f; u32 u; } v; v.f = f;
  u32 u = v.u + 0x7FFFu + ((v.u >> 16) & 1u);
  return (u16)(u >> 16);
}
__device__ __forceinline__ float lo16f(u32 q){ union { u32 u; float f; } v; v.u = q << 16; return v.f; }
__device__ __forceinline__ float hi16f(u32 q){ union { u32 u; float f; } v; v.u = q & 0xFFFF0000u; return v.f; }
__device__ __forceinline__ u32 pack2(float a, float b){
  return (u32)f2bf(a) | ((u32)f2bf(b) << 16);
}

__global__ void k_zero(float* __restrict__ p, long long n){
  long long i = (long long)blockIdx.x*256 + threadIdx.x;
  if (i < n) p[i] = 0.f;
}

__global__ void k_izero(int* __restrict__ p, int n){
  int i = blockIdx.x*256 + threadIdx.x;
  if (i < n) p[i] = 0;
}

// fused + vectorized: feature f32->bf16 cast (blocks 0..4999, 8 floats/thread)
// + W1 transpose (blocks 5000..5063)
__global__ void k_initb(const float* __restrict__ fu, const float* __restrict__ fi,
                        u16* __restrict__ fb,
                        const float* __restrict__ Wu, const float* __restrict__ Wi,
                        u16* __restrict__ Wut, u16* __restrict__ Wit){
  int b = blockIdx.x;
  if (b < 5000){
    long long off = ((long long)b*256 + threadIdx.x)*8;
    const float* src = (off < (long long)CNU*CD) ? (fu + off) : (fi + (off - (long long)CNU*CD));
    float4 f0 = *(const float4*)src;
    float4 f1 = *(const float4*)(src + 4);
    uint4 o;
    o.x = pack2(f0.x, f0.y);
    o.y = pack2(f0.z, f0.w);
    o.z = pack2(f1.x, f1.y);
    o.w = pack2(f1.z, f1.w);
    *(uint4*)(fb + off) = o;
  } else {
    int idx = (b - 5000)*256 + threadIdx.x;
    if (idx < 16384){
      int k = idx >> 7, j = idx & 127;
      Wut[j*128 + k] = f2bf(Wu[idx]);
      Wit[j*128 + k] = f2bf(Wi[idx]);
    }
  }
}

// ---- CSR build via LDS-aggregated counting sort ----
// Pass 1 (UI variant): dst-keyed pair scatter only.
__global__ void k_bucket1(const int* __restrict__ src, const int* __restrict__ dst,
                          int* __restrict__ gcur, u32* __restrict__ gpairs,
                          int E, int NB){
  __shared__ int cnt[320];
  __shared__ int sbase[320];
  int t = threadIdx.x;
  for (int i = t; i < NB; i += 256) cnt[i] = 0;
  __syncthreads();
  int base = blockIdx.x * P1_CHUNK;
  int r[16], dv[16], sv[16];
  #pragma unroll
  for (int u = 0; u < 16; ++u){
    int e = base + u*256 + t;
    bool ok = (e < E);
    dv[u] = ok ? dst[e] : -1;
    sv[u] = ok ? src[e] : 0;
    if (ok) r[u] = atomicAdd(&cnt[dv[u] >> 8], 1);
  }
  __syncthreads();
  for (int i = t; i < NB; i += 256){
    int c = cnt[i];
    sbase[i] = c ? atomicAdd(&gcur[i], c) : 0;
  }
  __syncthreads();
  #pragma unroll
  for (int u = 0; u < 16; ++u){
    if (dv[u] >= 0){
      int b = dv[u] >> 8;
      int p = sbase[b] + r[u];
      if (p < BK_CAP)
        gpairs[(long long)b*BK_CAP + p] = (u32)sv[u] | ((u32)(dv[u] & 255) << 18);
    }
  }
}

// Pass 1 (MP, 4-graph batched): dst-keyed pair scatter + src-keyed byte scatter.
__global__ void k_bucket1b4(const int* __restrict__ s0, const int* __restrict__ d0,
                            const int* __restrict__ s1, const int* __restrict__ d1,
                            const int* __restrict__ s2, const int* __restrict__ d2,
                            const int* __restrict__ s3, const int* __restrict__ d3,
                            int* __restrict__ gcur, u32* __restrict__ gpairs,
                            int* __restrict__ gcur2, u8* __restrict__ gbytes){
  __shared__ int cnt[320], sbase[320], cnt2[320], sbase2[320];
  int g = blockIdx.y;
  const int* src = (g==0) ? s0 : (g==1) ? s1 : (g==2) ? s2 : s3;
  const int* dst = (g==0) ? d0 : (g==1) ? d1 : (g==2) ? d2 : d3;
  int* gc  = gcur  + g*320;
  int* gc2 = gcur2 + g*320;
  u32* gp  = gpairs + (long long)g*NB_MP*BK_CAP;
  u8*  gb  = gbytes + (long long)g*NB_MP*BK_CAP;
  int t = threadIdx.x;
  for (int i = t; i < NB_MP; i += 256){ cnt[i] = 0; cnt2[i] = 0; }
  __syncthreads();
  int base = blockIdx.x * P1_CHUNK;
  int r[16], r2[16], dv[16], sv[16];
  #pragma unroll
  for (int u = 0; u < 16; ++u){
    int e = base + u*256 + t;
    bool ok = (e < CEMP);
    dv[u] = ok ? dst[e] : -1;
    sv[u] = ok ? src[e] : -1;
    if (ok){
      r[u]  = atomicAdd(&cnt[dv[u] >> 8], 1);
      r2[u] = atomicAdd(&cnt2[sv[u] >> 8], 1);
    }
  }
  __syncthreads();
  for (int i = t; i < NB_MP; i += 256){
    int c  = cnt[i];  sbase[i]  = c  ? atomicAdd(&gc[i],  c)  : 0;
    int c2 = cnt2[i]; sbase2[i] = c2 ? atomicAdd(&gc2[i], c2) : 0;
  }
  __syncthreads();
  #pragma unroll
  for (int u = 0; u < 16; ++u){
    if (dv[u] >= 0){
      int b = dv[u] >> 8;
      int p = sbase[b] + r[u];
      if (p < BK_CAP)
        gp[(long long)b*BK_CAP + p] = (u32)sv[u] | ((u32)(dv[u] & 255) << 18);
      int b2 = sv[u] >> 8;
      int p2 = sbase2[b2] + r2[u];
      if (p2 < BK_CAP)
        gb[(long long)b2*BK_CAP + p2] = (u8)(sv[u] & 255);
    }
  }
}

// exclusive scan of bucket counts; blockIdx.x = graph slice (stride 320).
__global__ void k_scanb(const int* __restrict__ gcur, int* __restrict__ bbase, int NB){
  __shared__ int s[512];
  int g = blockIdx.x;
  const int* gc = gcur + g*320;
  int* bb = bbase + g*320;
  int t = threadIdx.x;
  int v = (t < NB) ? gc[t] : 0;
  s[t] = v;
  __syncthreads();
  for (int off = 1; off < 512; off <<= 1){
    int u = (t >= off) ? s[t-off] : 0;
    __syncthreads();
    s[t] += u;
    __syncthreads();
  }
  if (t < NB) bb[t] = s[t] - v;
}

// Count-only pass over src byte-buckets -> u16 out-degree table; blockIdx.y = graph.
__global__ void k_odeg4(const u8* __restrict__ gbytes, const int* __restrict__ gcur2,
                        u16* __restrict__ odeg){
  __shared__ int hist[256];
  int g = blockIdx.y;
  int b = blockIdx.x, t = threadIdx.x;
  hist[t] = 0;
  __syncthreads();
  int cnt = gcur2[g*320 + b]; if (cnt > BK_CAP) cnt = BK_CAP;
  const u8* pp = gbytes + (long long)(g*NB_MP + b)*BK_CAP;
  for (int i = t; i < cnt; i += 256) atomicAdd(&hist[pp[i]], 1);
  __syncthreads();
  int dg = (b << 8) + t;
  if (dg < CNU) odeg[g*CNU + dg] = (u16)hist[t];
}

// Pass 2 (UI): one block per bucket; LDS scatter then streaming CSR write + ptr slice.
__global__ void k_bucket2(const u32* __restrict__ gpairs, const int* __restrict__ gcur,
                          const int* __restrict__ bbase, int* __restrict__ csr,
                          int* __restrict__ ptr, int n,
                          float* __restrict__ rs_ind, float zval){
  __shared__ int hist[256];
  __shared__ int excl[256];
  __shared__ int lptr[256];
  __shared__ int lsrc[BK_CAP];
  int b = blockIdx.x, t = threadIdx.x;
  int cnt = gcur[b]; if (cnt > BK_CAP) cnt = BK_CAP;
  int base = bbase[b];
  hist[t] = 0;
  __syncthreads();
  const u32* pp = gpairs + (long long)b*BK_CAP;
  for (int i = t; i < cnt; i += 256) atomicAdd(&hist[(pp[i] >> 18) & 255], 1);
  __syncthreads();
  int h = hist[t];
  lptr[t] = h;
  __syncthreads();
  for (int off = 1; off < 256; off <<= 1){
    int u2 = (t >= off) ? lptr[t-off] : 0;
    __syncthreads();
    lptr[t] += u2;
    __syncthreads();
  }
  excl[t] = lptr[t] - h;
  __syncthreads();
  hist[t] = excl[t];
  __syncthreads();
  for (int i = t; i < cnt; i += 256){
    u32 v = pp[i];
    int d = (v >> 18) & 255;
    int p = atomicAdd(&hist[d], 1);
    lsrc[p] = (int)(v & 0x3FFFFu);
  }
  __syncthreads();
  for (int i = t; i < cnt; i += 256) csr[base + i] = lsrc[i];
  int dg = (b << 8) + t;
  if (dg <= n) ptr[dg] = base + excl[t];
  if (dg < n)  rs_ind[dg] = (h > 0) ? rsqrtf((float)h) : zval;
}

// Pass 2 (MP, 4-graph batched): packs csr entries (outdeg<<16 | src); blockIdx.y = graph.
__global__ void k_bucket2b4(const u32* __restrict__ gpairs, const int* __restrict__ gcur,
                            const int* __restrict__ bbase, int* __restrict__ csr_base,
                            int* __restrict__ ptr_base, float* __restrict__ rs40k,
                            const u16* __restrict__ odeg){
  __shared__ int hist[256];
  __shared__ int excl[256];
  __shared__ int lptr[256];
  __shared__ int lsrc[BK_CAP];
  int g = blockIdx.y;
  int b = blockIdx.x, t = threadIdx.x;
  int cnt = gcur[g*320 + b]; if (cnt > BK_CAP) cnt = BK_CAP;
  int base = bbase[g*320 + b];
  int* csr = csr_base + (long long)g*CEMP;
  int* ptr = ptr_base + g*(CNU+1);
  float* rs_ind = rs40k + g*80000;
  const u16* od = odeg + g*CNU;
  hist[t] = 0;
  __syncthreads();
  const u32* pp = gpairs + (long long)(g*NB_MP + b)*BK_CAP;
  for (int i = t; i < cnt; i += 256) atomicAdd(&hist[(pp[i] >> 18) & 255], 1);
  __syncthreads();
  int h = hist[t];
  lptr[t] = h;
  __syncthreads();
  for (int off = 1; off < 256; off <<= 1){
    int u2 = (t >= off) ? lptr[t-off] : 0;
    __syncthreads();
    lptr[t] += u2;
    __syncthreads();
  }
  excl[t] = lptr[t] - h;
  __syncthreads();
  hist[t] = excl[t];
  __syncthreads();
  for (int i = t; i < cnt; i += 256){
    u32 v = pp[i];
    int d = (v >> 18) & 255;
    int p = atomicAdd(&hist[d], 1);
    lsrc[p] = (int)(v & 0x3FFFFu);
  }
  __syncthreads();
  for (int i = t; i < cnt; i += 256){
    int s = lsrc[i];
    csr[base + i] = (int)((u32)s | ((u32)od[s] << 16));
  }
  int dg = (b << 8) + t;
  if (dg <= CNU) ptr[dg] = base + excl[t];
  if (dg < CNU)  rs_ind[dg] = (h > 0) ? rsqrtf((float)h) : 1.0f;
}

// ---- gather: 1 wave/row, lane=(g=edge-slot 0..3, c=16B-chunk 0..15) ----
// MP 4-way variant: blockIdx.y = graph (0,1=user mp0/mp1; 2,3=item mp0/mp1).
__global__ void k_gather_mp4(const u16* __restrict__ fb, const u16* __restrict__ hu,
                             const u16* __restrict__ hi, int L,
                             const int* __restrict__ ptr_base, const u32* __restrict__ csr_base,
                             u16* __restrict__ z0base, u16* __restrict__ z2base){
  int row = (blockIdx.x*256 + threadIdx.x) >> 6;
  if (row >= CNU) return;
  int y = blockIdx.y;
  int side = y >> 1;
  const u16* h = (L == 0) ? (fb + (long long)side*CNU*CD) : (side ? hi : hu);
  const int* ptr = ptr_base + y*(CNU+1);
  const u32* csr = csr_base + (long long)y*CEMP;
  u16* z = (y < 2) ? (z0base + (long long)y*CNU*CD) : (z2base + (long long)(y-2)*CNU*CD);
  int lane = threadIdx.x & 63;
  int g = lane >> 4, c = lane & 15;
  int p = ptr[row], pe = ptr[row+1];
  float a0=0,a1=0,a2=0,a3=0,a4=0,a5=0,a6=0,a7=0;
  const u16* hb = h + (long long)c*8;
  int pm = p + ((pe - p) & ~15);
  while (p < pm){
    uint4 q[4]; float w[4];
    #pragma unroll
    for (int u = 0; u < 4; ++u){
      u32 e = csr[p + u*4 + g];
      w[u] = rsqrtf((float)(e >> 16));
      q[u] = *(const uint4*)(hb + (long long)(e & 0xFFFFu)*CD);
    }
    #pragma unroll
    for (int u = 0; u < 4; ++u){
      a0 += lo16f(q[u].x)*w[u]; a1 += hi16f(q[u].x)*w[u];
      a2 += lo16f(q[u].y)*w[u]; a3 += hi16f(q[u].y)*w[u];
      a4 += lo16f(q[u].z)*w[u]; a5 += hi16f(q[u].z)*w[u];
      a6 += lo16f(q[u].w)*w[u]; a7 += hi16f(q[u].w)*w[u];
    }
    p += 16;
  }
  if (p < pe){
    uint4 q[4]; float w[4];
    #pragma unroll
    for (int u = 0; u < 4; ++u){
      int ei = p + u*4 + g;
      bool ok = (ei < pe);
      u32 e = ok ? csr[ei] : 0u;
      w[u] = ok ? rsqrtf((float)(e >> 16)) : 0.f;
      q[u] = *(const uint4*)(hb + (long long)(e & 0xFFFFu)*CD);
    }
    #pragma unroll
    for (int u = 0; u < 4; ++u){
      a0 += lo16f(q[u].x)*w[u]; a1 += hi16f(q[u].x)*w[u];
      a2 += lo16f(q[u].y)*w[u]; a3 += hi16f(q[u].y)*w[u];
      a4 += lo16f(q[u].z)*w[u]; a5 += hi16f(q[u].z)*w[u];
      a6 += lo16f(q[u].w)*w[u]; a7 += hi16f(q[u].w)*w[u];
    }
  }
  #pragma unroll
  for (int m = 16; m <= 32; m <<= 1){
    a0 += __shfl_xor(a0, m); a1 += __shfl_xor(a1, m);
    a2 += __shfl_xor(a2, m); a3 += __shfl_xor(a3, m);
    a4 += __shfl_xor(a4, m); a5 += __shfl_xor(a5, m);
    a6 += __shfl_xor(a6, m); a7 += __shfl_xor(a7, m);
  }
  if (g == 0){
    uint4 o;
    o.x = pack2(a0, a1);
    o.y = pack2(a2, a3);
    o.z = pack2(a4, a5);
    o.w = pack2(a6, a7);
    *(uint4*)(z + (long long)row*CD + c*8) = o;
  }
}

// UI variant: per-edge w = dinv[src]; main/tail split.
__global__ void k_gather_ui(const u16* __restrict__ xin, const int* __restrict__ ptr,
                            const int* __restrict__ csr_src, const float* __restrict__ dinv,
                            u16* __restrict__ xout, int n){
  int row = (blockIdx.x*256 + threadIdx.x) >> 6;
  if (row >= n) return;
  int lane = threadIdx.x & 63;
  int g = lane >> 4, c = lane & 15;
  int p = ptr[row], pe = ptr[row+1];
  float a0=0,a1=0,a2=0,a3=0,a4=0,a5=0,a6=0,a7=0;
  const u16* hb = xin + (long long)c*8;
  int pm = p + ((pe - p) & ~15);
  while (p < pm){
    uint4 q[4]; float w[4];
    #pragma unroll
    for (int u = 0; u < 4; ++u){
      int s = csr_src[p + u*4 + g];
      w[u] = dinv[s];
      q[u] = *(const uint4*)(hb + (long long)s*CD);
    }
    #pragma unroll
    for (int u = 0; u < 4; ++u){
      a0 += lo16f(q[u].x)*w[u]; a1 += hi16f(q[u].x)*w[u];
      a2 += lo16f(q[u].y)*w[u]; a3 += hi16f(q[u].y)*w[u];
      a4 += lo16f(q[u].z)*w[u]; a5 += hi16f(q[u].z)*w[u];
      a6 += lo16f(q[u].w)*w[u]; a7 += hi16f(q[u].w)*w[u];
    }
    p += 16;
  }
  if (p < pe){
    uint4 q[4]; float w[4];
    #pragma unroll
    for (int u = 0; u < 4; ++u){
      int ei = p + u*4 + g;
      bool ok = (ei < pe);
      int s  = ok ? csr_src[ei] : 0;
      w[u]   = ok ? dinv[s] : 0.f;
      q[u]   = *(const uint4*)(hb + (long long)s*CD);
    }
    #pragma unroll
    for (int u = 0; u < 4; ++u){
      a0 += lo16f(q[u].x)*w[u]; a1 += hi16f(q[u].x)*w[u];
      a2 += lo16f(q[u].y)*w[u]; a3 += hi16f(q[u].y)*w[u];
      a4 += lo16f(q[u].z)*w[u]; a5 += hi16f(q[u].z)*w[u];
      a6 += lo16f(q[u].w)*w[u]; a7 += hi16f(q[u].w)*w[u];
    }
  }
  #pragma unroll
  for (int m = 16; m <= 32; m <<= 1){
    a0 += __shfl_xor(a0, m); a1 += __shfl_xor(a1, m);
    a2 += __shfl_xor(a2, m); a3 += __shfl_xor(a3, m);
    a4 += __shfl_xor(a4, m); a5 += __shfl_xor(a5, m);
    a6 += __shfl_xor(a6, m); a7 += __shfl_xor(a7, m);
  }
  if (g == 0){
    float wd = dinv[row];
    uint4 o;
    o.x = pack2(a0*wd, a1*wd);
    o.y = pack2(a2*wd, a3*wd);
    o.z = pack2(a4*wd, a5*wd);
    o.w = pack2(a6*wd, a7*wd);
    *(uint4*)(xout + (long long)row*CD + c*8) = o;
  }
}

// semantic attention: W1T staged in LDS (swizzled), 64 rows/wave, 256 rows/block.
// grid (157, ch=2, side=2); 40000 = 625 x 64 so tail waves skip cleanly.
__global__ void __launch_bounds__(256)
k_att3(const u16* __restrict__ z0, const u16* __restrict__ z1,
       const u16* __restrict__ z2, const u16* __restrict__ z3,
       const float* __restrict__ rs40k,
       const u16* __restrict__ W1Tu, const u16* __restrict__ W1Ti,
       const float* __restrict__ b1u, const float* __restrict__ b1i,
       const float* __restrict__ W2u, const float* __restrict__ W2i,
       float* __restrict__ misc, int L){
  __shared__ uint4 ldsW[2048];   // 128 rows x 16 chunks (uint4), XOR-swizzled = 32 KB
  __shared__ float wred[4];
  int side = blockIdx.z, ch = blockIdx.y;
  const u16* z = side ? (ch ? z3 : z2) : (ch ? z1 : z0);
  const float* rsi = rs40k + side*160000 + ch*80000;
  const u16* W1T = side ? W1Ti : W1Tu;
  const float* b1 = side ? b1i : b1u;
  const float* W2 = side ? W2i : W2u;
  float* s_out = misc + side*6 + 2*L + ch;
  int t = threadIdx.x;
  for (int i = t; i < 2048; i += 256){
    int row = i >> 4, c = i & 15;
    ldsW[(row << 4) | (c ^ (row & 7))] = *(const uint4*)(W1T + row*CD + c*8);
  }
  __syncthreads();
  int wv = t >> 6, lane = t & 63;
  int m = lane & 15, kq = lane >> 4;
  int base = blockIdx.x*256 + wv*64;
  float psum = 0.f;
  if (base < CNU){
    bf16x8 a[4][4];
    float rsv[4][4];
    #pragma unroll
    for (int c = 0; c < 4; ++c){
      int row = base + c*16;
      #pragma unroll
      for (int tt = 0; tt < 4; ++tt){
        uint4 q = *(const uint4*)(z + (long long)(row + m)*CD + tt*32 + kq*8);
        a[c][tt] = *(bf16x8*)&q;
      }
      #pragma unroll
      for (int ri = 0; ri < 4; ++ri) rsv[c][ri] = rsi[row + kq*4 + ri];
    }
    #pragma unroll
    for (int jt = 0; jt < 8; ++jt){
      f32x4 acc[4];
      #pragma unroll
      for (int c = 0; c < 4; ++c) acc[c] = (f32x4){0.f,0.f,0.f,0.f};
      #pragma unroll
      for (int tt = 0; tt < 4; ++tt){
        int row = jt*16 + m;
        uint4 bq = ldsW[(row << 4) | ((tt*4 + kq) ^ (row & 7))];
        bf16x8 b = *(bf16x8*)&bq;
        #pragma unroll
        for (int c = 0; c < 4; ++c)
          acc[c] = __builtin_amdgcn_mfma_f32_16x16x32_bf16(a[c][tt], b, acc[c], 0, 0, 0);
      }
      int j = jt*16 + m;
      float bb = b1[j], w2 = W2[j];
      #pragma unroll
      for (int c = 0; c < 4; ++c){
        #pragma unroll
        for (int ri = 0; ri < 4; ++ri){
          float x = acc[c][ri]*rsv[c][ri] + bb;
          x = fminf(fmaxf(x, -15.f), 15.f);
          float t2 = __expf(2.f*x);
          psum += ((t2 - 1.f)/(t2 + 1.f))*w2;
        }
      }
    }
    #pragma unroll
    for (int msk = 1; msk <= 32; msk <<= 1) psum += __shfl_xor(psum, msk);
  }
  if (lane == 0) wred[wv] = psum;
  __syncthreads();
  if (t == 0)
    atomicAdd(s_out, wred[0] + wred[1] + wred[2] + wred[3]);
}

// vectorized combine: 8 bf16/thread; blockIdx.y = side. grid (2500, 2).
__global__ void k_combine2v(const u16* __restrict__ z0, const u16* __restrict__ z1,
                            const u16* __restrict__ z2, const u16* __restrict__ z3,
                            const float* __restrict__ rs40k,
                            const float* __restrict__ misc, int L,
                            u16* __restrict__ hu, u16* __restrict__ hi){
  int side = blockIdx.y;
  const u16* za = side ? z2 : z0;
  const u16* zb = side ? z3 : z1;
  const float* rsi0 = rs40k + side*160000;
  const float* rsi1 = rsi0 + 80000;
  const float* s = misc + side*6 + 2*L;
  u16* h = side ? hi : hu;
  long long off = ((long long)blockIdx.x*256 + threadIdx.x)*8;
  int v = (int)(off >> 7);
  float s0 = s[0]*(1.0f/CNU), s1 = s[1]*(1.0f/CNU);
  float m = fmaxf(s0, s1);
  float e0 = __expf(s0 - m), e1 = __expf(s1 - m);
  float r = 1.0f/(e0 + e1);
  float wa = (e0*r)*rsi0[v], wb = (e1*r)*rsi1[v];
  uint4 qa = *(const uint4*)(za + off);
  uint4 qb = *(const uint4*)(zb + off);
  uint4 o;
  o.x = pack2(lo16f(qa.x)*wa + lo16f(qb.x)*wb, hi16f(qa.x)*wa + hi16f(qb.x)*wb);
  o.y = pack2(lo16f(qa.y)*wa + lo16f(qb.y)*wb, hi16f(qa.y)*wa + hi16f(qb.y)*wb);
  o.z = pack2(lo16f(qa.z)*wa + lo16f(qb.z)*wb, hi16f(qa.z)*wa + hi16f(qb.z)*wb);
  o.w = pack2(lo16f(qa.w)*wa + lo16f(qb.w)*wb, hi16f(qa.w)*wa + hi16f(qb.w)*wb);
  *(uint4*)(h + off) = o;
}

// vectorized emb merge: 8 bf16/thread; grid 5000.
__global__ void k_embv(const u16* __restrict__ x2, u16* __restrict__ h_u,
                       u16* __restrict__ h_i){
  long long off = ((long long)blockIdx.x*256 + threadIdx.x)*8;
  u16* h; long long ho;
  if (off < (long long)CNU*CD){ h = h_u; ho = off; }
  else { h = h_i; ho = off - (long long)CNU*CD; }
  uint4 qx = *(const uint4*)(x2 + off);
  uint4 qh = *(const uint4*)(h + ho);
  uint4 o;
  o.x = pack2(0.5f*bf2f((u16)(qh.x & 0xFFFF)) + 0.5f*lo16f(qx.x), 0.5f*hi16f(qh.x) + 0.5f*hi16f(qx.x));
  o.y = pack2(0.5f*lo16f(qh.y) + 0.5f*lo16f(qx.y), 0.5f*hi16f(qh.y) + 0.5f*hi16f(qx.y));
  o.z = pack2(0.5f*lo16f(qh.z) + 0.5f*lo16f(qx.z), 0.5f*hi16f(qh.z) + 0.5f*hi16f(qx.z));
  o.w = pack2(0.5f*lo16f(qh.w) + 0.5f*lo16f(qx.w), 0.5f*hi16f(qh.w) + 0.5f*hi16f(qx.w));
  *(uint4*)(h + ho) = o;
}

// both SSL sides in one launch; blockIdx.y = side (0=user,1=item)
__global__ void k_sslnorm2(const u16* __restrict__ x2, const u16* __restrict__ hu,
                           const u16* __restrict__ hi,
                           const int* __restrict__ uidx, const int* __restrict__ iidx,
                           u16* __restrict__ nbase, float* __restrict__ misc){
  __shared__ float wred[4];
  int side = blockIdx.y;
  const int* idx = side ? iidx : uidx;
  const u16* hemb = side ? hi : hu;
  int rowoff = side ? CNU : 0;
  u16* n1b = nbase + (long long)side*2*CB*CD;
  u16* n2b = n1b + (long long)CB*CD;
  float* pos_acc = misc + 12 + 2*side;
  int wv = threadIdx.x >> 6, lane = threadIdx.x & 63;
  int r0 = blockIdx.x*16 + wv*4;
  int g[4]; u32 q1[4], q2[4];
  #pragma unroll
  for (int u = 0; u < 4; ++u){
    g[u] = idx[r0 + u];
    q1[u] = *(const u32*)(x2 + (long long)(g[u] + rowoff)*CD + lane*2);
    q2[u] = *(const u32*)(hemb + (long long)g[u]*CD + lane*2);
  }
  float psum = 0.f;
  #pragma unroll
  for (int u = 0; u < 4; ++u){
    float a0 = lo16f(q1[u]), a1 = hi16f(q1[u]);
    float b0 = lo16f(q2[u]), b1 = hi16f(q2[u]);
    float s1 = a0*a0 + a1*a1, s2 = b0*b0 + b1*b1, s12 = a0*b0 + a1*b1;
    #pragma unroll
    for (int msk = 1; msk <= 32; msk <<= 1){
      s1  += __shfl_xor(s1, msk);
      s2  += __shfl_xor(s2, msk);
      s12 += __shfl_xor(s12, msk);
    }
    float i1 = 1.0f / fmaxf(sqrtf(s1), 1e-12f);
    float i2 = 1.0f / fmaxf(sqrtf(s2), 1e-12f);
    *(u32*)(n1b + (long long)(r0+u)*CD + lane*2) = pack2(a0*i1, a1*i1);
    *(u32*)(n2b + (long long)(r0+u)*CD + lane*2) = pack2(b0*i2, b1*i2);
    psum += s12*i1*i2*2.0f;
  }
  if (lane == 0) wred[wv] = psum;
  __syncthreads();
  if (threadIdx.x == 0)
    atomicAdd(pos_acc, wred[0] + wred[1] + wred[2] + wred[3]);
}

// alls[i] += sum_j exp(2 * n1_i . n2_j); LDS-staged B (double-buffered, XOR-swizzled),
// 2 i-tiles/wave, grid (64,16,2). blockIdx.z = side.
__global__ void __launch_bounds__(256)
k_alls3(const u16* __restrict__ nbase, float* __restrict__ alls){
  __shared__ uint4 ldsb[2][256];
  int side = blockIdx.z;
  const u16* n1b = nbase + (long long)side*2*CB*CD;
  const u16* n2b = n1b + (long long)CB*CD;
  float* al = alls + side*CB;
  int wv = threadIdx.x >> 6, lane = threadIdx.x & 63;
  int m = lane & 15, kq = lane >> 4;
  int i0 = (blockIdx.x*8 + wv*2)*16;
  bf16x8 a[2][4];
  #pragma unroll
  for (int c = 0; c < 2; ++c){
    #pragma unroll
    for (int t = 0; t < 4; ++t){
      uint4 q = *(const uint4*)(n1b + (long long)(i0 + c*16 + m)*CD + t*32 + kq*8);
      a[c][t] = *(bf16x8*)&q;
    }
  }
  float es0[4] = {0.f,0.f,0.f,0.f};
  float es1[4] = {0.f,0.f,0.f,0.f};
  int j0 = blockIdx.y*512;
  int sr = threadIdx.x >> 4, sc = threadIdx.x & 15;
  const u16* sp = n2b + (long long)(j0 + sr)*CD + sc*8;
  int se = sr*16 + (sc ^ (sr & 7));
  uint4 v = *(const uint4*)sp;
  for (int jt = 0; jt < 32; ++jt){
    ldsb[jt & 1][se] = v;
    if (jt < 31) v = *(const uint4*)(sp + (long long)(jt+1)*16*CD);
    __syncthreads();
    f32x4 ac0 = {0.f,0.f,0.f,0.f}, ac1 = {0.f,0.f,0.f,0.f};
    #pragma unroll
    for (int t = 0; t < 4; ++t){
      int cc = 4*t + kq;
      uint4 bq = ldsb[jt & 1][m*16 + (cc ^ (m & 7))];
      bf16x8 b = *(bf16x8*)&bq;
      ac0 = __builtin_amdgcn_mfma_f32_16x16x32_bf16(a[0][t], b, ac0, 0, 0, 0);
      ac1 = __builtin_amdgcn_mfma_f32_16x16x32_bf16(a[1][t], b, ac1, 0, 0, 0);
    }
    #pragma unroll
    for (int ri = 0; ri < 4; ++ri){
      es0[ri] += __expf(ac0[ri]*2.f);
      es1[ri] += __expf(ac1[ri]*2.f);
    }
  }
  #pragma unroll
  for (int ri = 0; ri < 4; ++ri){
    float v0 = es0[ri], v1 = es1[ri];
    #pragma unroll
    for (int msk = 1; msk <= 8; msk <<= 1){
      v0 += __shfl_xor(v0, msk);
      v1 += __shfl_xor(v1, msk);
    }
    if (m == 0){
      atomicAdd(&al[i0 + kq*4 + ri], v0);
      atomicAdd(&al[i0 + 16 + kq*4 + ri], v1);
    }
  }
}

__global__ void k_logsum(const float* __restrict__ alls, float* __restrict__ misc){
  int i = blockIdx.x*256 + threadIdx.x;
  float v = logf(alls[i]);
  for (int off = 32; off > 0; off >>= 1) v += __shfl_down(v, off);
  if ((threadIdx.x & 63) == 0) atomicAdd(&misc[(i < CB) ? 13 : 15], v);
}

// all 3 output GEMM+LN slabs in one launch; blockIdx.y = slab.
__global__ void k_final3(const u16* __restrict__ hu, const u16* __restrict__ hi,
                         const int* __restrict__ uidx, const int* __restrict__ iidx,
                         const int* __restrict__ nidx,
                         const float* __restrict__ uW, const float* __restrict__ ub,
                         const float* __restrict__ iW, const float* __restrict__ ib,
                         const float* __restrict__ lg, const float* __restrict__ lb,
                         float* __restrict__ outp){
  __shared__ float A[8][128];
  __shared__ float red[8][4];
  int y = blockIdx.y;
  const u16* emb = (y == 0) ? hu : hi;
  const int* idx = (y == 0) ? uidx : ((y == 1) ? iidx : nidx);
  const float* W = (y == 0) ? uW : iW;
  const float* bias = (y == 0) ? ub : ib;
  float* outb = outp + (long long)y*CB*CD;
  int j = threadIdx.x;
  int r0 = blockIdx.x*8;
  for (int r = 0; r < 8; ++r){
    int g = idx[r0 + r];
    A[r][j] = bf2f(emb[(long long)g*CD + j]);
  }
  __syncthreads();
  float acc[8];
  #pragma unroll
  for (int r = 0; r < 8; ++r) acc[r] = 0.f;
  for (int k = 0; k < 128; k += 4){
    float w0 = W[(k+0)*128 + j];
    float w1 = W[(k+1)*128 + j];
    float w2 = W[(k+2)*128 + j];
    float w3 = W[(k+3)*128 + j];
    #pragma unroll
    for (int r = 0; r < 8; ++r){
      float4 a = *(const float4*)&A[r][k];
      acc[r] += a.x*w0 + a.y*w1 + a.z*w2 + a.w*w3;
    }
  }
  float bb = bias[j];
  #pragma unroll
  for (int r = 0; r < 8; ++r){
    float v = acc[r] + bb;
    acc[r] = (v < 0.f) ? 0.f : v;
  }
  int wid = j >> 6, lane = j & 63;
  #pragma unroll
  for (int r = 0; r < 8; ++r){
    float s = acc[r], q = acc[r]*acc[r];
    for (int off = 32; off > 0; off >>= 1){
      s += __shfl_down(s, off); q += __shfl_down(q, off);
    }
    if (lane == 0){ red[r][wid*2] = s; red[r][wid*2+1] = q; }
  }
  __syncthreads();
  float gg = lg[j], be = lb[j];
  #pragma unroll
  for (int r = 0; r < 8; ++r){
    float mu = (red[r][0] + red[r][2]) * (1.0f/128.0f);
    float ms = (red[r][1] + red[r][3]) * (1.0f/128.0f);
    float var = ms - mu*mu;
    float yv = (acc[r] - mu) * rsqrtf(var + 1e-5f) * gg + be;
    outb[(long long)(r0 + r)*CD + j] = yv;
  }
}

__global__ void k_loss(const float* __restrict__ misc, float* __restrict__ o){
  float lu = (misc[13] - misc[12]) * (1.0f/CB);
  float li = (misc[15] - misc[14]) * (1.0f/CB);
  o[0] = 0.4f*(lu + li);
}

extern "C" void kernel_launch(void* const* d_in, const int* in_sizes, int n_in,
                              void* d_out, int out_size, void* d_ws, size_t ws_size,
                              hipStream_t stream){
  (void)in_sizes; (void)n_in; (void)out_size; (void)ws_size;
  const float* feat_user = (const float*)d_in[0];
  const float* feat_item = (const float*)d_in[1];
  const float* u_W1 = (const float*)d_in[2];
  const float* u_b1 = (const float*)d_in[3];
  const float* u_W2 = (const float*)d_in[4];
  const float* i_W1 = (const float*)d_in[5];
  const float* i_b1 = (const float*)d_in[6];
  const float* i_W2 = (const float*)d_in[7];
  const float* user_W = (const float*)d_in[8];
  const float* user_b = (const float*)d_in[9];
  const float* item_W = (const float*)d_in[10];
  const float* item_b = (const float*)d_in[11];
  const float* ln_g = (const float*)d_in[12];
  const float* ln_b = (const float*)d_in[13];
  const int* ump0s = (const int*)d_in[14]; const int* ump0d = (const int*)d_in[15];
  const int* ump1s = (const int*)d_in[16]; const int* ump1d = (const int*)d_in[17];
  const int* imp0s = (const int*)d_in[18]; const int* imp0d = (const int*)d_in[19];
  const int* imp1s = (const int*)d_in[20]; const int* imp1d = (const int*)d_in[21];
  const int* ui_row = (const int*)d_in[22]; const int* ui_col = (const int*)d_in[23];
  const int* user_idx = (const int*)d_in[24]; const int* item_idx = (const int*)d_in[25];
  const int* neg_idx = (const int*)d_in[26];

  u16* W  = (u16*)d_ws;
  u16* fb = W;                      // 10,240,000 bf16
  u16* hu = W + 10240000LL;
  u16* hi = W + 15360000LL;
  u16* xb = W + 20480000LL;         // UI intermediate; MP-build gbytes+odeg; later z2/z3; later SSL nbase
  u16* x2 = W + 30720000LL;
  u16* z0 = W + 40960000LL;
  u16* z1 = W + 46080000LL;
  float* F   = (float*)(W + 51200000LL);
  float* rs  = F;                   // 320,000 (indeg tables at +40000 + y*80000)
  float* dinv= F + 320000;          // 80,000
  float* alls= F + 400000;          // 16,384
  float* misc= F + 416384;          // 64
  int* I     = (int*)(F + 416448);
  int* mp_p  = I;                   // 4 x 40,001
  int* gcur  = I + 160004;          // 1280 (4 x 320)
  int* bbase = I + 161284;          // 1280
  int* gcur2 = I + 162564;          // 1280
  int* mp_c  = I + 163844;          // 4 x 640,000
  u16* w1tu  = (u16*)(I + 2723844); // 16,384 bf16 (W1^T user)
  u16* w1ti  = w1tu + 16384;        // 16,384 bf16 (W1^T item)
  int* ui_ptr    = (int*)hu;        // overlay (hu/hi dead until first combine)
  int* ui_csr    = ui_ptr + 160001; // 1,600,000 ints
  u32* gpairsU   = (u32*)z0;        // UI build: 313*8064*4B = 10.09MB (z0 dead during builds)
  u32* gpairs4   = (u32*)z0;        // MP build: 4*157*8064*4B = 20.26MB over z0+z1 (dead during builds)
  u8*  gbytes4   = (u8*)xb;         // MP build: 4*157*8064 = 5.06MB (xb dead after UI hops)
  u16* odeg4     = xb + 2540000LL;  // 4 x 40,000 u16 (after gbytes4; still inside xb)
  u16* z2 = xb;                     // layer-loop z for item side (xb free during loops)
  u16* z3 = xb + 5120000LL;
  u16* nbase = xb;                  // SSL overlay (z2/z3 dead after loops)
  float* out = (float*)d_out;

  k_zero<<<(16448 + 255)/256, 256, 0, stream>>>(alls, 16448);
  k_initb<<<5064, 256, 0, stream>>>(feat_user, feat_item, fb, u_W1, i_W1, w1tu, w1ti);

  // UI CSR build (counting sort; NB=313 buckets of 256 dst); dinv emitted by pass 2.
  k_izero<<<15, 256, 0, stream>>>(gcur, 3840);
  k_bucket1<<<(CEUI + P1_CHUNK - 1)/P1_CHUNK, 256, 0, stream>>>(ui_col, ui_row, gcur, gpairsU, CEUI, 313);
  k_scanb<<<1, 512, 0, stream>>>(gcur, bbase, 313);
  k_bucket2<<<313, 256, 0, stream>>>(gpairsU, gcur, bbase, ui_csr, ui_ptr, CNN, dinv, 0.0f);

  // UI propagation: fb -> x2 -> xb -> x2   (xb free after this)
  k_gather_ui<<<20000, 256, 0, stream>>>(fb, ui_ptr, ui_csr, dinv, x2, CNN);
  k_gather_ui<<<20000, 256, 0, stream>>>(x2, ui_ptr, ui_csr, dinv, xb, CNN);
  k_gather_ui<<<20000, 256, 0, stream>>>(xb, ui_ptr, ui_csr, dinv, x2, CNN);

  // All 4 MP CSRs in one batched build (y = graph: user mp0, user mp1, item mp0, item mp1)
  k_izero<<<15, 256, 0, stream>>>(gcur, 3840);
  k_bucket1b4<<<dim3((CEMP + P1_CHUNK - 1)/P1_CHUNK, 4), 256, 0, stream>>>(
      ump0s, ump0d, ump1s, ump1d, imp0s, imp0d, imp1s, imp1d,
      gcur, gpairs4, gcur2, gbytes4);
  k_scanb<<<4, 512, 0, stream>>>(gcur, bbase, NB_MP);
  k_odeg4<<<dim3(NB_MP, 4), 256, 0, stream>>>(gbytes4, gcur2, odeg4);
  k_bucket2b4<<<dim3(NB_MP, 4), 256, 0, stream>>>(gpairs4, gcur, bbase, mp_c, mp_p, rs + 40000, odeg4);

  // merged user+item HAN layers (independent chains -> joint launches)
  for (int L = 0; L < 3; ++L){
    k_gather_mp4<<<dim3(10000, 4), 256, 0, stream>>>(fb, hu, hi, L, mp_p, (const u32*)mp_c, z0, z2);
    k_att3<<<dim3(157, 2, 2), 256, 0, stream>>>(z0, z1, z2, z3, rs + 40000,
                                                w1tu, w1ti, u_b1, i_b1, u_W2, i_W2, misc, L);
    k_combine2v<<<dim3(2500, 2), 256, 0, stream>>>(z0, z1, z2, z3, rs + 40000, misc, L, hu, hi);
  }

  k_embv<<<5000, 256, 0, stream>>>(x2, hu, hi);

  // SSL (both sides per launch)
  k_sslnorm2<<<dim3(CB/16, 2), 256, 0, stream>>>(x2, hu, hi, user_idx, item_idx, nbase, misc);
  k_alls3<<<dim3(64, 16, 2), 256, 0, stream>>>(nbase, alls);
  k_logsum<<<64, 256, 0, stream>>>(alls, misc);

  k_final3<<<dim3(1024, 3), 128, 0, stream>>>(hu, hi, user_idx, item_idx, neg_idx,
                                              user_W, user_b, item_W, item_b,
                                              ln_g, ln_b, out);
  k_loss<<<1, 1, 0, stream>>>(misc, out + 3LL*CB*CD);
}

// Round 10
// 862.033 us; speedup vs baseline: 2.9280x; 1.0032x over previous
//
#include <hip/hip_runtime.h>
#include <math.h>

typedef unsigned short u16;
typedef unsigned int u32;
typedef unsigned char u8;
typedef __attribute__((ext_vector_type(8))) short bf16x8;
typedef __attribute__((ext_vector_type(4))) float f32x4;

#define CNU 40000
#define CNN 80000
#define CD  128
#define CEMP 640000
#define CEUI 1600000
#define CB  8192

#define BK_CAP 8064     // per-bucket capacity (mean 5120 UI / 4096 MP; >40 sigma margin)
#define P1_CHUNK 4096   // edges per block in bucket pass 1 (16/thread)
#define NB_MP 157       // MP bucket count (40000/256 rounded up)

__device__ __forceinline__ float bf2f(u16 b){
  union { u32 u; float f; } v; v.u = ((u32)b) << 16; return v.f;
}
__device__ __forceinline__ u16 f2bf(float f){
  union { float f; u32 u; } v; v.f = f;
  u32 u = v.u + 0x7FFFu + ((v.u >> 16) & 1u);
  return (u16)(u >> 16);
}
__device__ __forceinline__ float lo16f(u32 q){ union { u32 u; float f; } v; v.u = q << 16; return v.f; }
__device__ __forceinline__ float hi16f(u32 q){ union { u32 u; float f; } v; v.u = q & 0xFFFF0000u; return v.f; }
__device__ __forceinline__ u32 pack2(float a, float b){
  return (u32)f2bf(a) | ((u32)f2bf(b) << 16);
}

__global__ void k_zero(float* __restrict__ p, long long n){
  long long i = (long long)blockIdx.x*256 + threadIdx.x;
  if (i < n) p[i] = 0.f;
}

__global__ void k_izero(int* __restrict__ p, int n){
  int i = blockIdx.x*256 + threadIdx.x;
  if (i < n) p[i] = 0;
}

// fused + vectorized: feature f32->bf16 cast (blocks 0..4999, 8 floats/thread)
// + W1 transpose (blocks 5000..5063)
__global__ void k_initb(const float* __restrict__ fu, const float* __restrict__ fi,
                        u16* __restrict__ fb,
                        const float* __restrict__ Wu, const float* __restrict__ Wi,
                        u16* __restrict__ Wut, u16* __restrict__ Wit){
  int b = blockIdx.x;
  if (b < 5000){
    long long off = ((long long)b*256 + threadIdx.x)*8;
    const float* src = (off < (long long)CNU*CD) ? (fu + off) : (fi + (off - (long long)CNU*CD));
    float4 f0 = *(const float4*)src;
    float4 f1 = *(const float4*)(src + 4);
    uint4 o;
    o.x = pack2(f0.x, f0.y);
    o.y = pack2(f0.z, f0.w);
    o.z = pack2(f1.x, f1.y);
    o.w = pack2(f1.z, f1.w);
    *(uint4*)(fb + off) = o;
  } else {
    int idx = (b - 5000)*256 + threadIdx.x;
    if (idx < 16384){
      int k = idx >> 7, j = idx & 127;
      Wut[j*128 + k] = f2bf(Wu[idx]);
      Wit[j*128 + k] = f2bf(Wi[idx]);
    }
  }
}

// ---- CSR build via LDS-aggregated counting sort ----
// Pass 1 (UI variant): dst-keyed pair scatter only.
__global__ void k_bucket1(const int* __restrict__ src, const int* __restrict__ dst,
                          int* __restrict__ gcur, u32* __restrict__ gpairs,
                          int E, int NB){
  __shared__ int cnt[320];
  __shared__ int sbase[320];
  int t = threadIdx.x;
  for (int i = t; i < NB; i += 256) cnt[i] = 0;
  __syncthreads();
  int base = blockIdx.x * P1_CHUNK;
  int r[16], dv[16], sv[16];
  #pragma unroll
  for (int u = 0; u < 16; ++u){
    int e = base + u*256 + t;
    bool ok = (e < E);
    dv[u] = ok ? dst[e] : -1;
    sv[u] = ok ? src[e] : 0;
    if (ok) r[u] = atomicAdd(&cnt[dv[u] >> 8], 1);
  }
  __syncthreads();
  for (int i = t; i < NB; i += 256){
    int c = cnt[i];
    sbase[i] = c ? atomicAdd(&gcur[i], c) : 0;
  }
  __syncthreads();
  #pragma unroll
  for (int u = 0; u < 16; ++u){
    if (dv[u] >= 0){
      int b = dv[u] >> 8;
      int p = sbase[b] + r[u];
      if (p < BK_CAP)
        gpairs[(long long)b*BK_CAP + p] = (u32)sv[u] | ((u32)(dv[u] & 255) << 18);
    }
  }
}

// Pass 1 (MP, 4-graph batched): dst-keyed pair scatter + src-keyed byte scatter.
__global__ void k_bucket1b4(const int* __restrict__ s0, const int* __restrict__ d0,
                            const int* __restrict__ s1, const int* __restrict__ d1,
                            const int* __restrict__ s2, const int* __restrict__ d2,
                            const int* __restrict__ s3, const int* __restrict__ d3,
                            int* __restrict__ gcur, u32* __restrict__ gpairs,
                            int* __restrict__ gcur2, u8* __restrict__ gbytes){
  __shared__ int cnt[320], sbase[320], cnt2[320], sbase2[320];
  int g = blockIdx.y;
  const int* src = (g==0) ? s0 : (g==1) ? s1 : (g==2) ? s2 : s3;
  const int* dst = (g==0) ? d0 : (g==1) ? d1 : (g==2) ? d2 : d3;
  int* gc  = gcur  + g*320;
  int* gc2 = gcur2 + g*320;
  u32* gp  = gpairs + (long long)g*NB_MP*BK_CAP;
  u8*  gb  = gbytes + (long long)g*NB_MP*BK_CAP;
  int t = threadIdx.x;
  for (int i = t; i < NB_MP; i += 256){ cnt[i] = 0; cnt2[i] = 0; }
  __syncthreads();
  int base = blockIdx.x * P1_CHUNK;
  int r[16], r2[16], dv[16], sv[16];
  #pragma unroll
  for (int u = 0; u < 16; ++u){
    int e = base + u*256 + t;
    bool ok = (e < CEMP);
    dv[u] = ok ? dst[e] : -1;
    sv[u] = ok ? src[e] : -1;
    if (ok){
      r[u]  = atomicAdd(&cnt[dv[u] >> 8], 1);
      r2[u] = atomicAdd(&cnt2[sv[u] >> 8], 1);
    }
  }
  __syncthreads();
  for (int i = t; i < NB_MP; i += 256){
    int c  = cnt[i];  sbase[i]  = c  ? atomicAdd(&gc[i],  c)  : 0;
    int c2 = cnt2[i]; sbase2[i] = c2 ? atomicAdd(&gc2[i], c2) : 0;
  }
  __syncthreads();
  #pragma unroll
  for (int u = 0; u < 16; ++u){
    if (dv[u] >= 0){
      int b = dv[u] >> 8;
      int p = sbase[b] + r[u];
      if (p < BK_CAP)
        gp[(long long)b*BK_CAP + p] = (u32)sv[u] | ((u32)(dv[u] & 255) << 18);
      int b2 = sv[u] >> 8;
      int p2 = sbase2[b2] + r2[u];
      if (p2 < BK_CAP)
        gb[(long long)b2*BK_CAP + p2] = (u8)(sv[u] & 255);
    }
  }
}

// exclusive scan of bucket counts; blockIdx.x = graph slice (stride 320).
__global__ void k_scanb(const int* __restrict__ gcur, int* __restrict__ bbase, int NB){
  __shared__ int s[512];
  int g = blockIdx.x;
  const int* gc = gcur + g*320;
  int* bb = bbase + g*320;
  int t = threadIdx.x;
  int v = (t < NB) ? gc[t] : 0;
  s[t] = v;
  __syncthreads();
  for (int off = 1; off < 512; off <<= 1){
    int u = (t >= off) ? s[t-off] : 0;
    __syncthreads();
    s[t] += u;
    __syncthreads();
  }
  if (t < NB) bb[t] = s[t] - v;
}

// Count-only pass over src byte-buckets -> u16 out-degree table; blockIdx.y = graph.
__global__ void k_odeg4(const u8* __restrict__ gbytes, const int* __restrict__ gcur2,
                        u16* __restrict__ odeg){
  __shared__ int hist[256];
  int g = blockIdx.y;
  int b = blockIdx.x, t = threadIdx.x;
  hist[t] = 0;
  __syncthreads();
  int cnt = gcur2[g*320 + b]; if (cnt > BK_CAP) cnt = BK_CAP;
  const u8* pp = gbytes + (long long)(g*NB_MP + b)*BK_CAP;
  for (int i = t; i < cnt; i += 256) atomicAdd(&hist[pp[i]], 1);
  __syncthreads();
  int dg = (b << 8) + t;
  if (dg < CNU) odeg[g*CNU + dg] = (u16)hist[t];
}

// Pass 2 (UI): one block per bucket; LDS scatter then streaming CSR write + ptr slice.
__global__ void k_bucket2(const u32* __restrict__ gpairs, const int* __restrict__ gcur,
                          const int* __restrict__ bbase, int* __restrict__ csr,
                          int* __restrict__ ptr, int n,
                          float* __restrict__ rs_ind, float zval){
  __shared__ int hist[256];
  __shared__ int excl[256];
  __shared__ int lptr[256];
  __shared__ int lsrc[BK_CAP];
  int b = blockIdx.x, t = threadIdx.x;
  int cnt = gcur[b]; if (cnt > BK_CAP) cnt = BK_CAP;
  int base = bbase[b];
  hist[t] = 0;
  __syncthreads();
  const u32* pp = gpairs + (long long)b*BK_CAP;
  for (int i = t; i < cnt; i += 256) atomicAdd(&hist[(pp[i] >> 18) & 255], 1);
  __syncthreads();
  int h = hist[t];
  lptr[t] = h;
  __syncthreads();
  for (int off = 1; off < 256; off <<= 1){
    int u2 = (t >= off) ? lptr[t-off] : 0;
    __syncthreads();
    lptr[t] += u2;
    __syncthreads();
  }
  excl[t] = lptr[t] - h;
  __syncthreads();
  hist[t] = excl[t];
  __syncthreads();
  for (int i = t; i < cnt; i += 256){
    u32 v = pp[i];
    int d = (v >> 18) & 255;
    int p = atomicAdd(&hist[d], 1);
    lsrc[p] = (int)(v & 0x3FFFFu);
  }
  __syncthreads();
  for (int i = t; i < cnt; i += 256) csr[base + i] = lsrc[i];
  int dg = (b << 8) + t;
  if (dg <= n) ptr[dg] = base + excl[t];
  if (dg < n)  rs_ind[dg] = (h > 0) ? rsqrtf((float)h) : zval;
}

// Pass 2 (MP, 4-graph batched): packs csr entries (outdeg<<16 | src); blockIdx.y = graph.
__global__ void k_bucket2b4(const u32* __restrict__ gpairs, const int* __restrict__ gcur,
                            const int* __restrict__ bbase, int* __restrict__ csr_base,
                            int* __restrict__ ptr_base, float* __restrict__ rs40k,
                            const u16* __restrict__ odeg){
  __shared__ int hist[256];
  __shared__ int excl[256];
  __shared__ int lptr[256];
  __shared__ int lsrc[BK_CAP];
  int g = blockIdx.y;
  int b = blockIdx.x, t = threadIdx.x;
  int cnt = gcur[g*320 + b]; if (cnt > BK_CAP) cnt = BK_CAP;
  int base = bbase[g*320 + b];
  int* csr = csr_base + (long long)g*CEMP;
  int* ptr = ptr_base + g*(CNU+1);
  float* rs_ind = rs40k + g*80000;
  const u16* od = odeg + g*CNU;
  hist[t] = 0;
  __syncthreads();
  const u32* pp = gpairs + (long long)(g*NB_MP + b)*BK_CAP;
  for (int i = t; i < cnt; i += 256) atomicAdd(&hist[(pp[i] >> 18) & 255], 1);
  __syncthreads();
  int h = hist[t];
  lptr[t] = h;
  __syncthreads();
  for (int off = 1; off < 256; off <<= 1){
    int u2 = (t >= off) ? lptr[t-off] : 0;
    __syncthreads();
    lptr[t] += u2;
    __syncthreads();
  }
  excl[t] = lptr[t] - h;
  __syncthreads();
  hist[t] = excl[t];
  __syncthreads();
  for (int i = t; i < cnt; i += 256){
    u32 v = pp[i];
    int d = (v >> 18) & 255;
    int p = atomicAdd(&hist[d], 1);
    lsrc[p] = (int)(v & 0x3FFFFu);
  }
  __syncthreads();
  for (int i = t; i < cnt; i += 256){
    int s = lsrc[i];
    csr[base + i] = (int)((u32)s | ((u32)od[s] << 16));
  }
  int dg = (b << 8) + t;
  if (dg <= CNU) ptr[dg] = base + excl[t];
  if (dg < CNU)  rs_ind[dg] = (h > 0) ? rsqrtf((float)h) : 1.0f;
}

// ---- gather: 1 wave/row, lane=(g=edge-slot 0..3, c=16B-chunk 0..15) ----
// MP 4-way variant; 16-edge main loop + 4-edge-granule tail (cuts ~46% masked-slot waste).
__global__ void k_gather_mp4(const u16* __restrict__ fb, const u16* __restrict__ hu,
                             const u16* __restrict__ hi, int L,
                             const int* __restrict__ ptr_base, const u32* __restrict__ csr_base,
                             u16* __restrict__ z0base, u16* __restrict__ z2base){
  int row = (blockIdx.x*256 + threadIdx.x) >> 6;
  if (row >= CNU) return;
  int y = blockIdx.y;
  int side = y >> 1;
  const u16* h = (L == 0) ? (fb + (long long)side*CNU*CD) : (side ? hi : hu);
  const int* ptr = ptr_base + y*(CNU+1);
  const u32* csr = csr_base + (long long)y*CEMP;
  u16* z = (y < 2) ? (z0base + (long long)y*CNU*CD) : (z2base + (long long)(y-2)*CNU*CD);
  int lane = threadIdx.x & 63;
  int g = lane >> 4, c = lane & 15;
  int p = ptr[row], pe = ptr[row+1];
  float a0=0,a1=0,a2=0,a3=0,a4=0,a5=0,a6=0,a7=0;
  const u16* hb = h + (long long)c*8;
  int pm = p + ((pe - p) & ~15);
  while (p < pm){
    uint4 q[4]; float w[4];
    #pragma unroll
    for (int u = 0; u < 4; ++u){
      u32 e = csr[p + u*4 + g];
      w[u] = rsqrtf((float)(e >> 16));
      q[u] = *(const uint4*)(hb + (long long)(e & 0xFFFFu)*CD);
    }
    #pragma unroll
    for (int u = 0; u < 4; ++u){
      a0 += lo16f(q[u].x)*w[u]; a1 += hi16f(q[u].x)*w[u];
      a2 += lo16f(q[u].y)*w[u]; a3 += hi16f(q[u].y)*w[u];
      a4 += lo16f(q[u].z)*w[u]; a5 += hi16f(q[u].z)*w[u];
      a6 += lo16f(q[u].w)*w[u]; a7 += hi16f(q[u].w)*w[u];
    }
    p += 16;
  }
  while (p < pe){
    int ei = p + g;
    bool ok = (ei < pe);
    u32 e = ok ? csr[ei] : 0u;
    float w = ok ? rsqrtf((float)(e >> 16)) : 0.f;
    uint4 q = *(const uint4*)(hb + (long long)(e & 0xFFFFu)*CD);
    a0 += lo16f(q.x)*w; a1 += hi16f(q.x)*w;
    a2 += lo16f(q.y)*w; a3 += hi16f(q.y)*w;
    a4 += lo16f(q.z)*w; a5 += hi16f(q.z)*w;
    a6 += lo16f(q.w)*w; a7 += hi16f(q.w)*w;
    p += 4;
  }
  #pragma unroll
  for (int m = 16; m <= 32; m <<= 1){
    a0 += __shfl_xor(a0, m); a1 += __shfl_xor(a1, m);
    a2 += __shfl_xor(a2, m); a3 += __shfl_xor(a3, m);
    a4 += __shfl_xor(a4, m); a5 += __shfl_xor(a5, m);
    a6 += __shfl_xor(a6, m); a7 += __shfl_xor(a7, m);
  }
  if (g == 0){
    uint4 o;
    o.x = pack2(a0, a1);
    o.y = pack2(a2, a3);
    o.z = pack2(a4, a5);
    o.w = pack2(a6, a7);
    *(uint4*)(z + (long long)row*CD + c*8) = o;
  }
}

// UI variant: per-edge w = dinv[src]; 16-edge main + 4-edge tail.
__global__ void k_gather_ui(const u16* __restrict__ xin, const int* __restrict__ ptr,
                            const int* __restrict__ csr_src, const float* __restrict__ dinv,
                            u16* __restrict__ xout, int n){
  int row = (blockIdx.x*256 + threadIdx.x) >> 6;
  if (row >= n) return;
  int lane = threadIdx.x & 63;
  int g = lane >> 4, c = lane & 15;
  int p = ptr[row], pe = ptr[row+1];
  float a0=0,a1=0,a2=0,a3=0,a4=0,a5=0,a6=0,a7=0;
  const u16* hb = xin + (long long)c*8;
  int pm = p + ((pe - p) & ~15);
  while (p < pm){
    uint4 q[4]; float w[4];
    #pragma unroll
    for (int u = 0; u < 4; ++u){
      int s = csr_src[p + u*4 + g];
      w[u] = dinv[s];
      q[u] = *(const uint4*)(hb + (long long)s*CD);
    }
    #pragma unroll
    for (int u = 0; u < 4; ++u){
      a0 += lo16f(q[u].x)*w[u]; a1 += hi16f(q[u].x)*w[u];
      a2 += lo16f(q[u].y)*w[u]; a3 += hi16f(q[u].y)*w[u];
      a4 += lo16f(q[u].z)*w[u]; a5 += hi16f(q[u].z)*w[u];
      a6 += lo16f(q[u].w)*w[u]; a7 += hi16f(q[u].w)*w[u];
    }
    p += 16;
  }
  while (p < pe){
    int ei = p + g;
    bool ok = (ei < pe);
    int s  = ok ? csr_src[ei] : 0;
    float w = ok ? dinv[s] : 0.f;
    uint4 q = *(const uint4*)(hb + (long long)s*CD);
    a0 += lo16f(q.x)*w; a1 += hi16f(q.x)*w;
    a2 += lo16f(q.y)*w; a3 += hi16f(q.y)*w;
    a4 += lo16f(q.z)*w; a5 += hi16f(q.z)*w;
    a6 += lo16f(q.w)*w; a7 += hi16f(q.w)*w;
    p += 4;
  }
  #pragma unroll
  for (int m = 16; m <= 32; m <<= 1){
    a0 += __shfl_xor(a0, m); a1 += __shfl_xor(a1, m);
    a2 += __shfl_xor(a2, m); a3 += __shfl_xor(a3, m);
    a4 += __shfl_xor(a4, m); a5 += __shfl_xor(a5, m);
    a6 += __shfl_xor(a6, m); a7 += __shfl_xor(a7, m);
  }
  if (g == 0){
    float wd = dinv[row];
    uint4 o;
    o.x = pack2(a0*wd, a1*wd);
    o.y = pack2(a2*wd, a3*wd);
    o.z = pack2(a4*wd, a5*wd);
    o.w = pack2(a6*wd, a7*wd);
    *(uint4*)(xout + (long long)row*CD + c*8) = o;
  }
}

// semantic attention: W1T staged in LDS (swizzled), 64 rows/wave, 256 rows/block.
// grid (157, ch=2, side=2); 40000 = 625 x 64 so tail waves skip cleanly.
__global__ void __launch_bounds__(256)
k_att3(const u16* __restrict__ z0, const u16* __restrict__ z1,
       const u16* __restrict__ z2, const u16* __restrict__ z3,
       const float* __restrict__ rs40k,
       const u16* __restrict__ W1Tu, const u16* __restrict__ W1Ti,
       const float* __restrict__ b1u, const float* __restrict__ b1i,
       const float* __restrict__ W2u, const float* __restrict__ W2i,
       float* __restrict__ misc, int L){
  __shared__ uint4 ldsW[2048];   // 128 rows x 16 chunks (uint4), XOR-swizzled = 32 KB
  __shared__ float wred[4];
  int side = blockIdx.z, ch = blockIdx.y;
  const u16* z = side ? (ch ? z3 : z2) : (ch ? z1 : z0);
  const float* rsi = rs40k + side*160000 + ch*80000;
  const u16* W1T = side ? W1Ti : W1Tu;
  const float* b1 = side ? b1i : b1u;
  const float* W2 = side ? W2i : W2u;
  float* s_out = misc + side*6 + 2*L + ch;
  int t = threadIdx.x;
  for (int i = t; i < 2048; i += 256){
    int row = i >> 4, c = i & 15;
    ldsW[(row << 4) | (c ^ (row & 7))] = *(const uint4*)(W1T + row*CD + c*8);
  }
  __syncthreads();
  int wv = t >> 6, lane = t & 63;
  int m = lane & 15, kq = lane >> 4;
  int base = blockIdx.x*256 + wv*64;
  float psum = 0.f;
  if (base < CNU){
    bf16x8 a[4][4];
    float rsv[4][4];
    #pragma unroll
    for (int c = 0; c < 4; ++c){
      int row = base + c*16;
      #pragma unroll
      for (int tt = 0; tt < 4; ++tt){
        uint4 q = *(const uint4*)(z + (long long)(row + m)*CD + tt*32 + kq*8);
        a[c][tt] = *(bf16x8*)&q;
      }
      #pragma unroll
      for (int ri = 0; ri < 4; ++ri) rsv[c][ri] = rsi[row + kq*4 + ri];
    }
    #pragma unroll
    for (int jt = 0; jt < 8; ++jt){
      f32x4 acc[4];
      #pragma unroll
      for (int c = 0; c < 4; ++c) acc[c] = (f32x4){0.f,0.f,0.f,0.f};
      #pragma unroll
      for (int tt = 0; tt < 4; ++tt){
        int row = jt*16 + m;
        uint4 bq = ldsW[(row << 4) | ((tt*4 + kq) ^ (row & 7))];
        bf16x8 b = *(bf16x8*)&bq;
        #pragma unroll
        for (int c = 0; c < 4; ++c)
          acc[c] = __builtin_amdgcn_mfma_f32_16x16x32_bf16(a[c][tt], b, acc[c], 0, 0, 0);
      }
      int j = jt*16 + m;
      float bb = b1[j], w2 = W2[j];
      #pragma unroll
      for (int c = 0; c < 4; ++c){
        #pragma unroll
        for (int ri = 0; ri < 4; ++ri){
          float x = acc[c][ri]*rsv[c][ri] + bb;
          x = fminf(fmaxf(x, -15.f), 15.f);
          float t2 = __expf(2.f*x);
          psum += ((t2 - 1.f)/(t2 + 1.f))*w2;
        }
      }
    }
    #pragma unroll
    for (int msk = 1; msk <= 32; msk <<= 1) psum += __shfl_xor(psum, msk);
  }
  if (lane == 0) wred[wv] = psum;
  __syncthreads();
  if (t == 0)
    atomicAdd(s_out, wred[0] + wred[1] + wred[2] + wred[3]);
}

// vectorized combine: 8 bf16/thread; blockIdx.y = side. grid (2500, 2).
__global__ void k_combine2v(const u16* __restrict__ z0, const u16* __restrict__ z1,
                            const u16* __restrict__ z2, const u16* __restrict__ z3,
                            const float* __restrict__ rs40k,
                            const float* __restrict__ misc, int L,
                            u16* __restrict__ hu, u16* __restrict__ hi){
  int side = blockIdx.y;
  const u16* za = side ? z2 : z0;
  const u16* zb = side ? z3 : z1;
  const float* rsi0 = rs40k + side*160000;
  const float* rsi1 = rsi0 + 80000;
  const float* s = misc + side*6 + 2*L;
  u16* h = side ? hi : hu;
  long long off = ((long long)blockIdx.x*256 + threadIdx.x)*8;
  int v = (int)(off >> 7);
  float s0 = s[0]*(1.0f/CNU), s1 = s[1]*(1.0f/CNU);
  float m = fmaxf(s0, s1);
  float e0 = __expf(s0 - m), e1 = __expf(s1 - m);
  float r = 1.0f/(e0 + e1);
  float wa = (e0*r)*rsi0[v], wb = (e1*r)*rsi1[v];
  uint4 qa = *(const uint4*)(za + off);
  uint4 qb = *(const uint4*)(zb + off);
  uint4 o;
  o.x = pack2(lo16f(qa.x)*wa + lo16f(qb.x)*wb, hi16f(qa.x)*wa + hi16f(qb.x)*wb);
  o.y = pack2(lo16f(qa.y)*wa + lo16f(qb.y)*wb, hi16f(qa.y)*wa + hi16f(qb.y)*wb);
  o.z = pack2(lo16f(qa.z)*wa + lo16f(qb.z)*wb, hi16f(qa.z)*wa + hi16f(qb.z)*wb);
  o.w = pack2(lo16f(qa.w)*wa + lo16f(qb.w)*wb, hi16f(qa.w)*wa + hi16f(qb.w)*wb);
  *(uint4*)(h + off) = o;
}

// vectorized emb merge: 8 bf16/thread; grid 5000.
__global__ void k_embv(const u16* __restrict__ x2, u16* __restrict__ h_u,
                       u16* __restrict__ h_i){
  long long off = ((long long)blockIdx.x*256 + threadIdx.x)*8;
  u16* h; long long ho;
  if (off < (long long)CNU*CD){ h = h_u; ho = off; }
  else { h = h_i; ho = off - (long long)CNU*CD; }
  uint4 qx = *(const uint4*)(x2 + off);
  uint4 qh = *(const uint4*)(h + ho);
  uint4 o;
  o.x = pack2(0.5f*lo16f(qh.x) + 0.5f*lo16f(qx.x), 0.5f*hi16f(qh.x) + 0.5f*hi16f(qx.x));
  o.y = pack2(0.5f*lo16f(qh.y) + 0.5f*lo16f(qx.y), 0.5f*hi16f(qh.y) + 0.5f*hi16f(qx.y));
  o.z = pack2(0.5f*lo16f(qh.z) + 0.5f*lo16f(qx.z), 0.5f*hi16f(qh.z) + 0.5f*hi16f(qx.z));
  o.w = pack2(0.5f*lo16f(qh.w) + 0.5f*lo16f(qx.w), 0.5f*hi16f(qh.w) + 0.5f*hi16f(qx.w));
  *(uint4*)(h + ho) = o;
}

// both SSL sides in one launch; blockIdx.y = side (0=user,1=item)
__global__ void k_sslnorm2(const u16* __restrict__ x2, const u16* __restrict__ hu,
                           const u16* __restrict__ hi,
                           const int* __restrict__ uidx, const int* __restrict__ iidx,
                           u16* __restrict__ nbase, float* __restrict__ misc){
  __shared__ float wred[4];
  int side = blockIdx.y;
  const int* idx = side ? iidx : uidx;
  const u16* hemb = side ? hi : hu;
  int rowoff = side ? CNU : 0;
  u16* n1b = nbase + (long long)side*2*CB*CD;
  u16* n2b = n1b + (long long)CB*CD;
  float* pos_acc = misc + 12 + 2*side;
  int wv = threadIdx.x >> 6, lane = threadIdx.x & 63;
  int r0 = blockIdx.x*16 + wv*4;
  int g[4]; u32 q1[4], q2[4];
  #pragma unroll
  for (int u = 0; u < 4; ++u){
    g[u] = idx[r0 + u];
    q1[u] = *(const u32*)(x2 + (long long)(g[u] + rowoff)*CD + lane*2);
    q2[u] = *(const u32*)(hemb + (long long)g[u]*CD + lane*2);
  }
  float psum = 0.f;
  #pragma unroll
  for (int u = 0; u < 4; ++u){
    float a0 = lo16f(q1[u]), a1 = hi16f(q1[u]);
    float b0 = lo16f(q2[u]), b1 = hi16f(q2[u]);
    float s1 = a0*a0 + a1*a1, s2 = b0*b0 + b1*b1, s12 = a0*b0 + a1*b1;
    #pragma unroll
    for (int msk = 1; msk <= 32; msk <<= 1){
      s1  += __shfl_xor(s1, msk);
      s2  += __shfl_xor(s2, msk);
      s12 += __shfl_xor(s12, msk);
    }
    float i1 = 1.0f / fmaxf(sqrtf(s1), 1e-12f);
    float i2 = 1.0f / fmaxf(sqrtf(s2), 1e-12f);
    *(u32*)(n1b + (long long)(r0+u)*CD + lane*2) = pack2(a0*i1, a1*i1);
    *(u32*)(n2b + (long long)(r0+u)*CD + lane*2) = pack2(b0*i2, b1*i2);
    psum += s12*i1*i2*2.0f;
  }
  if (lane == 0) wred[wv] = psum;
  __syncthreads();
  if (threadIdx.x == 0)
    atomicAdd(pos_acc, wred[0] + wred[1] + wred[2] + wred[3]);
}

// alls[i] += sum_j exp(2 * n1_i . n2_j); LDS-staged B (double-buffered, XOR-swizzled),
// 2 i-tiles/wave, grid (64,16,2). blockIdx.z = side.
__global__ void __launch_bounds__(256)
k_alls3(const u16* __restrict__ nbase, float* __restrict__ alls){
  __shared__ uint4 ldsb[2][256];
  int side = blockIdx.z;
  const u16* n1b = nbase + (long long)side*2*CB*CD;
  const u16* n2b = n1b + (long long)CB*CD;
  float* al = alls + side*CB;
  int wv = threadIdx.x >> 6, lane = threadIdx.x & 63;
  int m = lane & 15, kq = lane >> 4;
  int i0 = (blockIdx.x*8 + wv*2)*16;
  bf16x8 a[2][4];
  #pragma unroll
  for (int c = 0; c < 2; ++c){
    #pragma unroll
    for (int t = 0; t < 4; ++t){
      uint4 q = *(const uint4*)(n1b + (long long)(i0 + c*16 + m)*CD + t*32 + kq*8);
      a[c][t] = *(bf16x8*)&q;
    }
  }
  float es0[4] = {0.f,0.f,0.f,0.f};
  float es1[4] = {0.f,0.f,0.f,0.f};
  int j0 = blockIdx.y*512;
  int sr = threadIdx.x >> 4, sc = threadIdx.x & 15;
  const u16* sp = n2b + (long long)(j0 + sr)*CD + sc*8;
  int se = sr*16 + (sc ^ (sr & 7));
  uint4 v = *(const uint4*)sp;
  for (int jt = 0; jt < 32; ++jt){
    ldsb[jt & 1][se] = v;
    if (jt < 31) v = *(const uint4*)(sp + (long long)(jt+1)*16*CD);
    __syncthreads();
    f32x4 ac0 = {0.f,0.f,0.f,0.f}, ac1 = {0.f,0.f,0.f,0.f};
    #pragma unroll
    for (int t = 0; t < 4; ++t){
      int cc = 4*t + kq;
      uint4 bq = ldsb[jt & 1][m*16 + (cc ^ (m & 7))];
      bf16x8 b = *(bf16x8*)&bq;
      ac0 = __builtin_amdgcn_mfma_f32_16x16x32_bf16(a[0][t], b, ac0, 0, 0, 0);
      ac1 = __builtin_amdgcn_mfma_f32_16x16x32_bf16(a[1][t], b, ac1, 0, 0, 0);
    }
    #pragma unroll
    for (int ri = 0; ri < 4; ++ri){
      es0[ri] += __expf(ac0[ri]*2.f);
      es1[ri] += __expf(ac1[ri]*2.f);
    }
  }
  #pragma unroll
  for (int ri = 0; ri < 4; ++ri){
    float v0 = es0[ri], v1 = es1[ri];
    #pragma unroll
    for (int msk = 1; msk <= 8; msk <<= 1){
      v0 += __shfl_xor(v0, msk);
      v1 += __shfl_xor(v1, msk);
    }
    if (m == 0){
      atomicAdd(&al[i0 + kq*4 + ri], v0);
      atomicAdd(&al[i0 + 16 + kq*4 + ri], v1);
    }
  }
}

__global__ void k_logsum(const float* __restrict__ alls, float* __restrict__ misc){
  int i = blockIdx.x*256 + threadIdx.x;
  float v = logf(alls[i]);
  for (int off = 32; off > 0; off >>= 1) v += __shfl_down(v, off);
  if ((threadIdx.x & 63) == 0) atomicAdd(&misc[(i < CB) ? 13 : 15], v);
}

// all 3 output GEMM+LN slabs in one launch; blockIdx.y = slab.
__global__ void k_final3(const u16* __restrict__ hu, const u16* __restrict__ hi,
                         const int* __restrict__ uidx, const int* __restrict__ iidx,
                         const int* __restrict__ nidx,
                         const float* __restrict__ uW, const float* __restrict__ ub,
                         const float* __restrict__ iW, const float* __restrict__ ib,
                         const float* __restrict__ lg, const float* __restrict__ lb,
                         float* __restrict__ outp){
  __shared__ float A[8][128];
  __shared__ float red[8][4];
  int y = blockIdx.y;
  const u16* emb = (y == 0) ? hu : hi;
  const int* idx = (y == 0) ? uidx : ((y == 1) ? iidx : nidx);
  const float* W = (y == 0) ? uW : iW;
  const float* bias = (y == 0) ? ub : ib;
  float* outb = outp + (long long)y*CB*CD;
  int j = threadIdx.x;
  int r0 = blockIdx.x*8;
  for (int r = 0; r < 8; ++r){
    int g = idx[r0 + r];
    A[r][j] = bf2f(emb[(long long)g*CD + j]);
  }
  __syncthreads();
  float acc[8];
  #pragma unroll
  for (int r = 0; r < 8; ++r) acc[r] = 0.f;
  for (int k = 0; k < 128; k += 4){
    float w0 = W[(k+0)*128 + j];
    float w1 = W[(k+1)*128 + j];
    float w2 = W[(k+2)*128 + j];
    float w3 = W[(k+3)*128 + j];
    #pragma unroll
    for (int r = 0; r < 8; ++r){
      float4 a = *(const float4*)&A[r][k];
      acc[r] += a.x*w0 + a.y*w1 + a.z*w2 + a.w*w3;
    }
  }
  float bb = bias[j];
  #pragma unroll
  for (int r = 0; r < 8; ++r){
    float v = acc[r] + bb;
    acc[r] = (v < 0.f) ? 0.f : v;
  }
  int wid = j >> 6, lane = j & 63;
  #pragma unroll
  for (int r = 0; r < 8; ++r){
    float s = acc[r], q = acc[r]*acc[r];
    for (int off = 32; off > 0; off >>= 1){
      s += __shfl_down(s, off); q += __shfl_down(q, off);
    }
    if (lane == 0){ red[r][wid*2] = s; red[r][wid*2+1] = q; }
  }
  __syncthreads();
  float gg = lg[j], be = lb[j];
  #pragma unroll
  for (int r = 0; r < 8; ++r){
    float mu = (red[r][0] + red[r][2]) * (1.0f/128.0f);
    float ms = (red[r][1] + red[r][3]) * (1.0f/128.0f);
    float var = ms - mu*mu;
    float yv = (acc[r] - mu) * rsqrtf(var + 1e-5f) * gg + be;
    outb[(long long)(r0 + r)*CD + j] = yv;
  }
}

__global__ void k_loss(const float* __restrict__ misc, float* __restrict__ o){
  float lu = (misc[13] - misc[12]) * (1.0f/CB);
  float li = (misc[15] - misc[14]) * (1.0f/CB);
  o[0] = 0.4f*(lu + li);
}

extern "C" void kernel_launch(void* const* d_in, const int* in_sizes, int n_in,
                              void* d_out, int out_size, void* d_ws, size_t ws_size,
                              hipStream_t stream){
  (void)in_sizes; (void)n_in; (void)out_size; (void)ws_size;
  const float* feat_user = (const float*)d_in[0];
  const float* feat_item = (const float*)d_in[1];
  const float* u_W1 = (const float*)d_in[2];
  const float* u_b1 = (const float*)d_in[3];
  const float* u_W2 = (const float*)d_in[4];
  const float* i_W1 = (const float*)d_in[5];
  const float* i_b1 = (const float*)d_in[6];
  const float* i_W2 = (const float*)d_in[7];
  const float* user_W = (const float*)d_in[8];
  const float* user_b = (const float*)d_in[9];
  const float* item_W = (const float*)d_in[10];
  const float* item_b = (const float*)d_in[11];
  const float* ln_g = (const float*)d_in[12];
  const float* ln_b = (const float*)d_in[13];
  const int* ump0s = (const int*)d_in[14]; const int* ump0d = (const int*)d_in[15];
  const int* ump1s = (const int*)d_in[16]; const int* ump1d = (const int*)d_in[17];
  const int* imp0s = (const int*)d_in[18]; const int* imp0d = (const int*)d_in[19];
  const int* imp1s = (const int*)d_in[20]; const int* imp1d = (const int*)d_in[21];
  const int* ui_row = (const int*)d_in[22]; const int* ui_col = (const int*)d_in[23];
  const int* user_idx = (const int*)d_in[24]; const int* item_idx = (const int*)d_in[25];
  const int* neg_idx = (const int*)d_in[26];

  u16* W  = (u16*)d_ws;
  u16* fb = W;                      // 10,240,000 bf16
  u16* hu = W + 10240000LL;
  u16* hi = W + 15360000LL;
  u16* xb = W + 20480000LL;         // UI intermediate; MP-build gbytes+odeg; later z2/z3; later SSL nbase
  u16* x2 = W + 30720000LL;
  u16* z0 = W + 40960000LL;
  u16* z1 = W + 46080000LL;
  float* F   = (float*)(W + 51200000LL);
  float* rs  = F;                   // 320,000 (indeg tables at +40000 + y*80000)
  float* dinv= F + 320000;          // 80,000
  float* alls= F + 400000;          // 16,384
  float* misc= F + 416384;          // 64
  int* I     = (int*)(F + 416448);
  int* mp_p  = I;                   // 4 x 40,001
  int* gcur  = I + 160004;          // 1280 (4 x 320)
  int* bbase = I + 161284;          // 1280
  int* gcur2 = I + 162564;          // 1280
  int* mp_c  = I + 163844;          // 4 x 640,000
  u16* w1tu  = (u16*)(I + 2723844); // 16,384 bf16 (W1^T user)
  u16* w1ti  = w1tu + 16384;        // 16,384 bf16 (W1^T item)
  int* ui_ptr    = (int*)hu;        // overlay (hu/hi dead until first combine)
  int* ui_csr    = ui_ptr + 160001; // 1,600,000 ints
  u32* gpairsU   = (u32*)z0;        // UI build: 313*8064*4B = 10.09MB (z0 dead during builds)
  u32* gpairs4   = (u32*)z0;        // MP build: 4*157*8064*4B = 20.26MB over z0+z1 (dead during builds)
  u8*  gbytes4   = (u8*)xb;         // MP build: 4*157*8064 = 5.06MB (xb dead after UI hops)
  u16* odeg4     = xb + 2540000LL;  // 4 x 40,000 u16 (after gbytes4; still inside xb)
  u16* z2 = xb;                     // layer-loop z for item side (xb free during loops)
  u16* z3 = xb + 5120000LL;
  u16* nbase = xb;                  // SSL overlay (z2/z3 dead after loops)
  float* out = (float*)d_out;

  k_zero<<<(16448 + 255)/256, 256, 0, stream>>>(alls, 16448);
  k_initb<<<5064, 256, 0, stream>>>(feat_user, feat_item, fb, u_W1, i_W1, w1tu, w1ti);

  // UI CSR build (counting sort; NB=313 buckets of 256 dst); dinv emitted by pass 2.
  k_izero<<<15, 256, 0, stream>>>(gcur, 3840);
  k_bucket1<<<(CEUI + P1_CHUNK - 1)/P1_CHUNK, 256, 0, stream>>>(ui_col, ui_row, gcur, gpairsU, CEUI, 313);
  k_scanb<<<1, 512, 0, stream>>>(gcur, bbase, 313);
  k_bucket2<<<313, 256, 0, stream>>>(gpairsU, gcur, bbase, ui_csr, ui_ptr, CNN, dinv, 0.0f);

  // UI propagation: fb -> x2 -> xb -> x2   (xb free after this)
  k_gather_ui<<<20000, 256, 0, stream>>>(fb, ui_ptr, ui_csr, dinv, x2, CNN);
  k_gather_ui<<<20000, 256, 0, stream>>>(x2, ui_ptr, ui_csr, dinv, xb, CNN);
  k_gather_ui<<<20000, 256, 0, stream>>>(xb, ui_ptr, ui_csr, dinv, x2, CNN);

  // All 4 MP CSRs in one batched build (y = graph: user mp0, user mp1, item mp0, item mp1)
  k_izero<<<15, 256, 0, stream>>>(gcur, 3840);
  k_bucket1b4<<<dim3((CEMP + P1_CHUNK - 1)/P1_CHUNK, 4), 256, 0, stream>>>(
      ump0s, ump0d, ump1s, ump1d, imp0s, imp0d, imp1s, imp1d,
      gcur, gpairs4, gcur2, gbytes4);
  k_scanb<<<4, 512, 0, stream>>>(gcur, bbase, NB_MP);
  k_odeg4<<<dim3(NB_MP, 4), 256, 0, stream>>>(gbytes4, gcur2, odeg4);
  k_bucket2b4<<<dim3(NB_MP, 4), 256, 0, stream>>>(gpairs4, gcur, bbase, mp_c, mp_p, rs + 40000, odeg4);

  // merged user+item HAN layers (independent chains -> joint launches)
  for (int L = 0; L < 3; ++L){
    k_gather_mp4<<<dim3(10000, 4), 256, 0, stream>>>(fb, hu, hi, L, mp_p, (const u32*)mp_c, z0, z2);
    k_att3<<<dim3(157, 2, 2), 256, 0, stream>>>(z0, z1, z2, z3, rs + 40000,
                                                w1tu, w1ti, u_b1, i_b1, u_W2, i_W2, misc, L);
    k_combine2v<<<dim3(2500, 2), 256, 0, stream>>>(z0, z1, z2, z3, rs + 40000, misc, L, hu, hi);
  }

  k_embv<<<5000, 256, 0, stream>>>(x2, hu, hi);

  // SSL (both sides per launch)
  k_sslnorm2<<<dim3(CB/16, 2), 256, 0, stream>>>(x2, hu, hi, user_idx, item_idx, nbase, misc);
  k_alls3<<<dim3(64, 16, 2), 256, 0, stream>>>(nbase, alls);
  k_logsum<<<64, 256, 0, stream>>>(alls, misc);

  k_final3<<<dim3(1024, 3), 128, 0, stream>>>(hu, hi, user_idx, item_idx, neg_idx,
                                              user_W, user_b, item_W, item_b,
                                              ln_g, ln_b, out);
  k_loss<<<1, 1, 0, stream>>>(misc, out + 3LL*CB*CD);
}